// Round 1
// baseline (2002.772 us; speedup 1.0000x reference)
//
#include <hip/hip_runtime.h>
#include <math.h>

#define NHEAD 4

// ---------------- CSR build (by dst), reused by both layers ----------------
__global__ void hist_kernel(const int* __restrict__ ei, int E, int* __restrict__ deg) {
  int i = blockIdx.x * blockDim.x + threadIdx.x;
  for (; i < E; i += gridDim.x * blockDim.x)
    atomicAdd(&deg[ei[E + i]], 1);
}

__global__ void scan_kernel(const int* __restrict__ deg, int* __restrict__ rp, int n) {
  __shared__ int tile[256];
  int carry = 0;
  for (int base = 0; base < n; base += 256) {
    int i = base + (int)threadIdx.x;
    int v = (i < n) ? deg[i] : 0;
    tile[threadIdx.x] = v;
    __syncthreads();
    for (int off = 1; off < 256; off <<= 1) {
      int t = (threadIdx.x >= (unsigned)off) ? tile[threadIdx.x - off] : 0;
      __syncthreads();
      tile[threadIdx.x] += t;
      __syncthreads();
    }
    if (i < n) rp[i] = carry + tile[threadIdx.x] - v;  // exclusive
    carry += tile[255];
    __syncthreads();
  }
  if (threadIdx.x == 0) rp[n] = carry;
}

__global__ void scatter_kernel(const int* __restrict__ ei, int E,
                               const int* __restrict__ rp, int* __restrict__ cur,
                               int* __restrict__ col) {
  int i = blockIdx.x * blockDim.x + threadIdx.x;
  for (; i < E; i += gridDim.x * blockDim.x) {
    int dst = ei[E + i];
    int pos = rp[dst] + atomicAdd(&cur[dst], 1);
    col[pos] = i;  // original edge id
  }
}

// ---------------- h = x @ W + b ----------------
template <int K, int F, int BM>
__global__ void proj_kernel(const float* __restrict__ x, const float* __restrict__ w,
                            const float* __restrict__ b, float* __restrict__ out, int n) {
  __shared__ float xs[BM][K];
  const int f = threadIdx.x;  // blockDim == F
  const int n0 = blockIdx.x * BM;
  for (int idx = threadIdx.x; idx < BM * K; idx += F) {
    int m = idx / K, k = idx - m * K;
    int nn = n0 + m;
    xs[m][k] = (nn < n) ? x[nn * K + k] : 0.f;
  }
  __syncthreads();
  float acc[BM];
#pragma unroll
  for (int m = 0; m < BM; ++m) acc[m] = 0.f;
  for (int k = 0; k < K; ++k) {
    float wv = w[k * F + f];
#pragma unroll
    for (int m = 0; m < BM; ++m) acc[m] += xs[m][k] * wv;
  }
  float bv = b[f];
#pragma unroll
  for (int m = 0; m < BM; ++m) {
    int nn = n0 + m;
    if (nn < n) out[nn * F + f] = acc[m] + bv;
  }
}

// ---------------- s[n,h]=sum_d h*asrc, d[n,h]=sum_d h*adst ----------------
template <int F, int D>
__global__ void sd_kernel(const float* __restrict__ h, const float* __restrict__ a_src,
                          const float* __restrict__ a_dst, float* __restrict__ s,
                          float* __restrict__ d, int n) {
  int nn = blockIdx.x;
  int f = threadIdx.x;  // blockDim == F
  float hv = h[nn * F + f];
  float sv = hv * a_src[f];
  float dv = hv * a_dst[f];
#pragma unroll
  for (int off = D / 2; off > 0; off >>= 1) {
    sv += __shfl_xor(sv, off, D);
    dv += __shfl_xor(dv, off, D);
  }
  if ((f % D) == 0) {
    s[nn * NHEAD + f / D] = sv;
    d[nn * NHEAD + f / D] = dv;
  }
}

// ---------------- per-edge: ex = exp(leaky_relu(s[src]+d[dst])), denom[dst] += ex ----
__global__ void edge_alpha_kernel(const float* __restrict__ s, const float* __restrict__ d,
                                  const int* __restrict__ ei, int E,
                                  float* __restrict__ ex, float* __restrict__ denom) {
  int idx = blockIdx.x * blockDim.x + threadIdx.x;
  int total = E * NHEAD;
  for (; idx < total; idx += gridDim.x * blockDim.x) {
    int e = idx >> 2, hh = idx & 3;
    int src = ei[e];
    int dst = ei[E + e];
    float a = s[src * NHEAD + hh] + d[dst * NHEAD + hh];
    a = (a >= 0.f) ? a : 0.2f * a;
    float v = expf(a);  // segment_max skipped: cancels exactly in softmax, alpha is O(1)
    ex[idx] = v;
    atomicAdd(&denom[dst * NHEAD + hh], v);
  }
}

// ---------------- out[dst] = relu( (sum_e ex_e * h[src_e]) / denom[dst] ) ----------
template <int F, int D>
__global__ void message_kernel(const float* __restrict__ h, const int* __restrict__ ei,
                               const int* __restrict__ rp, const int* __restrict__ col,
                               const float* __restrict__ ex, const float* __restrict__ denom,
                               float* __restrict__ out, int n, int E) {
  int nn = blockIdx.x;
  int f = threadIdx.x;  // blockDim == F
  int hh = f / D;
  int lo = rp[nn], hi = rp[nn + 1];
  float acc = 0.f;
  for (int j = lo; j < hi; ++j) {
    int e = col[j];
    int src = ei[e];
    float coef = ex[e * NHEAD + hh];
    acc += h[src * F + f] * coef;
  }
  float den = denom[nn * NHEAD + hh] + 1e-16f;
  out[nn * F + f] = fmaxf(acc / den, 0.f);
}

// ---------------- wsum[f] += sum_m tanh( st[m] @ klw[:,f] + klb[f] ) ----------------
template <int F, int BM>
__global__ void semantic_w_kernel(const float* __restrict__ st, const float* __restrict__ klw,
                                  const float* __restrict__ klb, float* __restrict__ wsum,
                                  int n) {
  __shared__ float xs[BM][F];
  const int f = threadIdx.x;  // blockDim == F
  const int n0 = blockIdx.x * BM;
#pragma unroll
  for (int m = 0; m < BM; ++m) {
    int nn = n0 + m;
    xs[m][f] = (nn < n) ? st[nn * F + f] : 0.f;
  }
  __syncthreads();
  float acc[BM];
#pragma unroll
  for (int m = 0; m < BM; ++m) acc[m] = 0.f;
  for (int k = 0; k < F; ++k) {
    float wv = klw[k * F + f];
#pragma unroll
    for (int m = 0; m < BM; ++m) acc[m] += xs[m][k] * wv;
  }
  float bv = klb[f];
  float part = 0.f;
  int rem = n - n0;
#pragma unroll
  for (int m = 0; m < BM; ++m)
    if (m < rem) part += tanhf(acc[m] + bv);
  atomicAdd(&wsum[f], part);
}

// ---------------- attn = softmax_r( mean_w_r . q ) ----------------
template <int F>
__global__ void attn_kernel(const float* __restrict__ wsum, const float* __restrict__ q,
                            float* __restrict__ attn, float inv_n) {
  __shared__ float red[2][F / 64];
  int f = threadIdx.x;
  float qv = q[f];
  float v0 = wsum[f] * inv_n * qv;
  float v1 = wsum[F + f] * inv_n * qv;
#pragma unroll
  for (int off = 32; off > 0; off >>= 1) {
    v0 += __shfl_down(v0, off, 64);
    v1 += __shfl_down(v1, off, 64);
  }
  int w = f / 64;
  if ((f & 63) == 0) { red[0][w] = v0; red[1][w] = v1; }
  __syncthreads();
  if (f == 0) {
    float d0 = 0.f, d1 = 0.f;
#pragma unroll
    for (int i = 0; i < F / 64; ++i) { d0 += red[0][i]; d1 += red[1][i]; }
    float m = fmaxf(d0, d1);
    float e0 = expf(d0 - m), e1 = expf(d1 - m);
    float inv = 1.f / (e0 + e1);
    attn[0] = e0 * inv;
    attn[1] = e1 * inv;
  }
}

// ---------------- out = attn0*st0 + attn1*st1 (elementwise, float4) ----------------
__global__ void combine_kernel(const float* __restrict__ st0, const float* __restrict__ st1,
                               const float* __restrict__ attn, float* __restrict__ out,
                               int total4) {
  float a0 = attn[0], a1 = attn[1];
  int i = blockIdx.x * blockDim.x + threadIdx.x;
  for (; i < total4; i += gridDim.x * blockDim.x) {
    float4 v0 = ((const float4*)st0)[i];
    float4 v1 = ((const float4*)st1)[i];
    float4 o;
    o.x = a0 * v0.x + a1 * v1.x;
    o.y = a0 * v0.y + a1 * v1.y;
    o.z = a0 * v0.z + a1 * v1.z;
    o.w = a0 * v0.w + a1 * v1.w;
    ((float4*)out)[i] = o;
  }
}

// ---------------- graph mean pool (batch sorted) ----------------
__device__ __forceinline__ int lower_bound_i(const int* a, int n, int key) {
  int lo = 0, hi = n;
  while (lo < hi) {
    int mid = (lo + hi) >> 1;
    if (a[mid] < key) lo = mid + 1; else hi = mid;
  }
  return lo;
}

__global__ void pool_kernel(const float* __restrict__ h, const int* __restrict__ batch,
                            float* __restrict__ pooled, int n) {
  int g = blockIdx.x;       // G blocks
  int f = threadIdx.x;      // 128 threads
  int lo = lower_bound_i(batch, n, g);
  int hi = lower_bound_i(batch, n, g + 1);
  float acc = 0.f;
  for (int nn = lo; nn < hi; ++nn) acc += h[nn * 128 + f];
  float cnt = fmaxf((float)(hi - lo), 1.f);
  pooled[g * 128 + f] = acc / cnt;
}

// ---------------- MLP head: d1 + BN(eval) + leaky(0.1) + d2 ----------------
__global__ void head_kernel(const float* __restrict__ pooled, const float* __restrict__ d1w,
                            const float* __restrict__ d1b, const float* __restrict__ gamma,
                            const float* __restrict__ beta, const float* __restrict__ mean,
                            const float* __restrict__ var, const float* __restrict__ d2w,
                            const float* __restrict__ d2b, float* __restrict__ out) {
  int g = blockIdx.x;   // G blocks
  int j = threadIdx.x;  // 64 threads = 1 wave
  float acc = d1b[j];
  for (int k = 0; k < 128; ++k) acc += pooled[g * 128 + k] * d1w[k * 64 + j];
  float z = (acc - mean[j]) / sqrtf(var[j] + 1e-5f) * gamma[j] + beta[j];
  z = (z >= 0.f) ? z : 0.1f * z;
  float t = z * d2w[j];
#pragma unroll
  for (int off = 32; off > 0; off >>= 1) t += __shfl_down(t, off, 64);
  if (j == 0) out[g] = t + d2b[0];
}

// =====================================================================
template <int IN_, int F, int D>
static void run_layer(const float* x_in, const float* pw, const float* pb,
                      const float* as0, const float* ad0,
                      const float* as1, const float* ad1,
                      const float* klw, const float* klb, const float* q,
                      const int* ei0, const int* ei1,
                      const int* rp0, const int* col0,
                      const int* rp1, const int* col1,
                      float* h_buf, float* st0, float* st1, float* ex_buf,
                      float* s_buf, float* d_buf, float* denom,
                      float* wsum, float* attn, float* out_buf,
                      int N, int E, hipStream_t stream) {
  constexpr int BM = 16;
  int nblk = (N + BM - 1) / BM;
  proj_kernel<IN_, F, BM><<<nblk, F, 0, stream>>>(x_in, pw, pb, h_buf, N);

  const float* as[2] = {as0, as1};
  const float* ad[2] = {ad0, ad1};
  const int* eis[2] = {ei0, ei1};
  const int* rps[2] = {rp0, rp1};
  const int* cols[2] = {col0, col1};
  float* sts[2] = {st0, st1};

  for (int r = 0; r < 2; ++r) {
    sd_kernel<F, D><<<N, F, 0, stream>>>(h_buf, as[r], ad[r], s_buf, d_buf, N);
    hipMemsetAsync(denom, 0, N * NHEAD * sizeof(float), stream);
    int tot = E * NHEAD;
    edge_alpha_kernel<<<(tot + 255) / 256, 256, 0, stream>>>(s_buf, d_buf, eis[r], E, ex_buf, denom);
    message_kernel<F, D><<<N, F, 0, stream>>>(h_buf, eis[r], rps[r], cols[r], ex_buf, denom, sts[r], N, E);
    hipMemsetAsync(wsum + r * F, 0, F * sizeof(float), stream);
    semantic_w_kernel<F, 16><<<nblk, F, 0, stream>>>(sts[r], klw, klb, wsum + r * F, N);
  }
  attn_kernel<F><<<1, F, 0, stream>>>(wsum, q, attn, 1.0f / (float)N);
  int total4 = N * F / 4;
  combine_kernel<<<2048, 256, 0, stream>>>(st0, st1, attn, out_buf, total4);
}

extern "C" void kernel_launch(void* const* d_in, const int* in_sizes, int n_in,
                              void* d_out, int out_size, void* d_ws, size_t ws_size,
                              hipStream_t stream) {
  const float* x      = (const float*)d_in[0];
  const int* ei0      = (const int*)d_in[1];
  const int* ei1      = (const int*)d_in[2];
  const int* batch    = (const int*)d_in[3];
  const float* p1w    = (const float*)d_in[4];
  const float* p1b    = (const float*)d_in[5];
  const float* as1r0  = (const float*)d_in[6];
  const float* ad1r0  = (const float*)d_in[7];
  const float* as1r1  = (const float*)d_in[8];
  const float* ad1r1  = (const float*)d_in[9];
  const float* kl1w   = (const float*)d_in[10];
  const float* kl1b   = (const float*)d_in[11];
  const float* q1     = (const float*)d_in[12];
  const float* p2w    = (const float*)d_in[13];
  const float* p2b    = (const float*)d_in[14];
  const float* as2r0  = (const float*)d_in[15];
  const float* ad2r0  = (const float*)d_in[16];
  const float* as2r1  = (const float*)d_in[17];
  const float* ad2r1  = (const float*)d_in[18];
  const float* kl2w   = (const float*)d_in[19];
  const float* kl2b   = (const float*)d_in[20];
  const float* q2     = (const float*)d_in[21];
  const float* d1w    = (const float*)d_in[22];
  const float* d1b    = (const float*)d_in[23];
  const float* bng    = (const float*)d_in[24];
  const float* bnb    = (const float*)d_in[25];
  const float* bnm    = (const float*)d_in[26];
  const float* bnv    = (const float*)d_in[27];
  const float* d2w    = (const float*)d_in[28];
  const float* d2b    = (const float*)d_in[29];
  float* out = (float*)d_out;

  const int N = in_sizes[3];       // 50000
  const int E = in_sizes[1] / 2;   // 400000
  const int G = 64;

  // ---- workspace bump allocator ----
  char* p = (char*)d_ws;
  auto alloc = [&](size_t bytes) -> void* {
    void* r = (void*)p;
    p += (bytes + 255) & ~(size_t)255;
    return r;
  };
  int* rp0    = (int*)alloc((N + 1) * sizeof(int));
  int* col0   = (int*)alloc(E * sizeof(int));
  int* rp1    = (int*)alloc((N + 1) * sizeof(int));
  int* col1   = (int*)alloc(E * sizeof(int));
  int* tmp    = (int*)alloc(N * sizeof(int));
  float* h_buf  = (float*)alloc((size_t)N * 256 * sizeof(float));
  float* st0    = (float*)alloc((size_t)N * 256 * sizeof(float));
  float* st1    = (float*)alloc((size_t)N * 256 * sizeof(float));
  float* h2_buf = (float*)alloc((size_t)N * 128 * sizeof(float));
  float* ex_buf = (float*)alloc((size_t)E * NHEAD * sizeof(float));
  float* s_buf  = (float*)alloc((size_t)N * NHEAD * sizeof(float));
  float* d_buf  = (float*)alloc((size_t)N * NHEAD * sizeof(float));
  float* denom  = (float*)alloc((size_t)N * NHEAD * sizeof(float));
  float* wsum   = (float*)alloc(2 * 256 * sizeof(float));
  float* attn   = (float*)alloc(2 * sizeof(float));
  float* pooled = (float*)alloc((size_t)G * 128 * sizeof(float));

  // ---- CSR build (dst-indexed), once, reused by both layers ----
  int eblk = (E + 255) / 256;
  {
    hipMemsetAsync(tmp, 0, N * sizeof(int), stream);
    hist_kernel<<<eblk, 256, 0, stream>>>(ei0, E, tmp);
    scan_kernel<<<1, 256, 0, stream>>>(tmp, rp0, N);
    hipMemsetAsync(tmp, 0, N * sizeof(int), stream);
    scatter_kernel<<<eblk, 256, 0, stream>>>(ei0, E, rp0, tmp, col0);

    hipMemsetAsync(tmp, 0, N * sizeof(int), stream);
    hist_kernel<<<eblk, 256, 0, stream>>>(ei1, E, tmp);
    scan_kernel<<<1, 256, 0, stream>>>(tmp, rp1, N);
    hipMemsetAsync(tmp, 0, N * sizeof(int), stream);
    scatter_kernel<<<eblk, 256, 0, stream>>>(ei1, E, rp1, tmp, col1);
  }

  // ---- layer 1: 128 -> 256, D=64; combined output overwrites h_buf ----
  run_layer<128, 256, 64>(x, p1w, p1b, as1r0, ad1r0, as1r1, ad1r1, kl1w, kl1b, q1,
                          ei0, ei1, rp0, col0, rp1, col1,
                          h_buf, st0, st1, ex_buf, s_buf, d_buf, denom, wsum, attn,
                          /*out=*/h_buf, N, E, stream);

  // ---- layer 2: 256 -> 128, D=32; combined output overwrites h2_buf ----
  run_layer<256, 128, 32>(h_buf, p2w, p2b, as2r0, ad2r0, as2r1, ad2r1, kl2w, kl2b, q2,
                          ei0, ei1, rp0, col0, rp1, col1,
                          h2_buf, st0, st1, ex_buf, s_buf, d_buf, denom, wsum, attn,
                          /*out=*/h2_buf, N, E, stream);

  // ---- pool + head ----
  pool_kernel<<<G, 128, 0, stream>>>(h2_buf, batch, pooled, N);
  head_kernel<<<G, 64, 0, stream>>>(pooled, d1w, d1b, bng, bnb, bnm, bnv, d2w, d2b, out);
}

// Round 2
// 1743.707 us; speedup vs baseline: 1.1486x; 1.1486x over previous
//
#include <hip/hip_runtime.h>
#include <math.h>

#define NHEAD 4

__device__ __forceinline__ float fast_tanh(float x) {
  x = fminf(fmaxf(x, -15.f), 15.f);
  float e = __expf(2.f * x);
  return (e - 1.f) / (e + 1.f);
}

// ---------------- CSR build (by dst), reused by both layers ----------------
__global__ void hist_kernel(const int* __restrict__ ei, int E, int* __restrict__ deg) {
  int i = blockIdx.x * blockDim.x + threadIdx.x;
  for (; i < E; i += gridDim.x * blockDim.x)
    atomicAdd(&deg[ei[E + i]], 1);
}

// per-chunk inclusive scan (chunk = 256), block totals to bsum
__global__ void scan_local_kernel(const int* __restrict__ deg, int* __restrict__ incl,
                                  int* __restrict__ bsum, int n) {
  __shared__ int tile[256];
  int i = blockIdx.x * 256 + threadIdx.x;
  int v = (i < n) ? deg[i] : 0;
  tile[threadIdx.x] = v;
  __syncthreads();
  for (int off = 1; off < 256; off <<= 1) {
    int t = (threadIdx.x >= (unsigned)off) ? tile[threadIdx.x - off] : 0;
    __syncthreads();
    tile[threadIdx.x] += t;
    __syncthreads();
  }
  if (i < n) incl[i] = tile[threadIdx.x];
  if (threadIdx.x == 255) bsum[blockIdx.x] = tile[255];
}

// single-block exclusive scan of block sums (nb <= 256)
__global__ void scan_bsum_kernel(int* __restrict__ bsum, int nb) {
  __shared__ int tile[256];
  int v = (threadIdx.x < (unsigned)nb) ? bsum[threadIdx.x] : 0;
  tile[threadIdx.x] = v;
  __syncthreads();
  for (int off = 1; off < 256; off <<= 1) {
    int t = (threadIdx.x >= (unsigned)off) ? tile[threadIdx.x - off] : 0;
    __syncthreads();
    tile[threadIdx.x] += t;
    __syncthreads();
  }
  if (threadIdx.x < (unsigned)nb) bsum[threadIdx.x] = tile[threadIdx.x] - v;
}

__global__ void scan_fix_kernel(const int* __restrict__ incl, const int* __restrict__ deg,
                                const int* __restrict__ bsum, int* __restrict__ rp,
                                int n, int E) {
  int i = blockIdx.x * 256 + threadIdx.x;
  if (i < n) rp[i] = incl[i] - deg[i] + bsum[blockIdx.x];  // global exclusive
  if (i == 0) rp[n] = E;
}

__global__ void scatter_kernel(const int* __restrict__ ei, int E,
                               const int* __restrict__ rp, int* __restrict__ cur,
                               int* __restrict__ col) {
  int i = blockIdx.x * blockDim.x + threadIdx.x;
  for (; i < E; i += gridDim.x * blockDim.x) {
    int dst = ei[E + i];
    int pos = rp[dst] + atomicAdd(&cur[dst], 1);
    col[pos] = i;  // original edge id
  }
}

// ---------------- h = x @ W + b ----------------
template <int K, int F, int BM>
__global__ void proj_kernel(const float* __restrict__ x, const float* __restrict__ w,
                            const float* __restrict__ b, float* __restrict__ out, int n) {
  __shared__ float xs[BM][K];
  const int f = threadIdx.x;  // blockDim == F
  const int n0 = blockIdx.x * BM;
  for (int idx = threadIdx.x; idx < BM * K; idx += F) {
    int m = idx / K, k = idx - m * K;
    int nn = n0 + m;
    xs[m][k] = (nn < n) ? x[nn * K + k] : 0.f;
  }
  __syncthreads();
  float acc[BM];
#pragma unroll
  for (int m = 0; m < BM; ++m) acc[m] = 0.f;
  for (int k = 0; k < K; ++k) {
    float wv = w[k * F + f];
#pragma unroll
    for (int m = 0; m < BM; ++m) acc[m] += xs[m][k] * wv;
  }
  float bv = b[f];
#pragma unroll
  for (int m = 0; m < BM; ++m) {
    int nn = n0 + m;
    if (nn < n) out[nn * F + f] = acc[m] + bv;
  }
}

// -------- s/d for BOTH relations in one pass over h --------
template <int F, int D>
__global__ void sd2_kernel(const float* __restrict__ h,
                           const float* __restrict__ as0, const float* __restrict__ ad0,
                           const float* __restrict__ as1, const float* __restrict__ ad1,
                           float* __restrict__ s0, float* __restrict__ d0,
                           float* __restrict__ s1, float* __restrict__ d1, int n) {
  int nn = blockIdx.x;
  int f = threadIdx.x;  // blockDim == F
  float hv = h[nn * F + f];
  float v0 = hv * as0[f], w0 = hv * ad0[f];
  float v1 = hv * as1[f], w1 = hv * ad1[f];
#pragma unroll
  for (int off = D / 2; off > 0; off >>= 1) {
    v0 += __shfl_xor(v0, off, D);
    w0 += __shfl_xor(w0, off, D);
    v1 += __shfl_xor(v1, off, D);
    w1 += __shfl_xor(w1, off, D);
  }
  if ((f % D) == 0) {
    int idx = nn * NHEAD + f / D;
    s0[idx] = v0; d0[idx] = w0;
    s1[idx] = v1; d1[idx] = w1;
  }
}

// ---- fused: per dst node, inline softmax (exp+denom) + weighted gather + relu ----
template <int F, int D>
__global__ void message_kernel(const float* __restrict__ h, const int* __restrict__ ei,
                               const int* __restrict__ rp, const int* __restrict__ col,
                               const float* __restrict__ s, const float* __restrict__ d,
                               float* __restrict__ out, int n, int E) {
  int nn = blockIdx.x;
  int f = threadIdx.x;  // blockDim == F
  int hh = f / D;
  int lo = rp[nn], hi = rp[nn + 1];
  float dv = d[nn * NHEAD + hh];
  float acc = 0.f, den = 0.f;
  for (int j = lo; j < hi; ++j) {
    int e = col[j];
    int src = ei[e];
    float a = s[src * NHEAD + hh] + dv;
    a = (a >= 0.f) ? a : 0.2f * a;
    float v = __expf(a);  // segment_max skipped: cancels in softmax, alpha is O(1)
    den += v;
    acc += h[src * F + f] * v;
  }
  out[nn * F + f] = fmaxf(acc / (den + 1e-16f), 0.f);
}

// ---------------- wsum[f] += sum_m tanh( st[m] @ klw[:,f] + klb[f] ) ----------------
template <int F, int BM>
__global__ void semantic_w_kernel(const float* __restrict__ st, const float* __restrict__ klw,
                                  const float* __restrict__ klb, float* __restrict__ wsum,
                                  int n) {
  __shared__ float xs[BM][F];
  const int f = threadIdx.x;  // blockDim == F
  const int n0 = blockIdx.x * BM;
#pragma unroll
  for (int m = 0; m < BM; ++m) {
    int nn = n0 + m;
    xs[m][f] = (nn < n) ? st[nn * F + f] : 0.f;
  }
  __syncthreads();
  float acc[BM];
#pragma unroll
  for (int m = 0; m < BM; ++m) acc[m] = 0.f;
  for (int k = 0; k < F; ++k) {
    float wv = klw[k * F + f];
#pragma unroll
    for (int m = 0; m < BM; ++m) acc[m] += xs[m][k] * wv;
  }
  float bv = klb[f];
  float part = 0.f;
  int rem = n - n0;
#pragma unroll
  for (int m = 0; m < BM; ++m)
    if (m < rem) part += fast_tanh(acc[m] + bv);
  atomicAdd(&wsum[f], part);
}

// ---------------- attn = softmax_r( mean_w_r . q ) ----------------
template <int F>
__global__ void attn_kernel(const float* __restrict__ wsum, const float* __restrict__ q,
                            float* __restrict__ attn, float inv_n) {
  __shared__ float red[2][F / 64];
  int f = threadIdx.x;
  float qv = q[f];
  float v0 = wsum[f] * inv_n * qv;
  float v1 = wsum[F + f] * inv_n * qv;
#pragma unroll
  for (int off = 32; off > 0; off >>= 1) {
    v0 += __shfl_down(v0, off, 64);
    v1 += __shfl_down(v1, off, 64);
  }
  int w = f / 64;
  if ((f & 63) == 0) { red[0][w] = v0; red[1][w] = v1; }
  __syncthreads();
  if (f == 0) {
    float d0 = 0.f, d1 = 0.f;
#pragma unroll
    for (int i = 0; i < F / 64; ++i) { d0 += red[0][i]; d1 += red[1][i]; }
    float m = fmaxf(d0, d1);
    float e0 = expf(d0 - m), e1 = expf(d1 - m);
    float inv = 1.f / (e0 + e1);
    attn[0] = e0 * inv;
    attn[1] = e1 * inv;
  }
}

// ---------------- out = attn0*st0 + attn1*st1 ----------------
__global__ void combine_kernel(const float* __restrict__ st0, const float* __restrict__ st1,
                               const float* __restrict__ attn, float* __restrict__ out,
                               int total4) {
  float a0 = attn[0], a1 = attn[1];
  int i = blockIdx.x * blockDim.x + threadIdx.x;
  for (; i < total4; i += gridDim.x * blockDim.x) {
    float4 v0 = ((const float4*)st0)[i];
    float4 v1 = ((const float4*)st1)[i];
    float4 o;
    o.x = a0 * v0.x + a1 * v1.x;
    o.y = a0 * v0.y + a1 * v1.y;
    o.z = a0 * v0.z + a1 * v1.z;
    o.w = a0 * v0.w + a1 * v1.w;
    ((float4*)out)[i] = o;
  }
}

// ---------------- graph mean pool (batch sorted): chunked partial sums ----------------
#define PCH 256
__global__ void pool_partial_kernel(const float* __restrict__ h, const int* __restrict__ batch,
                                    float* __restrict__ psum, int n) {
  int c0 = blockIdx.x * PCH;
  int f = threadIdx.x;  // 128
  int end = min(c0 + PCH, n);
  if (c0 >= n) return;
  int g_cur = batch[c0];
  float acc = 0.f;
  for (int nn = c0; nn < end; ++nn) {
    int g = batch[nn];
    if (g != g_cur) {
      atomicAdd(&psum[g_cur * 128 + f], acc);
      acc = 0.f;
      g_cur = g;
    }
    acc += h[nn * 128 + f];
  }
  atomicAdd(&psum[g_cur * 128 + f], acc);
}

__device__ __forceinline__ int lower_bound_i(const int* a, int n, int key) {
  int lo = 0, hi = n;
  while (lo < hi) {
    int mid = (lo + hi) >> 1;
    if (a[mid] < key) lo = mid + 1; else hi = mid;
  }
  return lo;
}

__global__ void pool_final_kernel(const float* __restrict__ psum, const int* __restrict__ batch,
                                  float* __restrict__ pooled, int n) {
  int g = blockIdx.x;   // G blocks
  int f = threadIdx.x;  // 128
  int lo = lower_bound_i(batch, n, g);
  int hi = lower_bound_i(batch, n, g + 1);
  float cnt = fmaxf((float)(hi - lo), 1.f);
  pooled[g * 128 + f] = psum[g * 128 + f] / cnt;
}

// ---------------- MLP head ----------------
__global__ void head_kernel(const float* __restrict__ pooled, const float* __restrict__ d1w,
                            const float* __restrict__ d1b, const float* __restrict__ gamma,
                            const float* __restrict__ beta, const float* __restrict__ mean,
                            const float* __restrict__ var, const float* __restrict__ d2w,
                            const float* __restrict__ d2b, float* __restrict__ out) {
  int g = blockIdx.x;   // G blocks
  int j = threadIdx.x;  // 64 threads = 1 wave
  float acc = d1b[j];
  for (int k = 0; k < 128; ++k) acc += pooled[g * 128 + k] * d1w[k * 64 + j];
  float z = (acc - mean[j]) / sqrtf(var[j] + 1e-5f) * gamma[j] + beta[j];
  z = (z >= 0.f) ? z : 0.1f * z;
  float t = z * d2w[j];
#pragma unroll
  for (int off = 32; off > 0; off >>= 1) t += __shfl_down(t, off, 64);
  if (j == 0) out[g] = t + d2b[0];
}

// =====================================================================
template <int IN_, int F, int D>
static void run_layer(const float* x_in, const float* pw, const float* pb,
                      const float* as0, const float* ad0,
                      const float* as1, const float* ad1,
                      const float* klw, const float* klb, const float* q,
                      const int* ei0, const int* ei1,
                      const int* rp0, const int* col0,
                      const int* rp1, const int* col1,
                      float* h_buf, float* st0, float* st1,
                      float* s0, float* d0, float* s1, float* d1,
                      float* wsum, float* attn, float* out_buf,
                      int N, int E, hipStream_t stream) {
  constexpr int BM = 32;
  int nblk = (N + BM - 1) / BM;
  proj_kernel<IN_, F, BM><<<nblk, F, 0, stream>>>(x_in, pw, pb, h_buf, N);
  sd2_kernel<F, D><<<N, F, 0, stream>>>(h_buf, as0, ad0, as1, ad1, s0, d0, s1, d1, N);
  message_kernel<F, D><<<N, F, 0, stream>>>(h_buf, ei0, rp0, col0, s0, d0, st0, N, E);
  message_kernel<F, D><<<N, F, 0, stream>>>(h_buf, ei1, rp1, col1, s1, d1, st1, N, E);
  hipMemsetAsync(wsum, 0, 2 * F * sizeof(float), stream);
  semantic_w_kernel<F, BM><<<nblk, F, 0, stream>>>(st0, klw, klb, wsum, N);
  semantic_w_kernel<F, BM><<<nblk, F, 0, stream>>>(st1, klw, klb, wsum + F, N);
  attn_kernel<F><<<1, F, 0, stream>>>(wsum, q, attn, 1.0f / (float)N);
  combine_kernel<<<2048, 256, 0, stream>>>(st0, st1, attn, out_buf, N * F / 4);
}

extern "C" void kernel_launch(void* const* d_in, const int* in_sizes, int n_in,
                              void* d_out, int out_size, void* d_ws, size_t ws_size,
                              hipStream_t stream) {
  const float* x      = (const float*)d_in[0];
  const int* ei0      = (const int*)d_in[1];
  const int* ei1      = (const int*)d_in[2];
  const int* batch    = (const int*)d_in[3];
  const float* p1w    = (const float*)d_in[4];
  const float* p1b    = (const float*)d_in[5];
  const float* as1r0  = (const float*)d_in[6];
  const float* ad1r0  = (const float*)d_in[7];
  const float* as1r1  = (const float*)d_in[8];
  const float* ad1r1  = (const float*)d_in[9];
  const float* kl1w   = (const float*)d_in[10];
  const float* kl1b   = (const float*)d_in[11];
  const float* q1     = (const float*)d_in[12];
  const float* p2w    = (const float*)d_in[13];
  const float* p2b    = (const float*)d_in[14];
  const float* as2r0  = (const float*)d_in[15];
  const float* ad2r0  = (const float*)d_in[16];
  const float* as2r1  = (const float*)d_in[17];
  const float* ad2r1  = (const float*)d_in[18];
  const float* kl2w   = (const float*)d_in[19];
  const float* kl2b   = (const float*)d_in[20];
  const float* q2     = (const float*)d_in[21];
  const float* d1w    = (const float*)d_in[22];
  const float* d1b    = (const float*)d_in[23];
  const float* bng    = (const float*)d_in[24];
  const float* bnb    = (const float*)d_in[25];
  const float* bnm    = (const float*)d_in[26];
  const float* bnv    = (const float*)d_in[27];
  const float* d2w    = (const float*)d_in[28];
  const float* d2b    = (const float*)d_in[29];
  float* out = (float*)d_out;

  const int N = in_sizes[3];       // 50000
  const int E = in_sizes[1] / 2;   // 400000
  const int G = 64;

  // ---- workspace bump allocator ----
  char* p = (char*)d_ws;
  auto alloc = [&](size_t bytes) -> void* {
    void* r = (void*)p;
    p += (bytes + 255) & ~(size_t)255;
    return r;
  };
  int* rp0    = (int*)alloc((N + 1) * sizeof(int));
  int* col0   = (int*)alloc(E * sizeof(int));
  int* rp1    = (int*)alloc((N + 1) * sizeof(int));
  int* col1   = (int*)alloc(E * sizeof(int));
  int* tmp    = (int*)alloc(N * sizeof(int));
  int* incl   = (int*)alloc(N * sizeof(int));
  int* bsum   = (int*)alloc(256 * sizeof(int));
  float* h_buf  = (float*)alloc((size_t)N * 256 * sizeof(float));
  float* st0    = (float*)alloc((size_t)N * 256 * sizeof(float));
  float* st1    = (float*)alloc((size_t)N * 256 * sizeof(float));
  float* h2_buf = (float*)alloc((size_t)N * 128 * sizeof(float));
  float* s0     = (float*)alloc((size_t)N * NHEAD * sizeof(float));
  float* d0     = (float*)alloc((size_t)N * NHEAD * sizeof(float));
  float* s1     = (float*)alloc((size_t)N * NHEAD * sizeof(float));
  float* d1     = (float*)alloc((size_t)N * NHEAD * sizeof(float));
  float* wsum   = (float*)alloc(2 * 256 * sizeof(float));
  float* attn   = (float*)alloc(2 * sizeof(float));
  float* psum   = (float*)alloc((size_t)G * 128 * sizeof(float));
  float* pooled = (float*)alloc((size_t)G * 128 * sizeof(float));

  // ---- CSR build (dst-indexed), once, reused by both layers ----
  int eblk = (E + 255) / 256;
  int nb = (N + 255) / 256;  // scan chunks (196 <= 256)
  {
    hipMemsetAsync(tmp, 0, N * sizeof(int), stream);
    hist_kernel<<<eblk, 256, 0, stream>>>(ei0, E, tmp);
    scan_local_kernel<<<nb, 256, 0, stream>>>(tmp, incl, bsum, N);
    scan_bsum_kernel<<<1, 256, 0, stream>>>(bsum, nb);
    scan_fix_kernel<<<nb, 256, 0, stream>>>(incl, tmp, bsum, rp0, N, E);
    hipMemsetAsync(tmp, 0, N * sizeof(int), stream);
    scatter_kernel<<<eblk, 256, 0, stream>>>(ei0, E, rp0, tmp, col0);

    hipMemsetAsync(tmp, 0, N * sizeof(int), stream);
    hist_kernel<<<eblk, 256, 0, stream>>>(ei1, E, tmp);
    scan_local_kernel<<<nb, 256, 0, stream>>>(tmp, incl, bsum, N);
    scan_bsum_kernel<<<1, 256, 0, stream>>>(bsum, nb);
    scan_fix_kernel<<<nb, 256, 0, stream>>>(incl, tmp, bsum, rp1, N, E);
    hipMemsetAsync(tmp, 0, N * sizeof(int), stream);
    scatter_kernel<<<eblk, 256, 0, stream>>>(ei1, E, rp1, tmp, col1);
  }

  // ---- layer 1: 128 -> 256, D=64 ----
  run_layer<128, 256, 64>(x, p1w, p1b, as1r0, ad1r0, as1r1, ad1r1, kl1w, kl1b, q1,
                          ei0, ei1, rp0, col0, rp1, col1,
                          h_buf, st0, st1, s0, d0, s1, d1, wsum, attn,
                          /*out=*/h_buf, N, E, stream);

  // ---- layer 2: 256 -> 128, D=32 ----
  run_layer<256, 128, 32>(h_buf, p2w, p2b, as2r0, ad2r0, as2r1, ad2r1, kl2w, kl2b, q2,
                          ei0, ei1, rp0, col0, rp1, col1,
                          h2_buf, st0, st1, s0, d0, s1, d1, wsum, attn,
                          /*out=*/h2_buf, N, E, stream);

  // ---- pool + head ----
  hipMemsetAsync(psum, 0, (size_t)G * 128 * sizeof(float), stream);
  int pblk = (N + PCH - 1) / PCH;
  pool_partial_kernel<<<pblk, 128, 0, stream>>>(h2_buf, batch, psum, N);
  pool_final_kernel<<<G, 128, 0, stream>>>(psum, batch, pooled, N);
  head_kernel<<<G, 64, 0, stream>>>(pooled, d1w, d1b, bng, bnb, bnm, bnv, d2w, d2b, out);
}

// Round 3
// 1014.346 us; speedup vs baseline: 1.9744x; 1.7190x over previous
//
#include <hip/hip_runtime.h>
#include <math.h>

#define NHEAD 4

__device__ __forceinline__ float fast_tanh(float x) {
  x = fminf(fmaxf(x, -15.f), 15.f);
  float e = __expf(2.f * x);
  return (e - 1.f) / (e + 1.f);
}

// ---------------- CSR build (by dst), reused by both layers ----------------
__global__ void hist_kernel(const int* __restrict__ ei, int E, int* __restrict__ deg) {
  int i = blockIdx.x * blockDim.x + threadIdx.x;
  for (; i < E; i += gridDim.x * blockDim.x)
    atomicAdd(&deg[ei[E + i]], 1);
}

__global__ void scan_local_kernel(const int* __restrict__ deg, int* __restrict__ incl,
                                  int* __restrict__ bsum, int n) {
  __shared__ int tile[256];
  int i = blockIdx.x * 256 + threadIdx.x;
  int v = (i < n) ? deg[i] : 0;
  tile[threadIdx.x] = v;
  __syncthreads();
  for (int off = 1; off < 256; off <<= 1) {
    int t = (threadIdx.x >= (unsigned)off) ? tile[threadIdx.x - off] : 0;
    __syncthreads();
    tile[threadIdx.x] += t;
    __syncthreads();
  }
  if (i < n) incl[i] = tile[threadIdx.x];
  if (threadIdx.x == 255) bsum[blockIdx.x] = tile[255];
}

__global__ void scan_bsum_kernel(int* __restrict__ bsum, int nb) {
  __shared__ int tile[256];
  int v = (threadIdx.x < (unsigned)nb) ? bsum[threadIdx.x] : 0;
  tile[threadIdx.x] = v;
  __syncthreads();
  for (int off = 1; off < 256; off <<= 1) {
    int t = (threadIdx.x >= (unsigned)off) ? tile[threadIdx.x - off] : 0;
    __syncthreads();
    tile[threadIdx.x] += t;
    __syncthreads();
  }
  if (threadIdx.x < (unsigned)nb) bsum[threadIdx.x] = tile[threadIdx.x] - v;
}

__global__ void scan_fix_kernel(const int* __restrict__ incl, const int* __restrict__ deg,
                                const int* __restrict__ bsum, int* __restrict__ rp,
                                int n, int E) {
  int i = blockIdx.x * 256 + threadIdx.x;
  if (i < n) rp[i] = incl[i] - deg[i] + bsum[blockIdx.x];
  if (i == 0) rp[n] = E;
}

__global__ void scatter_kernel(const int* __restrict__ ei, int E,
                               const int* __restrict__ rp, int* __restrict__ cur,
                               int* __restrict__ col) {
  int i = blockIdx.x * blockDim.x + threadIdx.x;
  for (; i < E; i += gridDim.x * blockDim.x) {
    int dst = ei[E + i];
    int pos = rp[dst] + atomicAdd(&cur[dst], 1);
    col[pos] = i;
  }
}

// =============== register-tiled GEMM core: 64x64 tile, 4x4/thread ===============
// A: [M,K] row-major, W: [K,F] row-major. As stored k-major ([k][row], pad 68).
#define GEMM_BODY(K, F)                                                              \
  __shared__ float As[16][68];                                                       \
  __shared__ float Bs[16][64];                                                       \
  const int tid = threadIdx.x;                                                       \
  const int tx = tid & 15, ty = tid >> 4;                                            \
  const int m0 = blockIdx.x * 64;                                                    \
  const int n0 = blockIdx.y * 64;                                                    \
  const int ar = tid >> 2;                                                           \
  const int ak = (tid & 3) * 4;                                                      \
  const int bk = tid >> 4;                                                           \
  const int bc = (tid & 15) * 4;                                                     \
  float acc[4][4] = {};                                                              \
  for (int k0 = 0; k0 < K; k0 += 16) {                                               \
    float4 av = make_float4(0.f, 0.f, 0.f, 0.f);                                     \
    int row = m0 + ar;                                                               \
    if (row < M) av = *(const float4*)&A[(size_t)row * K + k0 + ak];                 \
    float4 wv = *(const float4*)&W[(size_t)(k0 + bk) * F + n0 + bc];                 \
    __syncthreads();                                                                 \
    As[ak + 0][ar] = av.x;                                                           \
    As[ak + 1][ar] = av.y;                                                           \
    As[ak + 2][ar] = av.z;                                                           \
    As[ak + 3][ar] = av.w;                                                           \
    *(float4*)&Bs[bk][bc] = wv;                                                      \
    __syncthreads();                                                                 \
    _Pragma("unroll") for (int kk = 0; kk < 16; ++kk) {                              \
      float4 a = *(const float4*)&As[kk][ty * 4];                                    \
      float4 b = *(const float4*)&Bs[kk][tx * 4];                                    \
      acc[0][0] += a.x * b.x; acc[0][1] += a.x * b.y;                                \
      acc[0][2] += a.x * b.z; acc[0][3] += a.x * b.w;                                \
      acc[1][0] += a.y * b.x; acc[1][1] += a.y * b.y;                                \
      acc[1][2] += a.y * b.z; acc[1][3] += a.y * b.w;                                \
      acc[2][0] += a.z * b.x; acc[2][1] += a.z * b.y;                                \
      acc[2][2] += a.z * b.z; acc[2][3] += a.z * b.w;                                \
      acc[3][0] += a.w * b.x; acc[3][1] += a.w * b.y;                                \
      acc[3][2] += a.w * b.z; acc[3][3] += a.w * b.w;                                \
    }                                                                                \
  }

// out[m][f] = A@W + bias
template <int K, int F>
__global__ __launch_bounds__(256) void gemm_bias_kernel(
    const float* __restrict__ A, const float* __restrict__ W,
    const float* __restrict__ bias, float* __restrict__ out, int M) {
  GEMM_BODY(K, F)
  float4 bv = *(const float4*)&bias[n0 + tx * 4];
#pragma unroll
  for (int i = 0; i < 4; ++i) {
    int row = m0 + ty * 4 + i;
    if (row < M) {
      float4 o;
      o.x = acc[i][0] + bv.x;
      o.y = acc[i][1] + bv.y;
      o.z = acc[i][2] + bv.z;
      o.w = acc[i][3] + bv.w;
      *(float4*)&out[(size_t)row * F + n0 + tx * 4] = o;
    }
  }
}

// wsum[f] += sum_rows tanh(A@W + bias)
template <int K, int F>
__global__ __launch_bounds__(256) void gemm_tanh_kernel(
    const float* __restrict__ A, const float* __restrict__ W,
    const float* __restrict__ bias, float* __restrict__ wsum, int M) {
  GEMM_BODY(K, F)
  __shared__ float sh[64];
  float4 bv = *(const float4*)&bias[n0 + tx * 4];
  float colsum[4] = {0.f, 0.f, 0.f, 0.f};
#pragma unroll
  for (int i = 0; i < 4; ++i) {
    int row = m0 + ty * 4 + i;
    if (row < M) {
      colsum[0] += fast_tanh(acc[i][0] + bv.x);
      colsum[1] += fast_tanh(acc[i][1] + bv.y);
      colsum[2] += fast_tanh(acc[i][2] + bv.z);
      colsum[3] += fast_tanh(acc[i][3] + bv.w);
    }
  }
#pragma unroll
  for (int j = 0; j < 4; ++j) {
    colsum[j] += __shfl_xor(colsum[j], 16, 64);
    colsum[j] += __shfl_xor(colsum[j], 32, 64);
  }
  __syncthreads();
  if (tid < 64) sh[tid] = 0.f;
  __syncthreads();
  if ((tid & 63) < 16) {
#pragma unroll
    for (int j = 0; j < 4; ++j) atomicAdd(&sh[tx * 4 + j], colsum[j]);
  }
  __syncthreads();
  if (tid < 64) atomicAdd(&wsum[n0 + tid], sh[tid]);
}

// -------- s/d for BOTH relations in one pass over h --------
template <int F, int D>
__global__ void sd2_kernel(const float* __restrict__ h,
                           const float* __restrict__ as0, const float* __restrict__ ad0,
                           const float* __restrict__ as1, const float* __restrict__ ad1,
                           float* __restrict__ s0, float* __restrict__ d0,
                           float* __restrict__ s1, float* __restrict__ d1, int n) {
  int nn = blockIdx.x;
  int f = threadIdx.x;  // blockDim == F
  float hv = h[(size_t)nn * F + f];
  float v0 = hv * as0[f], w0 = hv * ad0[f];
  float v1 = hv * as1[f], w1 = hv * ad1[f];
#pragma unroll
  for (int off = D / 2; off > 0; off >>= 1) {
    v0 += __shfl_xor(v0, off, D);
    w0 += __shfl_xor(w0, off, D);
    v1 += __shfl_xor(v1, off, D);
    w1 += __shfl_xor(w1, off, D);
  }
  if ((f % D) == 0) {
    int idx = nn * NHEAD + f / D;
    s0[idx] = v0; d0[idx] = w0;
    s1[idx] = v1; d1[idx] = w1;
  }
}

// ---- fused per-dst softmax + weighted gather + relu; wave-per-node, float4 ----
template <int F, int D>
__global__ void message_kernel(const float* __restrict__ h, const int* __restrict__ ei,
                               const int* __restrict__ rp, const int* __restrict__ col,
                               const float* __restrict__ s, const float* __restrict__ d,
                               float* __restrict__ out, int N, int E) {
  constexpr int VEC = F / 64;
  int w = threadIdx.x >> 6;
  int lane = threadIdx.x & 63;
  int nn = blockIdx.x * 4 + w;
  if (nn >= N) return;
  int f0 = lane * VEC;
  int hh = f0 / D;
  float dv = d[nn * NHEAD + hh];
  int lo = rp[nn], hi = rp[nn + 1];
  float acc[VEC];
#pragma unroll
  for (int v = 0; v < VEC; ++v) acc[v] = 0.f;
  float den = 0.f;
  for (int j = lo; j < hi; ++j) {
    int e = col[j];
    int src = ei[e];
    float a = s[src * NHEAD + hh] + dv;
    a = (a >= 0.f) ? a : 0.2f * a;
    float v = __expf(a);  // segment_max skipped: cancels in softmax, alpha is O(1)
    den += v;
    const float* hp = &h[(size_t)src * F + f0];
    if constexpr (VEC == 4) {
      float4 hv = *(const float4*)hp;
      acc[0] += v * hv.x; acc[1] += v * hv.y;
      acc[2] += v * hv.z; acc[3] += v * hv.w;
    } else {
      float2 hv = *(const float2*)hp;
      acc[0] += v * hv.x; acc[1] += v * hv.y;
    }
  }
  float inv = 1.f / (den + 1e-16f);
  float* op = &out[(size_t)nn * F + f0];
  if constexpr (VEC == 4) {
    float4 o;
    o.x = fmaxf(acc[0] * inv, 0.f);
    o.y = fmaxf(acc[1] * inv, 0.f);
    o.z = fmaxf(acc[2] * inv, 0.f);
    o.w = fmaxf(acc[3] * inv, 0.f);
    *(float4*)op = o;
  } else {
    float2 o;
    o.x = fmaxf(acc[0] * inv, 0.f);
    o.y = fmaxf(acc[1] * inv, 0.f);
    *(float2*)op = o;
  }
}

// ---------------- attn = softmax_r( mean_w_r . q ) ----------------
template <int F>
__global__ void attn_kernel(const float* __restrict__ wsum, const float* __restrict__ q,
                            float* __restrict__ attn, float inv_n) {
  __shared__ float red[2][F / 64];
  int f = threadIdx.x;
  float qv = q[f];
  float v0 = wsum[f] * inv_n * qv;
  float v1 = wsum[F + f] * inv_n * qv;
#pragma unroll
  for (int off = 32; off > 0; off >>= 1) {
    v0 += __shfl_down(v0, off, 64);
    v1 += __shfl_down(v1, off, 64);
  }
  int w = f / 64;
  if ((f & 63) == 0) { red[0][w] = v0; red[1][w] = v1; }
  __syncthreads();
  if (f == 0) {
    float d0 = 0.f, d1 = 0.f;
#pragma unroll
    for (int i = 0; i < F / 64; ++i) { d0 += red[0][i]; d1 += red[1][i]; }
    float m = fmaxf(d0, d1);
    float e0 = expf(d0 - m), e1 = expf(d1 - m);
    float inv = 1.f / (e0 + e1);
    attn[0] = e0 * inv;
    attn[1] = e1 * inv;
  }
}

// ---------------- out = attn0*st0 + attn1*st1 ----------------
__global__ void combine_kernel(const float* __restrict__ st0, const float* __restrict__ st1,
                               const float* __restrict__ attn, float* __restrict__ out,
                               int total4) {
  float a0 = attn[0], a1 = attn[1];
  int i = blockIdx.x * blockDim.x + threadIdx.x;
  for (; i < total4; i += gridDim.x * blockDim.x) {
    float4 v0 = ((const float4*)st0)[i];
    float4 v1 = ((const float4*)st1)[i];
    float4 o;
    o.x = a0 * v0.x + a1 * v1.x;
    o.y = a0 * v0.y + a1 * v1.y;
    o.z = a0 * v0.z + a1 * v1.z;
    o.w = a0 * v0.w + a1 * v1.w;
    ((float4*)out)[i] = o;
  }
}

// ---------------- graph mean pool (batch sorted): chunked partial sums ----------------
#define PCH 256
__global__ void pool_partial_kernel(const float* __restrict__ h, const int* __restrict__ batch,
                                    float* __restrict__ psum, int n) {
  int c0 = blockIdx.x * PCH;
  int f = threadIdx.x;  // 128
  int end = min(c0 + PCH, n);
  if (c0 >= n) return;
  int g_cur = batch[c0];
  float acc = 0.f;
  for (int nn = c0; nn < end; ++nn) {
    int g = batch[nn];
    if (g != g_cur) {
      atomicAdd(&psum[g_cur * 128 + f], acc);
      acc = 0.f;
      g_cur = g;
    }
    acc += h[(size_t)nn * 128 + f];
  }
  atomicAdd(&psum[g_cur * 128 + f], acc);
}

__device__ __forceinline__ int lower_bound_i(const int* a, int n, int key) {
  int lo = 0, hi = n;
  while (lo < hi) {
    int mid = (lo + hi) >> 1;
    if (a[mid] < key) lo = mid + 1; else hi = mid;
  }
  return lo;
}

__global__ void pool_final_kernel(const float* __restrict__ psum, const int* __restrict__ batch,
                                  float* __restrict__ pooled, int n) {
  int g = blockIdx.x;
  int f = threadIdx.x;
  int lo = lower_bound_i(batch, n, g);
  int hi = lower_bound_i(batch, n, g + 1);
  float cnt = fmaxf((float)(hi - lo), 1.f);
  pooled[g * 128 + f] = psum[g * 128 + f] / cnt;
}

// ---------------- MLP head ----------------
__global__ void head_kernel(const float* __restrict__ pooled, const float* __restrict__ d1w,
                            const float* __restrict__ d1b, const float* __restrict__ gamma,
                            const float* __restrict__ beta, const float* __restrict__ mean,
                            const float* __restrict__ var, const float* __restrict__ d2w,
                            const float* __restrict__ d2b, float* __restrict__ out) {
  int g = blockIdx.x;
  int j = threadIdx.x;  // 64 = 1 wave
  float acc = d1b[j];
  for (int k = 0; k < 128; ++k) acc += pooled[g * 128 + k] * d1w[k * 64 + j];
  float z = (acc - mean[j]) / sqrtf(var[j] + 1e-5f) * gamma[j] + beta[j];
  z = (z >= 0.f) ? z : 0.1f * z;
  float t = z * d2w[j];
#pragma unroll
  for (int off = 32; off > 0; off >>= 1) t += __shfl_down(t, off, 64);
  if (j == 0) out[g] = t + d2b[0];
}

// =====================================================================
template <int IN_, int F, int D>
static void run_layer(const float* x_in, const float* pw, const float* pb,
                      const float* as0, const float* ad0,
                      const float* as1, const float* ad1,
                      const float* klw, const float* klb, const float* q,
                      const int* ei0, const int* ei1,
                      const int* rp0, const int* col0,
                      const int* rp1, const int* col1,
                      float* h_buf, float* st0, float* st1,
                      float* s0, float* d0, float* s1, float* d1,
                      float* wsum, float* attn, float* out_buf,
                      int N, int E, hipStream_t stream) {
  dim3 ggrid((N + 63) / 64, F / 64);
  gemm_bias_kernel<IN_, F><<<ggrid, 256, 0, stream>>>(x_in, pw, pb, h_buf, N);
  sd2_kernel<F, D><<<N, F, 0, stream>>>(h_buf, as0, ad0, as1, ad1, s0, d0, s1, d1, N);
  int mblk = (N + 3) / 4;
  message_kernel<F, D><<<mblk, 256, 0, stream>>>(h_buf, ei0, rp0, col0, s0, d0, st0, N, E);
  message_kernel<F, D><<<mblk, 256, 0, stream>>>(h_buf, ei1, rp1, col1, s1, d1, st1, N, E);
  hipMemsetAsync(wsum, 0, 2 * F * sizeof(float), stream);
  gemm_tanh_kernel<F, F><<<ggrid, 256, 0, stream>>>(st0, klw, klb, wsum, N);
  gemm_tanh_kernel<F, F><<<ggrid, 256, 0, stream>>>(st1, klw, klb, wsum + F, N);
  attn_kernel<F><<<1, F, 0, stream>>>(wsum, q, attn, 1.0f / (float)N);
  combine_kernel<<<2048, 256, 0, stream>>>(st0, st1, attn, out_buf, N * F / 4);
}

extern "C" void kernel_launch(void* const* d_in, const int* in_sizes, int n_in,
                              void* d_out, int out_size, void* d_ws, size_t ws_size,
                              hipStream_t stream) {
  const float* x      = (const float*)d_in[0];
  const int* ei0      = (const int*)d_in[1];
  const int* ei1      = (const int*)d_in[2];
  const int* batch    = (const int*)d_in[3];
  const float* p1w    = (const float*)d_in[4];
  const float* p1b    = (const float*)d_in[5];
  const float* as1r0  = (const float*)d_in[6];
  const float* ad1r0  = (const float*)d_in[7];
  const float* as1r1  = (const float*)d_in[8];
  const float* ad1r1  = (const float*)d_in[9];
  const float* kl1w   = (const float*)d_in[10];
  const float* kl1b   = (const float*)d_in[11];
  const float* q1     = (const float*)d_in[12];
  const float* p2w    = (const float*)d_in[13];
  const float* p2b    = (const float*)d_in[14];
  const float* as2r0  = (const float*)d_in[15];
  const float* ad2r0  = (const float*)d_in[16];
  const float* as2r1  = (const float*)d_in[17];
  const float* ad2r1  = (const float*)d_in[18];
  const float* kl2w   = (const float*)d_in[19];
  const float* kl2b   = (const float*)d_in[20];
  const float* q2     = (const float*)d_in[21];
  const float* d1w    = (const float*)d_in[22];
  const float* d1b    = (const float*)d_in[23];
  const float* bng    = (const float*)d_in[24];
  const float* bnb    = (const float*)d_in[25];
  const float* bnm    = (const float*)d_in[26];
  const float* bnv    = (const float*)d_in[27];
  const float* d2w    = (const float*)d_in[28];
  const float* d2b    = (const float*)d_in[29];
  float* out = (float*)d_out;

  const int N = in_sizes[3];       // 50000
  const int E = in_sizes[1] / 2;   // 400000
  const int G = 64;

  char* p = (char*)d_ws;
  auto alloc = [&](size_t bytes) -> void* {
    void* r = (void*)p;
    p += (bytes + 255) & ~(size_t)255;
    return r;
  };
  int* rp0    = (int*)alloc((N + 1) * sizeof(int));
  int* col0   = (int*)alloc(E * sizeof(int));
  int* rp1    = (int*)alloc((N + 1) * sizeof(int));
  int* col1   = (int*)alloc(E * sizeof(int));
  int* tmp    = (int*)alloc(N * sizeof(int));
  int* incl   = (int*)alloc(N * sizeof(int));
  int* bsum   = (int*)alloc(256 * sizeof(int));
  float* h_buf  = (float*)alloc((size_t)N * 256 * sizeof(float));
  float* st0    = (float*)alloc((size_t)N * 256 * sizeof(float));
  float* st1    = (float*)alloc((size_t)N * 256 * sizeof(float));
  float* h2_buf = (float*)alloc((size_t)N * 128 * sizeof(float));
  float* s0     = (float*)alloc((size_t)N * NHEAD * sizeof(float));
  float* d0     = (float*)alloc((size_t)N * NHEAD * sizeof(float));
  float* s1     = (float*)alloc((size_t)N * NHEAD * sizeof(float));
  float* d1     = (float*)alloc((size_t)N * NHEAD * sizeof(float));
  float* wsum   = (float*)alloc(2 * 256 * sizeof(float));
  float* attn   = (float*)alloc(2 * sizeof(float));
  float* psum   = (float*)alloc((size_t)G * 128 * sizeof(float));
  float* pooled = (float*)alloc((size_t)G * 128 * sizeof(float));

  int eblk = (E + 255) / 256;
  int nb = (N + 255) / 256;
  {
    hipMemsetAsync(tmp, 0, N * sizeof(int), stream);
    hist_kernel<<<eblk, 256, 0, stream>>>(ei0, E, tmp);
    scan_local_kernel<<<nb, 256, 0, stream>>>(tmp, incl, bsum, N);
    scan_bsum_kernel<<<1, 256, 0, stream>>>(bsum, nb);
    scan_fix_kernel<<<nb, 256, 0, stream>>>(incl, tmp, bsum, rp0, N, E);
    hipMemsetAsync(tmp, 0, N * sizeof(int), stream);
    scatter_kernel<<<eblk, 256, 0, stream>>>(ei0, E, rp0, tmp, col0);

    hipMemsetAsync(tmp, 0, N * sizeof(int), stream);
    hist_kernel<<<eblk, 256, 0, stream>>>(ei1, E, tmp);
    scan_local_kernel<<<nb, 256, 0, stream>>>(tmp, incl, bsum, N);
    scan_bsum_kernel<<<1, 256, 0, stream>>>(bsum, nb);
    scan_fix_kernel<<<nb, 256, 0, stream>>>(incl, tmp, bsum, rp1, N, E);
    hipMemsetAsync(tmp, 0, N * sizeof(int), stream);
    scatter_kernel<<<eblk, 256, 0, stream>>>(ei1, E, rp1, tmp, col1);
  }

  run_layer<128, 256, 64>(x, p1w, p1b, as1r0, ad1r0, as1r1, ad1r1, kl1w, kl1b, q1,
                          ei0, ei1, rp0, col0, rp1, col1,
                          h_buf, st0, st1, s0, d0, s1, d1, wsum, attn,
                          /*out=*/h_buf, N, E, stream);

  run_layer<256, 128, 32>(h_buf, p2w, p2b, as2r0, ad2r0, as2r1, ad2r1, kl2w, kl2b, q2,
                          ei0, ei1, rp0, col0, rp1, col1,
                          h2_buf, st0, st1, s0, d0, s1, d1, wsum, attn,
                          /*out=*/h2_buf, N, E, stream);

  hipMemsetAsync(psum, 0, (size_t)G * 128 * sizeof(float), stream);
  int pblk = (N + PCH - 1) / PCH;
  pool_partial_kernel<<<pblk, 128, 0, stream>>>(h2_buf, batch, psum, N);
  pool_final_kernel<<<G, 128, 0, stream>>>(psum, batch, pooled, N);
  head_kernel<<<G, 64, 0, stream>>>(pooled, d1w, d1b, bng, bnb, bnm, bnv, d2w, d2b, out);
}

// Round 4
// 845.446 us; speedup vs baseline: 2.3689x; 1.1998x over previous
//
#include <hip/hip_runtime.h>
#include <math.h>

#define NHEAD 4

typedef __bf16 bf16x8 __attribute__((ext_vector_type(8)));
typedef float f32x4 __attribute__((ext_vector_type(4)));

__device__ __forceinline__ unsigned short f2bf(float f) {
  unsigned int u = __float_as_uint(f);
  u += 0x7FFF + ((u >> 16) & 1);  // round-to-nearest-even
  return (unsigned short)(u >> 16);
}
__device__ __forceinline__ float bf2f(unsigned short s) {
  return __uint_as_float(((unsigned int)s) << 16);
}

__device__ __forceinline__ float fast_tanh(float x) {
  x = fminf(fmaxf(x, -15.f), 15.f);
  float e = __expf(2.f * x);
  return (e - 1.f) / (e + 1.f);
}

// ---------------- CSR build (by dst), reused by both layers ----------------
__global__ void hist_kernel(const int* __restrict__ ei, int E, int* __restrict__ deg) {
  int i = blockIdx.x * blockDim.x + threadIdx.x;
  for (; i < E; i += gridDim.x * blockDim.x)
    atomicAdd(&deg[ei[E + i]], 1);
}

__global__ void scan_local_kernel(const int* __restrict__ deg, int* __restrict__ incl,
                                  int* __restrict__ bsum, int n) {
  __shared__ int tile[256];
  int i = blockIdx.x * 256 + threadIdx.x;
  int v = (i < n) ? deg[i] : 0;
  tile[threadIdx.x] = v;
  __syncthreads();
  for (int off = 1; off < 256; off <<= 1) {
    int t = (threadIdx.x >= (unsigned)off) ? tile[threadIdx.x - off] : 0;
    __syncthreads();
    tile[threadIdx.x] += t;
    __syncthreads();
  }
  if (i < n) incl[i] = tile[threadIdx.x];
  if (threadIdx.x == 255) bsum[blockIdx.x] = tile[255];
}

__global__ void scan_bsum_kernel(int* __restrict__ bsum, int nb) {
  __shared__ int tile[256];
  int v = (threadIdx.x < (unsigned)nb) ? bsum[threadIdx.x] : 0;
  tile[threadIdx.x] = v;
  __syncthreads();
  for (int off = 1; off < 256; off <<= 1) {
    int t = (threadIdx.x >= (unsigned)off) ? tile[threadIdx.x - off] : 0;
    __syncthreads();
    tile[threadIdx.x] += t;
    __syncthreads();
  }
  if (threadIdx.x < (unsigned)nb) bsum[threadIdx.x] = tile[threadIdx.x] - v;
}

__global__ void scan_fix_kernel(const int* __restrict__ incl, const int* __restrict__ deg,
                                const int* __restrict__ bsum, int* __restrict__ rp,
                                int n, int E) {
  int i = blockIdx.x * 256 + threadIdx.x;
  if (i < n) rp[i] = incl[i] - deg[i] + bsum[blockIdx.x];
  if (i == 0) rp[n] = E;
}

__global__ void scatter_kernel(const int* __restrict__ ei, int E,
                               const int* __restrict__ rp, int* __restrict__ cur,
                               int* __restrict__ col) {
  int i = blockIdx.x * blockDim.x + threadIdx.x;
  for (; i < E; i += gridDim.x * blockDim.x) {
    int dst = ei[E + i];
    int pos = rp[dst] + atomicAdd(&cur[dst], 1);
    col[pos] = i;
  }
}

// ---------------- conversions ----------------
__global__ void f2b_kernel(const float* __restrict__ in, unsigned short* __restrict__ out,
                           int total4) {
  int i = blockIdx.x * blockDim.x + threadIdx.x;
  for (; i < total4; i += gridDim.x * blockDim.x) {
    float4 v = ((const float4*)in)[i];
    uint2 o;
    o.x = (unsigned)f2bf(v.x) | ((unsigned)f2bf(v.y) << 16);
    o.y = (unsigned)f2bf(v.z) | ((unsigned)f2bf(v.w) << 16);
    ((uint2*)out)[i] = o;
  }
}

// Wt[f][k] = bf16(W[k][f])
__global__ void wtrans_kernel(const float* __restrict__ W, unsigned short* __restrict__ Wt,
                              int K, int F, int total) {
  int i = blockIdx.x * blockDim.x + threadIdx.x;
  if (i < total) {
    int k = i / F, f = i - k * F;
    Wt[(size_t)f * K + k] = f2bf(W[i]);
  }
}

// =============== MFMA GEMM: A[M,K]bf16 row-major @ W (as Wt[F,K]bf16) ===============
// 64 rows x F cols per block, 256 threads (4 waves), 16x16x32 bf16 MFMA.
// G = F/64 col-groups; S = 4/G row-splits; RT = 4/S row-tiles per wave.
#define MFMA_GEMM_CORE(K, F)                                                          \
  constexpr int G = F / 64, S = 4 / G, RT = 4 / S;                                    \
  __shared__ unsigned short As[64][40]; /* pad 40: banks spread, 16B aligned */       \
  const int tid = threadIdx.x;                                                        \
  const int lane = tid & 63, wid = tid >> 6;                                          \
  const int cg = wid % G, rg = wid / G;                                               \
  const int l15 = lane & 15, l4 = lane >> 4;                                          \
  const int m0 = blockIdx.x * 64;                                                     \
  const int wrow = rg * RT * 16;                                                      \
  f32x4 acc[RT][4];                                                                   \
  _Pragma("unroll") for (int rt = 0; rt < RT; ++rt)                                   \
  _Pragma("unroll") for (int ct = 0; ct < 4; ++ct)                                    \
      acc[rt][ct] = (f32x4){0.f, 0.f, 0.f, 0.f};                                      \
  const int arow = tid >> 2;                                                          \
  const int akk = (tid & 3) * 8;                                                      \
  for (int k0 = 0; k0 < K; k0 += 32) {                                                \
    uint4 av = {0u, 0u, 0u, 0u};                                                      \
    if (m0 + arow < M) av = *(const uint4*)&A[(size_t)(m0 + arow) * K + k0 + akk];    \
    __syncthreads();                                                                  \
    *(uint4*)&As[arow][akk] = av;                                                     \
    __syncthreads();                                                                  \
    bf16x8 bfr[4];                                                                    \
    _Pragma("unroll") for (int ct = 0; ct < 4; ++ct) {                                \
      int colx = cg * 64 + ct * 16 + l15;                                             \
      bfr[ct] = *(const bf16x8*)&Wt[(size_t)colx * K + k0 + l4 * 8];                  \
    }                                                                                 \
    _Pragma("unroll") for (int rt = 0; rt < RT; ++rt) {                               \
      bf16x8 afr = *(const bf16x8*)&As[wrow + rt * 16 + l15][l4 * 8];                 \
      _Pragma("unroll") for (int ct = 0; ct < 4; ++ct)                                \
        acc[rt][ct] = __builtin_amdgcn_mfma_f32_16x16x32_bf16(                        \
            afr, bfr[ct], acc[rt][ct], 0, 0, 0);                                      \
    }                                                                                 \
  }

// out[m][f] = bf16(A@W + bias)
template <int K, int F>
__global__ __launch_bounds__(256) void mfma_gemm_bias(
    const unsigned short* __restrict__ A, const unsigned short* __restrict__ Wt,
    const float* __restrict__ bias, unsigned short* __restrict__ out, int M) {
  MFMA_GEMM_CORE(K, F)
#pragma unroll
  for (int ct = 0; ct < 4; ++ct) {
    int n = cg * 64 + ct * 16 + l15;
    float bv = bias[n];
#pragma unroll
    for (int rt = 0; rt < RT; ++rt) {
#pragma unroll
      for (int r = 0; r < 4; ++r) {
        int m = m0 + wrow + rt * 16 + l4 * 4 + r;
        if (m < M) out[(size_t)m * F + n] = f2bf(acc[rt][ct][r] + bv);
      }
    }
  }
}

// wsum[f] += sum_rows tanh(A@W + bias)   (no N x F store)
template <int K, int F>
__global__ __launch_bounds__(256) void mfma_gemm_tanh(
    const unsigned short* __restrict__ A, const unsigned short* __restrict__ Wt,
    const float* __restrict__ bias, float* __restrict__ wsum, int M) {
  MFMA_GEMM_CORE(K, F)
#pragma unroll
  for (int ct = 0; ct < 4; ++ct) {
    int n = cg * 64 + ct * 16 + l15;
    float bv = bias[n];
    float cs = 0.f;
#pragma unroll
    for (int rt = 0; rt < RT; ++rt) {
#pragma unroll
      for (int r = 0; r < 4; ++r) {
        int m = m0 + wrow + rt * 16 + l4 * 4 + r;
        if (m < M) cs += fast_tanh(acc[rt][ct][r] + bv);
      }
    }
    cs += __shfl_xor(cs, 16, 64);
    cs += __shfl_xor(cs, 32, 64);
    if (l4 == 0) atomicAdd(&wsum[n], cs);
  }
}

// -------- s/d for BOTH relations in one pass over h (bf16) --------
template <int F, int D>
__global__ void sd2_kernel(const unsigned short* __restrict__ h,
                           const float* __restrict__ as0, const float* __restrict__ ad0,
                           const float* __restrict__ as1, const float* __restrict__ ad1,
                           float* __restrict__ s0, float* __restrict__ d0,
                           float* __restrict__ s1, float* __restrict__ d1, int n) {
  int nn = blockIdx.x;
  int f = threadIdx.x;  // blockDim == F
  float hv = bf2f(h[(size_t)nn * F + f]);
  float v0 = hv * as0[f], w0 = hv * ad0[f];
  float v1 = hv * as1[f], w1 = hv * ad1[f];
#pragma unroll
  for (int off = D / 2; off > 0; off >>= 1) {
    v0 += __shfl_xor(v0, off, D);
    w0 += __shfl_xor(w0, off, D);
    v1 += __shfl_xor(v1, off, D);
    w1 += __shfl_xor(w1, off, D);
  }
  if ((f % D) == 0) {
    int idx = nn * NHEAD + f / D;
    s0[idx] = v0; d0[idx] = w0;
    s1[idx] = v1; d1[idx] = w1;
  }
}

// ---- fused per-dst softmax + weighted gather + relu; wave-per-node, bf16 ----
template <int F, int D>
__global__ void message_kernel(const unsigned short* __restrict__ h,
                               const int* __restrict__ ei,
                               const int* __restrict__ rp, const int* __restrict__ col,
                               const float* __restrict__ s, const float* __restrict__ d,
                               unsigned short* __restrict__ out, int N, int E) {
  constexpr int VEC = F / 64;
  int w = threadIdx.x >> 6;
  int lane = threadIdx.x & 63;
  int nn = blockIdx.x * 4 + w;
  if (nn >= N) return;
  int f0 = lane * VEC;
  int hh = f0 / D;
  float dv = d[nn * NHEAD + hh];
  int lo = rp[nn], hi = rp[nn + 1];
  float acc[VEC];
#pragma unroll
  for (int v = 0; v < VEC; ++v) acc[v] = 0.f;
  float den = 0.f;
  for (int j = lo; j < hi; ++j) {
    int e = col[j];
    int src = ei[e];
    float a = s[src * NHEAD + hh] + dv;
    a = (a >= 0.f) ? a : 0.2f * a;
    float v = __expf(a);  // segment_max skipped: cancels in softmax, alpha is O(1)
    den += v;
    if constexpr (VEC == 4) {
      uint2 hv = *(const uint2*)&h[(size_t)src * F + f0];
      acc[0] += v * bf2f((unsigned short)(hv.x & 0xffff));
      acc[1] += v * bf2f((unsigned short)(hv.x >> 16));
      acc[2] += v * bf2f((unsigned short)(hv.y & 0xffff));
      acc[3] += v * bf2f((unsigned short)(hv.y >> 16));
    } else {
      unsigned int hv = *(const unsigned int*)&h[(size_t)src * F + f0];
      acc[0] += v * bf2f((unsigned short)(hv & 0xffff));
      acc[1] += v * bf2f((unsigned short)(hv >> 16));
    }
  }
  float inv = 1.f / (den + 1e-16f);
  if constexpr (VEC == 4) {
    uint2 o;
    o.x = (unsigned)f2bf(fmaxf(acc[0] * inv, 0.f)) |
          ((unsigned)f2bf(fmaxf(acc[1] * inv, 0.f)) << 16);
    o.y = (unsigned)f2bf(fmaxf(acc[2] * inv, 0.f)) |
          ((unsigned)f2bf(fmaxf(acc[3] * inv, 0.f)) << 16);
    *(uint2*)&out[(size_t)nn * F + f0] = o;
  } else {
    unsigned int o = (unsigned)f2bf(fmaxf(acc[0] * inv, 0.f)) |
                     ((unsigned)f2bf(fmaxf(acc[1] * inv, 0.f)) << 16);
    *(unsigned int*)&out[(size_t)nn * F + f0] = o;
  }
}

// ---------------- attn = softmax_r( mean_w_r . q ) ----------------
template <int F>
__global__ void attn_kernel(const float* __restrict__ wsum, const float* __restrict__ q,
                            float* __restrict__ attn, float inv_n) {
  __shared__ float red[2][F / 64];
  int f = threadIdx.x;
  float qv = q[f];
  float v0 = wsum[f] * inv_n * qv;
  float v1 = wsum[F + f] * inv_n * qv;
#pragma unroll
  for (int off = 32; off > 0; off >>= 1) {
    v0 += __shfl_down(v0, off, 64);
    v1 += __shfl_down(v1, off, 64);
  }
  int w = f / 64;
  if ((f & 63) == 0) { red[0][w] = v0; red[1][w] = v1; }
  __syncthreads();
  if (f == 0) {
    float d0 = 0.f, d1 = 0.f;
#pragma unroll
    for (int i = 0; i < F / 64; ++i) { d0 += red[0][i]; d1 += red[1][i]; }
    float m = fmaxf(d0, d1);
    float e0 = expf(d0 - m), e1 = expf(d1 - m);
    float inv = 1.f / (e0 + e1);
    attn[0] = e0 * inv;
    attn[1] = e1 * inv;
  }
}

// ---------------- out = attn0*st0 + attn1*st1 (bf16) ----------------
__device__ __forceinline__ unsigned int comb2(unsigned int p, unsigned int q,
                                              float a0, float a1) {
  float lo = a0 * bf2f((unsigned short)p) + a1 * bf2f((unsigned short)q);
  float hi = a0 * bf2f((unsigned short)(p >> 16)) + a1 * bf2f((unsigned short)(q >> 16));
  return (unsigned)f2bf(lo) | ((unsigned)f2bf(hi) << 16);
}

__global__ void combine_bf_kernel(const unsigned short* __restrict__ st0,
                                  const unsigned short* __restrict__ st1,
                                  const float* __restrict__ attn,
                                  unsigned short* __restrict__ out, int total4) {
  float a0 = attn[0], a1 = attn[1];
  int i = blockIdx.x * blockDim.x + threadIdx.x;
  for (; i < total4; i += gridDim.x * blockDim.x) {
    uint2 v0 = ((const uint2*)st0)[i];
    uint2 v1 = ((const uint2*)st1)[i];
    uint2 o;
    o.x = comb2(v0.x, v1.x, a0, a1);
    o.y = comb2(v0.y, v1.y, a0, a1);
    ((uint2*)out)[i] = o;
  }
}

// ---------------- graph mean pool (batch sorted): chunked partial sums ----------------
#define PCH 256
__global__ void pool_partial_kernel(const unsigned short* __restrict__ h,
                                    const int* __restrict__ batch,
                                    float* __restrict__ psum, int n) {
  int c0 = blockIdx.x * PCH;
  int f = threadIdx.x;  // 128
  int end = min(c0 + PCH, n);
  if (c0 >= n) return;
  int g_cur = batch[c0];
  float acc = 0.f;
  for (int nn = c0; nn < end; ++nn) {
    int g = batch[nn];
    if (g != g_cur) {
      atomicAdd(&psum[g_cur * 128 + f], acc);
      acc = 0.f;
      g_cur = g;
    }
    acc += bf2f(h[(size_t)nn * 128 + f]);
  }
  atomicAdd(&psum[g_cur * 128 + f], acc);
}

__device__ __forceinline__ int lower_bound_i(const int* a, int n, int key) {
  int lo = 0, hi = n;
  while (lo < hi) {
    int mid = (lo + hi) >> 1;
    if (a[mid] < key) lo = mid + 1; else hi = mid;
  }
  return lo;
}

__global__ void pool_final_kernel(const float* __restrict__ psum, const int* __restrict__ batch,
                                  float* __restrict__ pooled, int n) {
  int g = blockIdx.x;
  int f = threadIdx.x;
  int lo = lower_bound_i(batch, n, g);
  int hi = lower_bound_i(batch, n, g + 1);
  float cnt = fmaxf((float)(hi - lo), 1.f);
  pooled[g * 128 + f] = psum[g * 128 + f] / cnt;
}

// ---------------- MLP head ----------------
__global__ void head_kernel(const float* __restrict__ pooled, const float* __restrict__ d1w,
                            const float* __restrict__ d1b, const float* __restrict__ gamma,
                            const float* __restrict__ beta, const float* __restrict__ mean,
                            const float* __restrict__ var, const float* __restrict__ d2w,
                            const float* __restrict__ d2b, float* __restrict__ out) {
  int g = blockIdx.x;
  int j = threadIdx.x;  // 64 = 1 wave
  float acc = d1b[j];
  for (int k = 0; k < 128; ++k) acc += pooled[g * 128 + k] * d1w[k * 64 + j];
  float z = (acc - mean[j]) / sqrtf(var[j] + 1e-5f) * gamma[j] + beta[j];
  z = (z >= 0.f) ? z : 0.1f * z;
  float t = z * d2w[j];
#pragma unroll
  for (int off = 32; off > 0; off >>= 1) t += __shfl_down(t, off, 64);
  if (j == 0) out[g] = t + d2b[0];
}

// =====================================================================
template <int IN_, int F, int D>
static void run_layer(const unsigned short* x_bf, const unsigned short* pwt, const float* pb,
                      const float* as0, const float* ad0,
                      const float* as1, const float* ad1,
                      const unsigned short* klwt, const float* klb, const float* q,
                      const int* ei0, const int* ei1,
                      const int* rp0, const int* col0,
                      const int* rp1, const int* col1,
                      unsigned short* h_bf, unsigned short* st0, unsigned short* st1,
                      float* s0, float* d0, float* s1, float* d1,
                      float* wsum, float* attn, unsigned short* out_bf,
                      int N, int E, hipStream_t stream) {
  int gblk = (N + 63) / 64;
  mfma_gemm_bias<IN_, F><<<gblk, 256, 0, stream>>>(x_bf, pwt, pb, h_bf, N);
  sd2_kernel<F, D><<<N, F, 0, stream>>>(h_bf, as0, ad0, as1, ad1, s0, d0, s1, d1, N);
  int mblk = (N + 3) / 4;
  message_kernel<F, D><<<mblk, 256, 0, stream>>>(h_bf, ei0, rp0, col0, s0, d0, st0, N, E);
  message_kernel<F, D><<<mblk, 256, 0, stream>>>(h_bf, ei1, rp1, col1, s1, d1, st1, N, E);
  hipMemsetAsync(wsum, 0, 2 * F * sizeof(float), stream);
  mfma_gemm_tanh<F, F><<<gblk, 256, 0, stream>>>(st0, klwt, klb, wsum, N);
  mfma_gemm_tanh<F, F><<<gblk, 256, 0, stream>>>(st1, klwt, klb, wsum + F, N);
  attn_kernel<F><<<1, F, 0, stream>>>(wsum, q, attn, 1.0f / (float)N);
  combine_bf_kernel<<<2048, 256, 0, stream>>>(st0, st1, attn, out_bf, N * F / 4);
}

extern "C" void kernel_launch(void* const* d_in, const int* in_sizes, int n_in,
                              void* d_out, int out_size, void* d_ws, size_t ws_size,
                              hipStream_t stream) {
  const float* x      = (const float*)d_in[0];
  const int* ei0      = (const int*)d_in[1];
  const int* ei1      = (const int*)d_in[2];
  const int* batch    = (const int*)d_in[3];
  const float* p1w    = (const float*)d_in[4];
  const float* p1b    = (const float*)d_in[5];
  const float* as1r0  = (const float*)d_in[6];
  const float* ad1r0  = (const float*)d_in[7];
  const float* as1r1  = (const float*)d_in[8];
  const float* ad1r1  = (const float*)d_in[9];
  const float* kl1w   = (const float*)d_in[10];
  const float* kl1b   = (const float*)d_in[11];
  const float* q1     = (const float*)d_in[12];
  const float* p2w    = (const float*)d_in[13];
  const float* p2b    = (const float*)d_in[14];
  const float* as2r0  = (const float*)d_in[15];
  const float* ad2r0  = (const float*)d_in[16];
  const float* as2r1  = (const float*)d_in[17];
  const float* ad2r1  = (const float*)d_in[18];
  const float* kl2w   = (const float*)d_in[19];
  const float* kl2b   = (const float*)d_in[20];
  const float* q2     = (const float*)d_in[21];
  const float* d1w    = (const float*)d_in[22];
  const float* d1b    = (const float*)d_in[23];
  const float* bng    = (const float*)d_in[24];
  const float* bnb    = (const float*)d_in[25];
  const float* bnm    = (const float*)d_in[26];
  const float* bnv    = (const float*)d_in[27];
  const float* d2w    = (const float*)d_in[28];
  const float* d2b    = (const float*)d_in[29];
  float* out = (float*)d_out;

  const int N = in_sizes[3];       // 50000
  const int E = in_sizes[1] / 2;   // 400000
  const int G = 64;

  char* p = (char*)d_ws;
  auto alloc = [&](size_t bytes) -> void* {
    void* r = (void*)p;
    p += (bytes + 255) & ~(size_t)255;
    return r;
  };
  int* rp0    = (int*)alloc((N + 1) * sizeof(int));
  int* col0   = (int*)alloc(E * sizeof(int));
  int* rp1    = (int*)alloc((N + 1) * sizeof(int));
  int* col1   = (int*)alloc(E * sizeof(int));
  int* tmp    = (int*)alloc(N * sizeof(int));
  int* incl   = (int*)alloc(N * sizeof(int));
  int* bsum   = (int*)alloc(256 * sizeof(int));
  unsigned short* x_bf  = (unsigned short*)alloc((size_t)N * 128 * 2);
  unsigned short* h_bf  = (unsigned short*)alloc((size_t)N * 256 * 2);
  unsigned short* st0   = (unsigned short*)alloc((size_t)N * 256 * 2);
  unsigned short* st1   = (unsigned short*)alloc((size_t)N * 256 * 2);
  unsigned short* h2_bf = (unsigned short*)alloc((size_t)N * 128 * 2);
  unsigned short* p1wt  = (unsigned short*)alloc(128 * 256 * 2);
  unsigned short* p2wt  = (unsigned short*)alloc(256 * 128 * 2);
  unsigned short* k1wt  = (unsigned short*)alloc(256 * 256 * 2);
  unsigned short* k2wt  = (unsigned short*)alloc(128 * 128 * 2);
  float* s0     = (float*)alloc((size_t)N * NHEAD * sizeof(float));
  float* d0     = (float*)alloc((size_t)N * NHEAD * sizeof(float));
  float* s1     = (float*)alloc((size_t)N * NHEAD * sizeof(float));
  float* d1     = (float*)alloc((size_t)N * NHEAD * sizeof(float));
  float* wsum   = (float*)alloc(2 * 256 * sizeof(float));
  float* attn   = (float*)alloc(2 * sizeof(float));
  float* psum   = (float*)alloc((size_t)G * 128 * sizeof(float));
  float* pooled = (float*)alloc((size_t)G * 128 * sizeof(float));

  // ---- conversions ----
  f2b_kernel<<<2048, 256, 0, stream>>>(x, x_bf, N * 128 / 4);
  wtrans_kernel<<<(128 * 256 + 255) / 256, 256, 0, stream>>>(p1w, p1wt, 128, 256, 128 * 256);
  wtrans_kernel<<<(256 * 128 + 255) / 256, 256, 0, stream>>>(p2w, p2wt, 256, 128, 256 * 128);
  wtrans_kernel<<<(256 * 256 + 255) / 256, 256, 0, stream>>>(kl1w, k1wt, 256, 256, 256 * 256);
  wtrans_kernel<<<(128 * 128 + 255) / 256, 256, 0, stream>>>(kl2w, k2wt, 128, 128, 128 * 128);

  // ---- CSR build (dst-indexed), once, reused by both layers ----
  int eblk = (E + 255) / 256;
  int nb = (N + 255) / 256;
  {
    hipMemsetAsync(tmp, 0, N * sizeof(int), stream);
    hist_kernel<<<eblk, 256, 0, stream>>>(ei0, E, tmp);
    scan_local_kernel<<<nb, 256, 0, stream>>>(tmp, incl, bsum, N);
    scan_bsum_kernel<<<1, 256, 0, stream>>>(bsum, nb);
    scan_fix_kernel<<<nb, 256, 0, stream>>>(incl, tmp, bsum, rp0, N, E);
    hipMemsetAsync(tmp, 0, N * sizeof(int), stream);
    scatter_kernel<<<eblk, 256, 0, stream>>>(ei0, E, rp0, tmp, col0);

    hipMemsetAsync(tmp, 0, N * sizeof(int), stream);
    hist_kernel<<<eblk, 256, 0, stream>>>(ei1, E, tmp);
    scan_local_kernel<<<nb, 256, 0, stream>>>(tmp, incl, bsum, N);
    scan_bsum_kernel<<<1, 256, 0, stream>>>(bsum, nb);
    scan_fix_kernel<<<nb, 256, 0, stream>>>(incl, tmp, bsum, rp1, N, E);
    hipMemsetAsync(tmp, 0, N * sizeof(int), stream);
    scatter_kernel<<<eblk, 256, 0, stream>>>(ei1, E, rp1, tmp, col1);
  }

  // ---- layer 1: 128 -> 256, D=64 (combine writes back into h_bf) ----
  run_layer<128, 256, 64>(x_bf, p1wt, p1b, as1r0, ad1r0, as1r1, ad1r1, k1wt, kl1b, q1,
                          ei0, ei1, rp0, col0, rp1, col1,
                          h_bf, st0, st1, s0, d0, s1, d1, wsum, attn,
                          /*out=*/h_bf, N, E, stream);

  // ---- layer 2: 256 -> 128, D=32 (combine writes back into h2_bf) ----
  run_layer<256, 128, 32>(h_bf, p2wt, p2b, as2r0, ad2r0, as2r1, ad2r1, k2wt, kl2b, q2,
                          ei0, ei1, rp0, col0, rp1, col1,
                          h2_bf, st0, st1, s0, d0, s1, d1, wsum, attn,
                          /*out=*/h2_bf, N, E, stream);

  // ---- pool + head ----
  hipMemsetAsync(psum, 0, (size_t)G * 128 * sizeof(float), stream);
  int pblk = (N + PCH - 1) / PCH;
  pool_partial_kernel<<<pblk, 128, 0, stream>>>(h2_bf, batch, psum, N);
  pool_final_kernel<<<G, 128, 0, stream>>>(psum, batch, pooled, N);
  head_kernel<<<G, 64, 0, stream>>>(pooled, d1w, d1b, bng, bnb, bnm, bnv, d2w, d2b, out);
}

// Round 5
// 614.709 us; speedup vs baseline: 3.2581x; 1.3754x over previous
//
#include <hip/hip_runtime.h>
#include <math.h>

#define NHEAD 4
#define PCH 256

typedef __bf16 bf16x8 __attribute__((ext_vector_type(8)));
typedef float f32x4 __attribute__((ext_vector_type(4)));

__device__ __forceinline__ unsigned short f2bf(float f) {
  unsigned int u = __float_as_uint(f);
  u += 0x7FFF + ((u >> 16) & 1);  // round-to-nearest-even
  return (unsigned short)(u >> 16);
}
__device__ __forceinline__ float bf2f(unsigned short s) {
  return __uint_as_float(((unsigned int)s) << 16);
}
__device__ __forceinline__ unsigned int comb2(unsigned int p, unsigned int q,
                                              float a0, float a1) {
  float lo = a0 * bf2f((unsigned short)p) + a1 * bf2f((unsigned short)q);
  float hi = a0 * bf2f((unsigned short)(p >> 16)) + a1 * bf2f((unsigned short)(q >> 16));
  return (unsigned)f2bf(lo) | ((unsigned)f2bf(hi) << 16);
}
__device__ __forceinline__ float fast_tanh(float x) {
  x = fminf(fmaxf(x, -15.f), 15.f);
  float e = __expf(2.f * x);
  return (e - 1.f) / (e + 1.f);
}

// ================= CSR build (by dst), both relations batched =================
__global__ void hist2_kernel(const int* __restrict__ ei0, const int* __restrict__ ei1,
                             int E, int* __restrict__ deg, int N) {
  int i = blockIdx.x * blockDim.x + threadIdx.x;
  int tot = 2 * E;
  for (; i < tot; i += gridDim.x * blockDim.x) {
    int r = i >= E;
    int e = i - (r ? E : 0);
    const int* ei = r ? ei1 : ei0;
    atomicAdd(&deg[r * N + ei[E + e]], 1);
  }
}

// grid = 2*nb blocks of 256; per-relation chunked inclusive scan
__global__ void scan_local2_kernel(const int* __restrict__ deg, int* __restrict__ incl,
                                   int* __restrict__ bsum, int n, int nb) {
  __shared__ int tile[256];
  int r = blockIdx.x / nb;
  int b = blockIdx.x - r * nb;
  int i = b * 256 + threadIdx.x;
  int v = (i < n) ? deg[r * n + i] : 0;
  tile[threadIdx.x] = v;
  __syncthreads();
  for (int off = 1; off < 256; off <<= 1) {
    int t = (threadIdx.x >= (unsigned)off) ? tile[threadIdx.x - off] : 0;
    __syncthreads();
    tile[threadIdx.x] += t;
    __syncthreads();
  }
  if (i < n) incl[r * n + i] = tile[threadIdx.x];
  if (threadIdx.x == 255) bsum[blockIdx.x] = tile[255];
}

// grid = 2 blocks; each scans its relation's nb block sums (exclusive)
__global__ void scan_bsum2_kernel(int* __restrict__ bsum, int nb) {
  __shared__ int tile[256];
  int r = blockIdx.x;
  int v = (threadIdx.x < (unsigned)nb) ? bsum[r * nb + threadIdx.x] : 0;
  tile[threadIdx.x] = v;
  __syncthreads();
  for (int off = 1; off < 256; off <<= 1) {
    int t = (threadIdx.x >= (unsigned)off) ? tile[threadIdx.x - off] : 0;
    __syncthreads();
    tile[threadIdx.x] += t;
    __syncthreads();
  }
  if (threadIdx.x < (unsigned)nb) bsum[r * nb + threadIdx.x] = tile[threadIdx.x] - v;
}

__global__ void scan_fix2_kernel(const int* __restrict__ incl, const int* __restrict__ deg,
                                 const int* __restrict__ bsum, int* __restrict__ rp0,
                                 int* __restrict__ rp1, int n, int nb, int E) {
  int r = blockIdx.x / nb;
  int b = blockIdx.x - r * nb;
  int i = b * 256 + threadIdx.x;
  int* rp = r ? rp1 : rp0;
  if (i < n) rp[i] = incl[r * n + i] - deg[r * n + i] + bsum[blockIdx.x];
  if (i == 0) rp[n] = E;
}

// stores SRC node id directly (no edge-id indirection in the hot gather)
__global__ void scatter2_kernel(const int* __restrict__ ei0, const int* __restrict__ ei1,
                                int E, const int* __restrict__ rp0, const int* __restrict__ rp1,
                                int* __restrict__ cur, int* __restrict__ cs0,
                                int* __restrict__ cs1, int N) {
  int i = blockIdx.x * blockDim.x + threadIdx.x;
  int tot = 2 * E;
  for (; i < tot; i += gridDim.x * blockDim.x) {
    int r = i >= E;
    int e = i - (r ? E : 0);
    const int* ei = r ? ei1 : ei0;
    const int* rp = r ? rp1 : rp0;
    int* cs = r ? cs1 : cs0;
    int dst = ei[E + e];
    int pos = rp[dst] + atomicAdd(&cur[r * N + dst], 1);
    cs[pos] = ei[e];  // src
  }
}

// ---------------- weight transpose+cast, all four in one launch ----------------
__global__ void wtrans_all_kernel(const float* __restrict__ p1w, const float* __restrict__ p2w,
                                  const float* __restrict__ k1w, const float* __restrict__ k2w,
                                  unsigned short* __restrict__ p1wt,
                                  unsigned short* __restrict__ p2wt,
                                  unsigned short* __restrict__ k1wt,
                                  unsigned short* __restrict__ k2wt) {
  int i = blockIdx.x * 256 + threadIdx.x;
  if (i < 32768) {                      // p1: [128,256]
    int k = i >> 8, f = i & 255;
    p1wt[f * 128 + k] = f2bf(p1w[i]);
  } else if (i < 65536) {               // p2: [256,128]
    int j = i - 32768; int k = j >> 7, f = j & 127;
    p2wt[f * 256 + k] = f2bf(p2w[j]);
  } else if (i < 131072) {              // k1: [256,256]
    int j = i - 65536; int k = j >> 8, f = j & 255;
    k1wt[f * 256 + k] = f2bf(k1w[j]);
  } else if (i < 147456) {              // k2: [128,128]
    int j = i - 131072; int k = j >> 7, f = j & 127;
    k2wt[f * 128 + k] = f2bf(k2w[j]);
  }
}

// =============== MFMA GEMM: 64 rows x F cols/block, 256 thr, 16x16x32 bf16 ===============
// MODE: 0 = A bf16; 1 = A fp32 (convert in staging); 2 = A = bf16(a0*S0 + a1*S1)
// EPI:  0 = out[m][f] = bf16(acc + bias); 1 = wsum[f] += sum_rows tanh(acc + bias)
template <int K, int F, int MODE, int EPI>
__global__ __launch_bounds__(256) void mfma_gemm(
    const unsigned short* __restrict__ A, const float* __restrict__ Af,
    const unsigned short* __restrict__ S0, const unsigned short* __restrict__ S1,
    const float* __restrict__ attnp, const unsigned short* __restrict__ Wt,
    const float* __restrict__ bias, unsigned short* __restrict__ out,
    float* __restrict__ wsum, int M) {
  constexpr int G = F / 64, S = 4 / G, RT = 4 / S;
  __shared__ unsigned short As[64][40];  // pad 40: bank spread, rows 16B-aligned
  const int tid = threadIdx.x;
  const int lane = tid & 63, wid = tid >> 6;
  const int cg = wid % G, rg = wid / G;
  const int l15 = lane & 15, l4 = lane >> 4;
  const int m0 = blockIdx.x * 64;
  const int wrow = rg * RT * 16;
  float ca0 = 0.f, ca1 = 0.f;
  if constexpr (MODE == 2) { ca0 = attnp[0]; ca1 = attnp[1]; }
  f32x4 acc[RT][4];
#pragma unroll
  for (int rt = 0; rt < RT; ++rt)
#pragma unroll
    for (int ct = 0; ct < 4; ++ct) acc[rt][ct] = (f32x4){0.f, 0.f, 0.f, 0.f};
  const int arow = tid >> 2;
  const int akk = (tid & 3) * 8;
  for (int k0 = 0; k0 < K; k0 += 32) {
    uint4 av = {0u, 0u, 0u, 0u};
    int row = m0 + arow;
    if (row < M) {
      if constexpr (MODE == 0) {
        av = *(const uint4*)&A[(size_t)row * K + k0 + akk];
      } else if constexpr (MODE == 1) {
        float4 f0 = *(const float4*)&Af[(size_t)row * K + k0 + akk];
        float4 f1 = *(const float4*)&Af[(size_t)row * K + k0 + akk + 4];
        av.x = (unsigned)f2bf(f0.x) | ((unsigned)f2bf(f0.y) << 16);
        av.y = (unsigned)f2bf(f0.z) | ((unsigned)f2bf(f0.w) << 16);
        av.z = (unsigned)f2bf(f1.x) | ((unsigned)f2bf(f1.y) << 16);
        av.w = (unsigned)f2bf(f1.z) | ((unsigned)f2bf(f1.w) << 16);
      } else {
        uint4 u0 = *(const uint4*)&S0[(size_t)row * K + k0 + akk];
        uint4 u1 = *(const uint4*)&S1[(size_t)row * K + k0 + akk];
        av.x = comb2(u0.x, u1.x, ca0, ca1);
        av.y = comb2(u0.y, u1.y, ca0, ca1);
        av.z = comb2(u0.z, u1.z, ca0, ca1);
        av.w = comb2(u0.w, u1.w, ca0, ca1);
      }
    }
    __syncthreads();
    *(uint4*)&As[arow][akk] = av;
    __syncthreads();
    bf16x8 bfr[4];
#pragma unroll
    for (int ct = 0; ct < 4; ++ct) {
      int colx = cg * 64 + ct * 16 + l15;
      bfr[ct] = *(const bf16x8*)&Wt[(size_t)colx * K + k0 + l4 * 8];
    }
#pragma unroll
    for (int rt = 0; rt < RT; ++rt) {
      bf16x8 afr = *(const bf16x8*)&As[wrow + rt * 16 + l15][l4 * 8];
#pragma unroll
      for (int ct = 0; ct < 4; ++ct)
        acc[rt][ct] = __builtin_amdgcn_mfma_f32_16x16x32_bf16(afr, bfr[ct], acc[rt][ct], 0, 0, 0);
    }
  }
  if constexpr (EPI == 0) {
#pragma unroll
    for (int ct = 0; ct < 4; ++ct) {
      int n = cg * 64 + ct * 16 + l15;
      float bv = bias[n];
#pragma unroll
      for (int rt = 0; rt < RT; ++rt)
#pragma unroll
        for (int r = 0; r < 4; ++r) {
          int m = m0 + wrow + rt * 16 + l4 * 4 + r;
          if (m < M) out[(size_t)m * F + n] = f2bf(acc[rt][ct][r] + bv);
        }
    }
  } else {
#pragma unroll
    for (int ct = 0; ct < 4; ++ct) {
      int n = cg * 64 + ct * 16 + l15;
      float bv = bias[n];
      float cs = 0.f;
#pragma unroll
      for (int rt = 0; rt < RT; ++rt)
#pragma unroll
        for (int r = 0; r < 4; ++r) {
          int m = m0 + wrow + rt * 16 + l4 * 4 + r;
          if (m < M) cs += fast_tanh(acc[rt][ct][r] + bv);
        }
      cs += __shfl_xor(cs, 16, 64);
      cs += __shfl_xor(cs, 32, 64);
      if (l4 == 0) atomicAdd(&wsum[n], cs);
    }
  }
}

// -------- s/d both relations, wave-per-node, vectorized row loads --------
template <int F, int D>
__global__ void sd2v_kernel(const unsigned short* __restrict__ h,
                            const float* __restrict__ as0, const float* __restrict__ ad0,
                            const float* __restrict__ as1, const float* __restrict__ ad1,
                            float* __restrict__ s0, float* __restrict__ d0,
                            float* __restrict__ s1, float* __restrict__ d1, int n) {
  constexpr int VEC = F / 64;
  int w = threadIdx.x >> 6, lane = threadIdx.x & 63;
  int nn = blockIdx.x * 4 + w;
  if (nn >= n) return;
  int f0 = lane * VEC;
  float hv[VEC];
  if constexpr (VEC == 4) {
    uint2 u = *(const uint2*)&h[(size_t)nn * F + f0];
    hv[0] = bf2f((unsigned short)(u.x & 0xffff));
    hv[1] = bf2f((unsigned short)(u.x >> 16));
    hv[2] = bf2f((unsigned short)(u.y & 0xffff));
    hv[3] = bf2f((unsigned short)(u.y >> 16));
  } else {
    unsigned int u = *(const unsigned int*)&h[(size_t)nn * F + f0];
    hv[0] = bf2f((unsigned short)(u & 0xffff));
    hv[1] = bf2f((unsigned short)(u >> 16));
  }
  float v0 = 0.f, w0 = 0.f, v1 = 0.f, w1 = 0.f;
#pragma unroll
  for (int v = 0; v < VEC; ++v) {
    v0 += hv[v] * as0[f0 + v];
    w0 += hv[v] * ad0[f0 + v];
    v1 += hv[v] * as1[f0 + v];
    w1 += hv[v] * ad1[f0 + v];
  }
  // head boundary == 16-lane group in both layers (D/VEC == 16)
#pragma unroll
  for (int off = 8; off > 0; off >>= 1) {
    v0 += __shfl_xor(v0, off, 16);
    w0 += __shfl_xor(w0, off, 16);
    v1 += __shfl_xor(v1, off, 16);
    w1 += __shfl_xor(w1, off, 16);
  }
  if ((lane & 15) == 0) {
    int idx = nn * NHEAD + (lane >> 4);
    s0[idx] = v0; d0[idx] = w0;
    s1[idx] = v1; d1[idx] = w1;
  }
}

// ---- fused per-dst softmax + weighted gather + relu; wave/node, 4-edge unroll ----
__device__ __forceinline__ void acc4(uint2 hv, float v, float* acc) {
  acc[0] += v * bf2f((unsigned short)(hv.x & 0xffff));
  acc[1] += v * bf2f((unsigned short)(hv.x >> 16));
  acc[2] += v * bf2f((unsigned short)(hv.y & 0xffff));
  acc[3] += v * bf2f((unsigned short)(hv.y >> 16));
}
__device__ __forceinline__ void acc2(unsigned int hv, float v, float* acc) {
  acc[0] += v * bf2f((unsigned short)(hv & 0xffff));
  acc[1] += v * bf2f((unsigned short)(hv >> 16));
}
__device__ __forceinline__ float ecoef(float sv, float dv) {
  float a = sv + dv;
  a = (a >= 0.f) ? a : 0.2f * a;
  return __expf(a);  // segment_max skipped: cancels in softmax, alpha is O(1)
}

template <int F, int D>
__global__ void message_kernel(const unsigned short* __restrict__ h,
                               const int* __restrict__ colsrc, const int* __restrict__ rp,
                               const float* __restrict__ s, const float* __restrict__ d,
                               unsigned short* __restrict__ out, int N) {
  constexpr int VEC = F / 64;
  int w = threadIdx.x >> 6;
  int lane = threadIdx.x & 63;
  int nn = blockIdx.x * 4 + w;
  if (nn >= N) return;
  int f0 = lane * VEC;
  int hh = f0 / D;
  float dv = d[nn * NHEAD + hh];
  int lo = rp[nn], hi = rp[nn + 1];
  float acc[VEC];
#pragma unroll
  for (int v = 0; v < VEC; ++v) acc[v] = 0.f;
  float den = 0.f;
  int j = lo;
  for (; j + 4 <= hi; j += 4) {
    int c0 = colsrc[j], c1 = colsrc[j + 1], c2 = colsrc[j + 2], c3 = colsrc[j + 3];
    float e0 = s[c0 * NHEAD + hh], e1 = s[c1 * NHEAD + hh];
    float e2 = s[c2 * NHEAD + hh], e3 = s[c3 * NHEAD + hh];
    if constexpr (VEC == 4) {
      uint2 h0 = *(const uint2*)&h[(size_t)c0 * F + f0];
      uint2 h1 = *(const uint2*)&h[(size_t)c1 * F + f0];
      uint2 h2 = *(const uint2*)&h[(size_t)c2 * F + f0];
      uint2 h3 = *(const uint2*)&h[(size_t)c3 * F + f0];
      float v0 = ecoef(e0, dv), v1 = ecoef(e1, dv);
      float v2 = ecoef(e2, dv), v3 = ecoef(e3, dv);
      den += v0 + v1 + v2 + v3;
      acc4(h0, v0, acc); acc4(h1, v1, acc);
      acc4(h2, v2, acc); acc4(h3, v3, acc);
    } else {
      unsigned int h0 = *(const unsigned int*)&h[(size_t)c0 * F + f0];
      unsigned int h1 = *(const unsigned int*)&h[(size_t)c1 * F + f0];
      unsigned int h2 = *(const unsigned int*)&h[(size_t)c2 * F + f0];
      unsigned int h3 = *(const unsigned int*)&h[(size_t)c3 * F + f0];
      float v0 = ecoef(e0, dv), v1 = ecoef(e1, dv);
      float v2 = ecoef(e2, dv), v3 = ecoef(e3, dv);
      den += v0 + v1 + v2 + v3;
      acc2(h0, v0, acc); acc2(h1, v1, acc);
      acc2(h2, v2, acc); acc2(h3, v3, acc);
    }
  }
  for (; j < hi; ++j) {
    int c = colsrc[j];
    float v = ecoef(s[c * NHEAD + hh], dv);
    den += v;
    if constexpr (VEC == 4) acc4(*(const uint2*)&h[(size_t)c * F + f0], v, acc);
    else acc2(*(const unsigned int*)&h[(size_t)c * F + f0], v, acc);
  }
  float inv = 1.f / (den + 1e-16f);
  if constexpr (VEC == 4) {
    uint2 o;
    o.x = (unsigned)f2bf(fmaxf(acc[0] * inv, 0.f)) |
          ((unsigned)f2bf(fmaxf(acc[1] * inv, 0.f)) << 16);
    o.y = (unsigned)f2bf(fmaxf(acc[2] * inv, 0.f)) |
          ((unsigned)f2bf(fmaxf(acc[3] * inv, 0.f)) << 16);
    *(uint2*)&out[(size_t)nn * F + f0] = o;
  } else {
    unsigned int o = (unsigned)f2bf(fmaxf(acc[0] * inv, 0.f)) |
                     ((unsigned)f2bf(fmaxf(acc[1] * inv, 0.f)) << 16);
    *(unsigned int*)&out[(size_t)nn * F + f0] = o;
  }
}

// ---------------- attn = softmax_r( mean_w_r . q ) ----------------
template <int F>
__global__ void attn_kernel(const float* __restrict__ wsum, const float* __restrict__ q,
                            float* __restrict__ attn, float inv_n) {
  __shared__ float red[2][F / 64];
  int f = threadIdx.x;
  float qv = q[f];
  float v0 = wsum[f] * inv_n * qv;
  float v1 = wsum[F + f] * inv_n * qv;
#pragma unroll
  for (int off = 32; off > 0; off >>= 1) {
    v0 += __shfl_down(v0, off, 64);
    v1 += __shfl_down(v1, off, 64);
  }
  int w = f / 64;
  if ((f & 63) == 0) { red[0][w] = v0; red[1][w] = v1; }
  __syncthreads();
  if (f == 0) {
    float d0 = 0.f, d1 = 0.f;
#pragma unroll
    for (int i = 0; i < F / 64; ++i) { d0 += red[0][i]; d1 += red[1][i]; }
    float m = fmaxf(d0, d1);
    float e0 = expf(d0 - m), e1 = expf(d1 - m);
    float inv = 1.f / (e0 + e1);
    attn[0] = e0 * inv;
    attn[1] = e1 * inv;
  }
}

// ------- pool with layer-2 combine fused in (batch sorted, chunked) -------
__global__ void pool_fused_kernel(const unsigned short* __restrict__ st0,
                                  const unsigned short* __restrict__ st1,
                                  const float* __restrict__ attn,
                                  const int* __restrict__ batch,
                                  float* __restrict__ psum, int n) {
  int c0 = blockIdx.x * PCH;
  if (c0 >= n) return;
  int lane = threadIdx.x;  // 64; 2 features each
  float a0 = attn[0], a1 = attn[1];
  int end = min(c0 + PCH, n);
  int g_cur = batch[c0];
  float acc0 = 0.f, acc1 = 0.f;
  for (int nn = c0; nn < end; ++nn) {
    int g = batch[nn];
    if (g != g_cur) {
      atomicAdd(&psum[g_cur * 128 + lane * 2], acc0);
      atomicAdd(&psum[g_cur * 128 + lane * 2 + 1], acc1);
      acc0 = acc1 = 0.f;
      g_cur = g;
    }
    unsigned int u0 = *(const unsigned int*)&st0[(size_t)nn * 128 + lane * 2];
    unsigned int u1 = *(const unsigned int*)&st1[(size_t)nn * 128 + lane * 2];
    // combine(st0,st1) rounded to bf16 to match prior numerics
    acc0 += bf2f(f2bf(a0 * bf2f((unsigned short)(u0 & 0xffff)) +
                      a1 * bf2f((unsigned short)(u1 & 0xffff))));
    acc1 += bf2f(f2bf(a0 * bf2f((unsigned short)(u0 >> 16)) +
                      a1 * bf2f((unsigned short)(u1 >> 16))));
  }
  atomicAdd(&psum[g_cur * 128 + lane * 2], acc0);
  atomicAdd(&psum[g_cur * 128 + lane * 2 + 1], acc1);
}

__device__ __forceinline__ int lower_bound_i(const int* a, int n, int key) {
  int lo = 0, hi = n;
  while (lo < hi) {
    int mid = (lo + hi) >> 1;
    if (a[mid] < key) lo = mid + 1; else hi = mid;
  }
  return lo;
}

__global__ void pool_final_kernel(const float* __restrict__ psum, const int* __restrict__ batch,
                                  float* __restrict__ pooled, int n) {
  int g = blockIdx.x;
  int f = threadIdx.x;
  int lo = lower_bound_i(batch, n, g);
  int hi = lower_bound_i(batch, n, g + 1);
  float cnt = fmaxf((float)(hi - lo), 1.f);
  pooled[g * 128 + f] = psum[g * 128 + f] / cnt;
}

__global__ void head_kernel(const float* __restrict__ pooled, const float* __restrict__ d1w,
                            const float* __restrict__ d1b, const float* __restrict__ gamma,
                            const float* __restrict__ beta, const float* __restrict__ mean,
                            const float* __restrict__ var, const float* __restrict__ d2w,
                            const float* __restrict__ d2b, float* __restrict__ out) {
  int g = blockIdx.x;
  int j = threadIdx.x;  // 64 = 1 wave
  float acc = d1b[j];
  for (int k = 0; k < 128; ++k) acc += pooled[g * 128 + k] * d1w[k * 64 + j];
  float z = (acc - mean[j]) / sqrtf(var[j] + 1e-5f) * gamma[j] + beta[j];
  z = (z >= 0.f) ? z : 0.1f * z;
  float t = z * d2w[j];
#pragma unroll
  for (int off = 32; off > 0; off >>= 1) t += __shfl_down(t, off, 64);
  if (j == 0) out[g] = t + d2b[0];
}

// =====================================================================
extern "C" void kernel_launch(void* const* d_in, const int* in_sizes, int n_in,
                              void* d_out, int out_size, void* d_ws, size_t ws_size,
                              hipStream_t stream) {
  const float* x      = (const float*)d_in[0];
  const int* ei0      = (const int*)d_in[1];
  const int* ei1      = (const int*)d_in[2];
  const int* batch    = (const int*)d_in[3];
  const float* p1w    = (const float*)d_in[4];
  const float* p1b    = (const float*)d_in[5];
  const float* as1r0  = (const float*)d_in[6];
  const float* ad1r0  = (const float*)d_in[7];
  const float* as1r1  = (const float*)d_in[8];
  const float* ad1r1  = (const float*)d_in[9];
  const float* kl1w   = (const float*)d_in[10];
  const float* kl1b   = (const float*)d_in[11];
  const float* q1     = (const float*)d_in[12];
  const float* p2w    = (const float*)d_in[13];
  const float* p2b    = (const float*)d_in[14];
  const float* as2r0  = (const float*)d_in[15];
  const float* ad2r0  = (const float*)d_in[16];
  const float* as2r1  = (const float*)d_in[17];
  const float* ad2r1  = (const float*)d_in[18];
  const float* kl2w   = (const float*)d_in[19];
  const float* kl2b   = (const float*)d_in[20];
  const float* q2     = (const float*)d_in[21];
  const float* d1w    = (const float*)d_in[22];
  const float* d1b    = (const float*)d_in[23];
  const float* bng    = (const float*)d_in[24];
  const float* bnb    = (const float*)d_in[25];
  const float* bnm    = (const float*)d_in[26];
  const float* bnv    = (const float*)d_in[27];
  const float* d2w    = (const float*)d_in[28];
  const float* d2b    = (const float*)d_in[29];
  float* out = (float*)d_out;

  const int N = in_sizes[3];       // 50000
  const int E = in_sizes[1] / 2;   // 400000
  const int G = 64;

  char* p = (char*)d_ws;
  auto alloc = [&](size_t bytes) -> void* {
    void* r = (void*)p;
    p += (bytes + 255) & ~(size_t)255;
    return r;
  };
  int* rp0    = (int*)alloc((N + 1) * sizeof(int));
  int* rp1    = (int*)alloc((N + 1) * sizeof(int));
  int* cs0    = (int*)alloc(E * sizeof(int));        // src per CSR slot
  int* cs1    = (int*)alloc(E * sizeof(int));
  int* deg    = (int*)alloc(2 * (size_t)N * sizeof(int));
  int* incl   = (int*)alloc(2 * (size_t)N * sizeof(int));
  int* cur    = (int*)alloc(2 * (size_t)N * sizeof(int));
  int* bsum   = (int*)alloc(512 * sizeof(int));
  unsigned short* h_bf  = (unsigned short*)alloc((size_t)N * 256 * 2);
  unsigned short* st0   = (unsigned short*)alloc((size_t)N * 256 * 2);
  unsigned short* st1   = (unsigned short*)alloc((size_t)N * 256 * 2);
  unsigned short* h2_bf = (unsigned short*)alloc((size_t)N * 128 * 2);
  unsigned short* p1wt  = (unsigned short*)alloc(128 * 256 * 2);
  unsigned short* p2wt  = (unsigned short*)alloc(256 * 128 * 2);
  unsigned short* k1wt  = (unsigned short*)alloc(256 * 256 * 2);
  unsigned short* k2wt  = (unsigned short*)alloc(128 * 128 * 2);
  float* s0     = (float*)alloc((size_t)N * NHEAD * sizeof(float));
  float* d0     = (float*)alloc((size_t)N * NHEAD * sizeof(float));
  float* s1     = (float*)alloc((size_t)N * NHEAD * sizeof(float));
  float* d1     = (float*)alloc((size_t)N * NHEAD * sizeof(float));
  float* wsum   = (float*)alloc(2 * 256 * sizeof(float));
  float* attn1  = (float*)alloc(2 * sizeof(float));
  float* attn2  = (float*)alloc(2 * sizeof(float));
  float* psum   = (float*)alloc((size_t)G * 128 * sizeof(float));
  float* pooled = (float*)alloc((size_t)G * 128 * sizeof(float));

  // ---- weights ----
  wtrans_all_kernel<<<576, 256, 0, stream>>>(p1w, p2w, kl1w, kl2w, p1wt, p2wt, k1wt, k2wt);

  // ---- CSR build (both relations batched) ----
  int nb = (N + 255) / 256;
  int e2blk = (2 * E + 255) / 256;
  hipMemsetAsync(deg, 0, 2 * (size_t)N * sizeof(int), stream);
  hist2_kernel<<<e2blk, 256, 0, stream>>>(ei0, ei1, E, deg, N);
  scan_local2_kernel<<<2 * nb, 256, 0, stream>>>(deg, incl, bsum, N, nb);
  scan_bsum2_kernel<<<2, 256, 0, stream>>>(bsum, nb);
  scan_fix2_kernel<<<2 * nb, 256, 0, stream>>>(incl, deg, bsum, rp0, rp1, N, nb, E);
  hipMemsetAsync(cur, 0, 2 * (size_t)N * sizeof(int), stream);
  scatter2_kernel<<<e2blk, 256, 0, stream>>>(ei0, ei1, E, rp0, rp1, cur, cs0, cs1, N);

  int gblk = (N + 63) / 64;
  int nblk4 = (N + 3) / 4;

  // ================= layer 1: 128 -> 256, D=64 =================
  mfma_gemm<128, 256, 1, 0><<<gblk, 256, 0, stream>>>(
      nullptr, x, nullptr, nullptr, nullptr, p1wt, p1b, h_bf, nullptr, N);
  sd2v_kernel<256, 64><<<nblk4, 256, 0, stream>>>(h_bf, as1r0, ad1r0, as1r1, ad1r1,
                                                  s0, d0, s1, d1, N);
  message_kernel<256, 64><<<nblk4, 256, 0, stream>>>(h_bf, cs0, rp0, s0, d0, st0, N);
  message_kernel<256, 64><<<nblk4, 256, 0, stream>>>(h_bf, cs1, rp1, s1, d1, st1, N);
  hipMemsetAsync(wsum, 0, 2 * 256 * sizeof(float), stream);
  mfma_gemm<256, 256, 0, 1><<<gblk, 256, 0, stream>>>(
      st0, nullptr, nullptr, nullptr, nullptr, k1wt, kl1b, nullptr, wsum, N);
  mfma_gemm<256, 256, 0, 1><<<gblk, 256, 0, stream>>>(
      st1, nullptr, nullptr, nullptr, nullptr, k1wt, kl1b, nullptr, wsum + 256, N);
  attn_kernel<256><<<1, 256, 0, stream>>>(wsum, q1, attn1, 1.0f / (float)N);

  // ================= layer 2: 256 -> 128, D=32 (combine fused into proj staging) ====
  mfma_gemm<256, 128, 2, 0><<<gblk, 256, 0, stream>>>(
      nullptr, nullptr, st0, st1, attn1, p2wt, p2b, h2_bf, nullptr, N);
  sd2v_kernel<128, 32><<<nblk4, 256, 0, stream>>>(h2_bf, as2r0, ad2r0, as2r1, ad2r1,
                                                  s0, d0, s1, d1, N);
  message_kernel<128, 32><<<nblk4, 256, 0, stream>>>(h2_bf, cs0, rp0, s0, d0, st0, N);
  message_kernel<128, 32><<<nblk4, 256, 0, stream>>>(h2_bf, cs1, rp1, s1, d1, st1, N);
  hipMemsetAsync(wsum, 0, 2 * 256 * sizeof(float), stream);
  mfma_gemm<128, 128, 0, 1><<<gblk, 256, 0, stream>>>(
      st0, nullptr, nullptr, nullptr, nullptr, k2wt, kl2b, nullptr, wsum, N);
  mfma_gemm<128, 128, 0, 1><<<gblk, 256, 0, stream>>>(
      st1, nullptr, nullptr, nullptr, nullptr, k2wt, kl2b, nullptr, wsum + 128, N);
  attn_kernel<128><<<1, 128, 0, stream>>>(wsum, q2, attn2, 1.0f / (float)N);

  // ---- pool (combine fused) + head ----
  hipMemsetAsync(psum, 0, (size_t)G * 128 * sizeof(float), stream);
  int pblk = (N + PCH - 1) / PCH;
  pool_fused_kernel<<<pblk, 64, 0, stream>>>(st0, st1, attn2, batch, psum, N);
  pool_final_kernel<<<G, 128, 0, stream>>>(psum, batch, pooled, N);
  head_kernel<<<G, 64, 0, stream>>>(pooled, d1w, d1b, bng, bnb, bnm, bnv, d2w, d2b, out);
}

// Round 6
// 539.472 us; speedup vs baseline: 3.7125x; 1.1395x over previous
//
#include <hip/hip_runtime.h>
#include <math.h>

#define NHEAD 4
#define PCH 16

typedef __bf16 bf16x8 __attribute__((ext_vector_type(8)));
typedef float f32x4 __attribute__((ext_vector_type(4)));

__device__ __forceinline__ unsigned short f2bf(float f) {
  unsigned int u = __float_as_uint(f);
  u += 0x7FFF + ((u >> 16) & 1);  // round-to-nearest-even
  return (unsigned short)(u >> 16);
}
__device__ __forceinline__ float bf2f(unsigned short s) {
  return __uint_as_float(((unsigned int)s) << 16);
}
__device__ __forceinline__ unsigned int comb2(unsigned int p, unsigned int q,
                                              float a0, float a1) {
  float lo = a0 * bf2f((unsigned short)p) + a1 * bf2f((unsigned short)q);
  float hi = a0 * bf2f((unsigned short)(p >> 16)) + a1 * bf2f((unsigned short)(q >> 16));
  return (unsigned)f2bf(lo) | ((unsigned)f2bf(hi) << 16);
}
__device__ __forceinline__ float fast_tanh(float x) {
  x = fminf(fmaxf(x, -15.f), 15.f);
  float e = __expf(2.f * x);
  return (e - 1.f) / (e + 1.f);
}

// ================= CSR build (by dst), both relations batched =================
__global__ void hist2_kernel(const int* __restrict__ ei0, const int* __restrict__ ei1,
                             int E, int* __restrict__ deg, int N) {
  int i = blockIdx.x * blockDim.x + threadIdx.x;
  int tot = 2 * E;
  for (; i < tot; i += gridDim.x * blockDim.x) {
    int r = i >= E;
    int e = i - (r ? E : 0);
    const int* ei = r ? ei1 : ei0;
    atomicAdd(&deg[r * N + ei[E + e]], 1);
  }
}

__global__ void scan_local2_kernel(const int* __restrict__ deg, int* __restrict__ incl,
                                   int* __restrict__ bsum, int n, int nb) {
  __shared__ int tile[256];
  int r = blockIdx.x / nb;
  int b = blockIdx.x - r * nb;
  int i = b * 256 + threadIdx.x;
  int v = (i < n) ? deg[r * n + i] : 0;
  tile[threadIdx.x] = v;
  __syncthreads();
  for (int off = 1; off < 256; off <<= 1) {
    int t = (threadIdx.x >= (unsigned)off) ? tile[threadIdx.x - off] : 0;
    __syncthreads();
    tile[threadIdx.x] += t;
    __syncthreads();
  }
  if (i < n) incl[r * n + i] = tile[threadIdx.x];
  if (threadIdx.x == 255) bsum[blockIdx.x] = tile[255];
}

__global__ void scan_bsum2_kernel(int* __restrict__ bsum, int nb) {
  __shared__ int tile[256];
  int r = blockIdx.x;
  int v = (threadIdx.x < (unsigned)nb) ? bsum[r * nb + threadIdx.x] : 0;
  tile[threadIdx.x] = v;
  __syncthreads();
  for (int off = 1; off < 256; off <<= 1) {
    int t = (threadIdx.x >= (unsigned)off) ? tile[threadIdx.x - off] : 0;
    __syncthreads();
    tile[threadIdx.x] += t;
    __syncthreads();
  }
  if (threadIdx.x < (unsigned)nb) bsum[r * nb + threadIdx.x] = tile[threadIdx.x] - v;
}

__global__ void scan_fix2_kernel(const int* __restrict__ incl, const int* __restrict__ deg,
                                 const int* __restrict__ bsum, int* __restrict__ rp0,
                                 int* __restrict__ rp1, int n, int nb, int E) {
  int r = blockIdx.x / nb;
  int b = blockIdx.x - r * nb;
  int i = b * 256 + threadIdx.x;
  int* rp = r ? rp1 : rp0;
  if (i < n) rp[i] = incl[r * n + i] - deg[r * n + i] + bsum[blockIdx.x];
  if (i == 0) rp[n] = E;
}

__global__ void scatter2_kernel(const int* __restrict__ ei0, const int* __restrict__ ei1,
                                int E, const int* __restrict__ rp0, const int* __restrict__ rp1,
                                int* __restrict__ cur, int* __restrict__ cs0,
                                int* __restrict__ cs1, int N) {
  int i = blockIdx.x * blockDim.x + threadIdx.x;
  int tot = 2 * E;
  for (; i < tot; i += gridDim.x * blockDim.x) {
    int r = i >= E;
    int e = i - (r ? E : 0);
    const int* ei = r ? ei1 : ei0;
    const int* rp = r ? rp1 : rp0;
    int* cs = r ? cs1 : cs0;
    int dst = ei[E + e];
    int pos = rp[dst] + atomicAdd(&cur[r * N + dst], 1);
    cs[pos] = ei[e];  // src node id, no edge indirection later
  }
}

// ---------------- weight transpose+cast, all four in one launch ----------------
__global__ void wtrans_all_kernel(const float* __restrict__ p1w, const float* __restrict__ p2w,
                                  const float* __restrict__ k1w, const float* __restrict__ k2w,
                                  unsigned short* __restrict__ p1wt,
                                  unsigned short* __restrict__ p2wt,
                                  unsigned short* __restrict__ k1wt,
                                  unsigned short* __restrict__ k2wt) {
  int i = blockIdx.x * 256 + threadIdx.x;
  if (i < 32768) {                      // p1: [128,256]
    int k = i >> 8, f = i & 255;
    p1wt[f * 128 + k] = f2bf(p1w[i]);
  } else if (i < 65536) {               // p2: [256,128]
    int j = i - 32768; int k = j >> 7, f = j & 127;
    p2wt[f * 256 + k] = f2bf(p2w[j]);
  } else if (i < 131072) {              // k1: [256,256]
    int j = i - 65536; int k = j >> 8, f = j & 255;
    k1wt[f * 256 + k] = f2bf(k1w[j]);
  } else if (i < 147456) {              // k2: [128,128]
    int j = i - 131072; int k = j >> 7, f = j & 127;
    k2wt[f * 128 + k] = f2bf(k2w[j]);
  }
}

// =============== MFMA GEMM: 64 rows x F cols/block, 256 thr, 16x16x32 bf16 ===============
// MODE: 0 = A bf16; 1 = A fp32 (convert in staging); 2 = A = bf16(a0*S0 + a1*S1)
// EPI:  0 = out[m][f] = bf16(acc + bias); 1 = wsum[f] += sum_rows tanh(acc + bias)
template <int K, int F, int MODE, int EPI>
__global__ __launch_bounds__(256) void mfma_gemm(
    const unsigned short* __restrict__ A, const float* __restrict__ Af,
    const unsigned short* __restrict__ S0, const unsigned short* __restrict__ S1,
    const float* __restrict__ attnp, const unsigned short* __restrict__ Wt,
    const float* __restrict__ bias, unsigned short* __restrict__ out,
    float* __restrict__ wsum, int M) {
  constexpr int G = F / 64, S = 4 / G, RT = 4 / S;
  __shared__ unsigned short As[64][40];  // pad 40: bank spread, rows 16B-aligned
  const int tid = threadIdx.x;
  const int lane = tid & 63, wid = tid >> 6;
  const int cg = wid % G, rg = wid / G;
  const int l15 = lane & 15, l4 = lane >> 4;
  const int m0 = blockIdx.x * 64;
  const int wrow = rg * RT * 16;
  float ca0 = 0.f, ca1 = 0.f;
  if constexpr (MODE == 2) { ca0 = attnp[0]; ca1 = attnp[1]; }
  f32x4 acc[RT][4];
#pragma unroll
  for (int rt = 0; rt < RT; ++rt)
#pragma unroll
    for (int ct = 0; ct < 4; ++ct) acc[rt][ct] = (f32x4){0.f, 0.f, 0.f, 0.f};
  const int arow = tid >> 2;
  const int akk = (tid & 3) * 8;
  for (int k0 = 0; k0 < K; k0 += 32) {
    uint4 av = {0u, 0u, 0u, 0u};
    int row = m0 + arow;
    if (row < M) {
      if constexpr (MODE == 0) {
        av = *(const uint4*)&A[(size_t)row * K + k0 + akk];
      } else if constexpr (MODE == 1) {
        float4 f0 = *(const float4*)&Af[(size_t)row * K + k0 + akk];
        float4 f1 = *(const float4*)&Af[(size_t)row * K + k0 + akk + 4];
        av.x = (unsigned)f2bf(f0.x) | ((unsigned)f2bf(f0.y) << 16);
        av.y = (unsigned)f2bf(f0.z) | ((unsigned)f2bf(f0.w) << 16);
        av.z = (unsigned)f2bf(f1.x) | ((unsigned)f2bf(f1.y) << 16);
        av.w = (unsigned)f2bf(f1.z) | ((unsigned)f2bf(f1.w) << 16);
      } else {
        uint4 u0 = *(const uint4*)&S0[(size_t)row * K + k0 + akk];
        uint4 u1 = *(const uint4*)&S1[(size_t)row * K + k0 + akk];
        av.x = comb2(u0.x, u1.x, ca0, ca1);
        av.y = comb2(u0.y, u1.y, ca0, ca1);
        av.z = comb2(u0.z, u1.z, ca0, ca1);
        av.w = comb2(u0.w, u1.w, ca0, ca1);
      }
    }
    __syncthreads();
    *(uint4*)&As[arow][akk] = av;
    __syncthreads();
    bf16x8 bfr[4];
#pragma unroll
    for (int ct = 0; ct < 4; ++ct) {
      int colx = cg * 64 + ct * 16 + l15;
      bfr[ct] = *(const bf16x8*)&Wt[(size_t)colx * K + k0 + l4 * 8];
    }
#pragma unroll
    for (int rt = 0; rt < RT; ++rt) {
      bf16x8 afr = *(const bf16x8*)&As[wrow + rt * 16 + l15][l4 * 8];
#pragma unroll
      for (int ct = 0; ct < 4; ++ct)
        acc[rt][ct] = __builtin_amdgcn_mfma_f32_16x16x32_bf16(afr, bfr[ct], acc[rt][ct], 0, 0, 0);
    }
  }
  if constexpr (EPI == 0) {
#pragma unroll
    for (int ct = 0; ct < 4; ++ct) {
      int n = cg * 64 + ct * 16 + l15;
      float bv = bias[n];
#pragma unroll
      for (int rt = 0; rt < RT; ++rt)
#pragma unroll
        for (int r = 0; r < 4; ++r) {
          int m = m0 + wrow + rt * 16 + l4 * 4 + r;
          if (m < M) out[(size_t)m * F + n] = f2bf(acc[rt][ct][r] + bv);
        }
    }
  } else {
#pragma unroll
    for (int ct = 0; ct < 4; ++ct) {
      int n = cg * 64 + ct * 16 + l15;
      float bv = bias[n];
      float cs = 0.f;
#pragma unroll
      for (int rt = 0; rt < RT; ++rt)
#pragma unroll
        for (int r = 0; r < 4; ++r) {
          int m = m0 + wrow + rt * 16 + l4 * 4 + r;
          if (m < M) cs += fast_tanh(acc[rt][ct][r] + bv);
        }
      cs += __shfl_xor(cs, 16, 64);
      cs += __shfl_xor(cs, 32, 64);
      if (l4 == 0) atomicAdd(&wsum[n], cs);
    }
  }
}

// -------- s/d both relations, wave-per-node, vectorized row loads --------
template <int F, int D>
__global__ void sd2v_kernel(const unsigned short* __restrict__ h,
                            const float* __restrict__ as0, const float* __restrict__ ad0,
                            const float* __restrict__ as1, const float* __restrict__ ad1,
                            float* __restrict__ s0, float* __restrict__ d0,
                            float* __restrict__ s1, float* __restrict__ d1, int n) {
  constexpr int VEC = F / 64;
  int w = threadIdx.x >> 6, lane = threadIdx.x & 63;
  int nn = blockIdx.x * 4 + w;
  if (nn >= n) return;
  int f0 = lane * VEC;
  float hv[VEC];
  if constexpr (VEC == 4) {
    uint2 u = *(const uint2*)&h[(size_t)nn * F + f0];
    hv[0] = bf2f((unsigned short)(u.x & 0xffff));
    hv[1] = bf2f((unsigned short)(u.x >> 16));
    hv[2] = bf2f((unsigned short)(u.y & 0xffff));
    hv[3] = bf2f((unsigned short)(u.y >> 16));
  } else {
    unsigned int u = *(const unsigned int*)&h[(size_t)nn * F + f0];
    hv[0] = bf2f((unsigned short)(u & 0xffff));
    hv[1] = bf2f((unsigned short)(u >> 16));
  }
  float v0 = 0.f, w0 = 0.f, v1 = 0.f, w1 = 0.f;
#pragma unroll
  for (int v = 0; v < VEC; ++v) {
    v0 += hv[v] * as0[f0 + v];
    w0 += hv[v] * ad0[f0 + v];
    v1 += hv[v] * as1[f0 + v];
    w1 += hv[v] * ad1[f0 + v];
  }
  // head boundary == 16-lane group in both layers (D/VEC == 16)
#pragma unroll
  for (int off = 8; off > 0; off >>= 1) {
    v0 += __shfl_xor(v0, off, 16);
    w0 += __shfl_xor(w0, off, 16);
    v1 += __shfl_xor(v1, off, 16);
    w1 += __shfl_xor(w1, off, 16);
  }
  if ((lane & 15) == 0) {
    int idx = nn * NHEAD + (lane >> 4);
    s0[idx] = v0; d0[idx] = w0;
    s1[idx] = v1; d1[idx] = w1;
  }
}

// ---- fused per-dst softmax + weighted gather + relu; wave/node, 4-edge unroll ----
// both relations in ONE launch (r = blockIdx.x >= half) -> shared-h L3 reuse
__device__ __forceinline__ void acc4(uint2 hv, float v, float* acc) {
  acc[0] += v * bf2f((unsigned short)(hv.x & 0xffff));
  acc[1] += v * bf2f((unsigned short)(hv.x >> 16));
  acc[2] += v * bf2f((unsigned short)(hv.y & 0xffff));
  acc[3] += v * bf2f((unsigned short)(hv.y >> 16));
}
__device__ __forceinline__ void acc2(unsigned int hv, float v, float* acc) {
  acc[0] += v * bf2f((unsigned short)(hv & 0xffff));
  acc[1] += v * bf2f((unsigned short)(hv >> 16));
}
__device__ __forceinline__ float ecoef(float sv, float dv) {
  float a = sv + dv;
  a = (a >= 0.f) ? a : 0.2f * a;
  return __expf(a);  // segment_max skipped: cancels in softmax, alpha is O(1)
}

template <int F, int D>
__global__ void message2_kernel(const unsigned short* __restrict__ h,
                                const int* __restrict__ cs0, const int* __restrict__ rp0,
                                const float* __restrict__ s0, const float* __restrict__ d0,
                                unsigned short* __restrict__ o0,
                                const int* __restrict__ cs1, const int* __restrict__ rp1,
                                const float* __restrict__ s1, const float* __restrict__ d1,
                                unsigned short* __restrict__ o1,
                                int N, int half) {
  constexpr int VEC = F / 64;
  int b = blockIdx.x;
  const int* colsrc; const int* rp; const float* s; const float* d;
  unsigned short* out;
  if (b < half) { colsrc = cs0; rp = rp0; s = s0; d = d0; out = o0; }
  else { b -= half; colsrc = cs1; rp = rp1; s = s1; d = d1; out = o1; }
  int w = threadIdx.x >> 6;
  int lane = threadIdx.x & 63;
  int nn = b * 4 + w;
  if (nn >= N) return;
  int f0 = lane * VEC;
  int hh = f0 / D;
  float dv = d[nn * NHEAD + hh];
  int lo = rp[nn], hi = rp[nn + 1];
  float acc[VEC];
#pragma unroll
  for (int v = 0; v < VEC; ++v) acc[v] = 0.f;
  float den = 0.f;
  int j = lo;
  for (; j + 4 <= hi; j += 4) {
    int c0 = colsrc[j], c1 = colsrc[j + 1], c2 = colsrc[j + 2], c3 = colsrc[j + 3];
    float e0 = s[c0 * NHEAD + hh], e1 = s[c1 * NHEAD + hh];
    float e2 = s[c2 * NHEAD + hh], e3 = s[c3 * NHEAD + hh];
    if constexpr (VEC == 4) {
      uint2 h0 = *(const uint2*)&h[(size_t)c0 * F + f0];
      uint2 h1 = *(const uint2*)&h[(size_t)c1 * F + f0];
      uint2 h2 = *(const uint2*)&h[(size_t)c2 * F + f0];
      uint2 h3 = *(const uint2*)&h[(size_t)c3 * F + f0];
      float v0 = ecoef(e0, dv), v1 = ecoef(e1, dv);
      float v2 = ecoef(e2, dv), v3 = ecoef(e3, dv);
      den += v0 + v1 + v2 + v3;
      acc4(h0, v0, acc); acc4(h1, v1, acc);
      acc4(h2, v2, acc); acc4(h3, v3, acc);
    } else {
      unsigned int h0 = *(const unsigned int*)&h[(size_t)c0 * F + f0];
      unsigned int h1 = *(const unsigned int*)&h[(size_t)c1 * F + f0];
      unsigned int h2 = *(const unsigned int*)&h[(size_t)c2 * F + f0];
      unsigned int h3 = *(const unsigned int*)&h[(size_t)c3 * F + f0];
      float v0 = ecoef(e0, dv), v1 = ecoef(e1, dv);
      float v2 = ecoef(e2, dv), v3 = ecoef(e3, dv);
      den += v0 + v1 + v2 + v3;
      acc2(h0, v0, acc); acc2(h1, v1, acc);
      acc2(h2, v2, acc); acc2(h3, v3, acc);
    }
  }
  for (; j < hi; ++j) {
    int c = colsrc[j];
    float v = ecoef(s[c * NHEAD + hh], dv);
    den += v;
    if constexpr (VEC == 4) acc4(*(const uint2*)&h[(size_t)c * F + f0], v, acc);
    else acc2(*(const unsigned int*)&h[(size_t)c * F + f0], v, acc);
  }
  float inv = 1.f / (den + 1e-16f);
  if constexpr (VEC == 4) {
    uint2 o;
    o.x = (unsigned)f2bf(fmaxf(acc[0] * inv, 0.f)) |
          ((unsigned)f2bf(fmaxf(acc[1] * inv, 0.f)) << 16);
    o.y = (unsigned)f2bf(fmaxf(acc[2] * inv, 0.f)) |
          ((unsigned)f2bf(fmaxf(acc[3] * inv, 0.f)) << 16);
    *(uint2*)&out[(size_t)nn * F + f0] = o;
  } else {
    unsigned int o = (unsigned)f2bf(fmaxf(acc[0] * inv, 0.f)) |
                     ((unsigned)f2bf(fmaxf(acc[1] * inv, 0.f)) << 16);
    *(unsigned int*)&out[(size_t)nn * F + f0] = o;
  }
}

// ---------------- attn = softmax_r( mean_w_r . q ) ----------------
template <int F>
__global__ void attn_kernel(const float* __restrict__ wsum, const float* __restrict__ q,
                            float* __restrict__ attn, float inv_n) {
  __shared__ float red[2][F / 64];
  int f = threadIdx.x;
  float qv = q[f];
  float v0 = wsum[f] * inv_n * qv;
  float v1 = wsum[F + f] * inv_n * qv;
#pragma unroll
  for (int off = 32; off > 0; off >>= 1) {
    v0 += __shfl_down(v0, off, 64);
    v1 += __shfl_down(v1, off, 64);
  }
  int w = f / 64;
  if ((f & 63) == 0) { red[0][w] = v0; red[1][w] = v1; }
  __syncthreads();
  if (f == 0) {
    float d0 = 0.f, d1 = 0.f;
#pragma unroll
    for (int i = 0; i < F / 64; ++i) { d0 += red[0][i]; d1 += red[1][i]; }
    float m = fmaxf(d0, d1);
    float e0 = expf(d0 - m), e1 = expf(d1 - m);
    float inv = 1.f / (e0 + e1);
    attn[0] = e0 * inv;
    attn[1] = e1 * inv;
  }
}

// ------- pool with layer-2 combine fused (PCH=16 -> 3125 blocks, 1 wave each) -------
__global__ void pool_fused_kernel(const unsigned short* __restrict__ st0,
                                  const unsigned short* __restrict__ st1,
                                  const float* __restrict__ attn,
                                  const int* __restrict__ batch,
                                  float* __restrict__ psum, int n) {
  int c0 = blockIdx.x * PCH;
  if (c0 >= n) return;
  int lane = threadIdx.x;  // 64; 2 features each
  float a0 = attn[0], a1 = attn[1];
  int end = min(c0 + PCH, n);
  int g_cur = batch[c0];
  float acc0 = 0.f, acc1 = 0.f;
  for (int nn = c0; nn < end; ++nn) {
    int g = batch[nn];
    if (g != g_cur) {
      atomicAdd(&psum[g_cur * 128 + lane * 2], acc0);
      atomicAdd(&psum[g_cur * 128 + lane * 2 + 1], acc1);
      acc0 = acc1 = 0.f;
      g_cur = g;
    }
    unsigned int u0 = *(const unsigned int*)&st0[(size_t)nn * 128 + lane * 2];
    unsigned int u1 = *(const unsigned int*)&st1[(size_t)nn * 128 + lane * 2];
    // combine(st0,st1) rounded to bf16 to match prior numerics
    acc0 += bf2f(f2bf(a0 * bf2f((unsigned short)(u0 & 0xffff)) +
                      a1 * bf2f((unsigned short)(u1 & 0xffff))));
    acc1 += bf2f(f2bf(a0 * bf2f((unsigned short)(u0 >> 16)) +
                      a1 * bf2f((unsigned short)(u1 >> 16))));
  }
  atomicAdd(&psum[g_cur * 128 + lane * 2], acc0);
  atomicAdd(&psum[g_cur * 128 + lane * 2 + 1], acc1);
}

__device__ __forceinline__ int lower_bound_i(const int* a, int n, int key) {
  int lo = 0, hi = n;
  while (lo < hi) {
    int mid = (lo + hi) >> 1;
    if (a[mid] < key) lo = mid + 1; else hi = mid;
  }
  return lo;
}

// ------- fused pool-final + MLP head: G blocks x 128 threads -------
__global__ void poolhead_kernel(const float* __restrict__ psum, const int* __restrict__ batch,
                                int n, const float* __restrict__ d1w,
                                const float* __restrict__ d1b, const float* __restrict__ gamma,
                                const float* __restrict__ beta, const float* __restrict__ mean,
                                const float* __restrict__ var, const float* __restrict__ d2w,
                                const float* __restrict__ d2b, float* __restrict__ out) {
  __shared__ float pool_sh[128];
  int g = blockIdx.x;
  int f = threadIdx.x;  // 128
  int lo = lower_bound_i(batch, n, g);
  int hi = lower_bound_i(batch, n, g + 1);
  float cnt = fmaxf((float)(hi - lo), 1.f);
  pool_sh[f] = psum[g * 128 + f] / cnt;
  __syncthreads();
  if (f < 64) {
    float acc = d1b[f];
#pragma unroll 8
    for (int k = 0; k < 128; ++k) acc += pool_sh[k] * d1w[k * 64 + f];
    float z = (acc - mean[f]) / sqrtf(var[f] + 1e-5f) * gamma[f] + beta[f];
    z = (z >= 0.f) ? z : 0.1f * z;
    float t = z * d2w[f];
#pragma unroll
    for (int off = 32; off > 0; off >>= 1) t += __shfl_down(t, off, 64);
    if (f == 0) out[g] = t + d2b[0];
  }
}

// =====================================================================
extern "C" void kernel_launch(void* const* d_in, const int* in_sizes, int n_in,
                              void* d_out, int out_size, void* d_ws, size_t ws_size,
                              hipStream_t stream) {
  const float* x      = (const float*)d_in[0];
  const int* ei0      = (const int*)d_in[1];
  const int* ei1      = (const int*)d_in[2];
  const int* batch    = (const int*)d_in[3];
  const float* p1w    = (const float*)d_in[4];
  const float* p1b    = (const float*)d_in[5];
  const float* as1r0  = (const float*)d_in[6];
  const float* ad1r0  = (const float*)d_in[7];
  const float* as1r1  = (const float*)d_in[8];
  const float* ad1r1  = (const float*)d_in[9];
  const float* kl1w   = (const float*)d_in[10];
  const float* kl1b   = (const float*)d_in[11];
  const float* q1     = (const float*)d_in[12];
  const float* p2w    = (const float*)d_in[13];
  const float* p2b    = (const float*)d_in[14];
  const float* as2r0  = (const float*)d_in[15];
  const float* ad2r0  = (const float*)d_in[16];
  const float* as2r1  = (const float*)d_in[17];
  const float* ad2r1  = (const float*)d_in[18];
  const float* kl2w   = (const float*)d_in[19];
  const float* kl2b   = (const float*)d_in[20];
  const float* q2     = (const float*)d_in[21];
  const float* d1w    = (const float*)d_in[22];
  const float* d1b    = (const float*)d_in[23];
  const float* bng    = (const float*)d_in[24];
  const float* bnb    = (const float*)d_in[25];
  const float* bnm    = (const float*)d_in[26];
  const float* bnv    = (const float*)d_in[27];
  const float* d2w    = (const float*)d_in[28];
  const float* d2b    = (const float*)d_in[29];
  float* out = (float*)d_out;

  const int N = in_sizes[3];       // 50000
  const int E = in_sizes[1] / 2;   // 400000
  const int G = 64;

  char* p = (char*)d_ws;
  auto alloc = [&](size_t bytes) -> void* {
    void* r = (void*)p;
    p += (bytes + 255) & ~(size_t)255;
    return r;
  };
  int* rp0    = (int*)alloc((N + 1) * sizeof(int));
  int* rp1    = (int*)alloc((N + 1) * sizeof(int));
  int* cs0    = (int*)alloc(E * sizeof(int));        // src per CSR slot
  int* cs1    = (int*)alloc(E * sizeof(int));
  int* deg    = (int*)alloc(2 * (size_t)N * sizeof(int));
  int* incl   = (int*)alloc(2 * (size_t)N * sizeof(int));
  int* cur    = (int*)alloc(2 * (size_t)N * sizeof(int));
  int* bsum   = (int*)alloc(512 * sizeof(int));
  unsigned short* h_bf  = (unsigned short*)alloc((size_t)N * 256 * 2);
  unsigned short* st0   = (unsigned short*)alloc((size_t)N * 256 * 2);
  unsigned short* st1   = (unsigned short*)alloc((size_t)N * 256 * 2);
  unsigned short* h2_bf = (unsigned short*)alloc((size_t)N * 128 * 2);
  unsigned short* p1wt  = (unsigned short*)alloc(128 * 256 * 2);
  unsigned short* p2wt  = (unsigned short*)alloc(256 * 128 * 2);
  unsigned short* k1wt  = (unsigned short*)alloc(256 * 256 * 2);
  unsigned short* k2wt  = (unsigned short*)alloc(128 * 128 * 2);
  float* s0     = (float*)alloc((size_t)N * NHEAD * sizeof(float));
  float* d0     = (float*)alloc((size_t)N * NHEAD * sizeof(float));
  float* s1     = (float*)alloc((size_t)N * NHEAD * sizeof(float));
  float* d1     = (float*)alloc((size_t)N * NHEAD * sizeof(float));
  float* wsum   = (float*)alloc(2 * 256 * sizeof(float));
  float* attn1  = (float*)alloc(2 * sizeof(float));
  float* attn2  = (float*)alloc(2 * sizeof(float));
  float* psum   = (float*)alloc((size_t)G * 128 * sizeof(float));

  // ---- weights ----
  wtrans_all_kernel<<<576, 256, 0, stream>>>(p1w, p2w, kl1w, kl2w, p1wt, p2wt, k1wt, k2wt);

  // ---- CSR build (both relations batched) ----
  int nb = (N + 255) / 256;
  int e2blk = (2 * E + 255) / 256;
  hipMemsetAsync(deg, 0, 2 * (size_t)N * sizeof(int), stream);
  hist2_kernel<<<e2blk, 256, 0, stream>>>(ei0, ei1, E, deg, N);
  scan_local2_kernel<<<2 * nb, 256, 0, stream>>>(deg, incl, bsum, N, nb);
  scan_bsum2_kernel<<<2, 256, 0, stream>>>(bsum, nb);
  scan_fix2_kernel<<<2 * nb, 256, 0, stream>>>(incl, deg, bsum, rp0, rp1, N, nb, E);
  hipMemsetAsync(cur, 0, 2 * (size_t)N * sizeof(int), stream);
  scatter2_kernel<<<e2blk, 256, 0, stream>>>(ei0, ei1, E, rp0, rp1, cur, cs0, cs1, N);

  int gblk = (N + 63) / 64;
  int nblk4 = (N + 3) / 4;

  // ================= layer 1: 128 -> 256, D=64 =================
  mfma_gemm<128, 256, 1, 0><<<gblk, 256, 0, stream>>>(
      nullptr, x, nullptr, nullptr, nullptr, p1wt, p1b, h_bf, nullptr, N);
  sd2v_kernel<256, 64><<<nblk4, 256, 0, stream>>>(h_bf, as1r0, ad1r0, as1r1, ad1r1,
                                                  s0, d0, s1, d1, N);
  message2_kernel<256, 64><<<2 * nblk4, 256, 0, stream>>>(
      h_bf, cs0, rp0, s0, d0, st0, cs1, rp1, s1, d1, st1, N, nblk4);
  hipMemsetAsync(wsum, 0, 2 * 256 * sizeof(float), stream);
  mfma_gemm<256, 256, 0, 1><<<gblk, 256, 0, stream>>>(
      st0, nullptr, nullptr, nullptr, nullptr, k1wt, kl1b, nullptr, wsum, N);
  mfma_gemm<256, 256, 0, 1><<<gblk, 256, 0, stream>>>(
      st1, nullptr, nullptr, nullptr, nullptr, k1wt, kl1b, nullptr, wsum + 256, N);
  attn_kernel<256><<<1, 256, 0, stream>>>(wsum, q1, attn1, 1.0f / (float)N);

  // ================= layer 2: 256 -> 128, D=32 (combine fused into proj staging) ====
  mfma_gemm<256, 128, 2, 0><<<gblk, 256, 0, stream>>>(
      nullptr, nullptr, st0, st1, attn1, p2wt, p2b, h2_bf, nullptr, N);
  sd2v_kernel<128, 32><<<nblk4, 256, 0, stream>>>(h2_bf, as2r0, ad2r0, as2r1, ad2r1,
                                                  s0, d0, s1, d1, N);
  message2_kernel<128, 32><<<2 * nblk4, 256, 0, stream>>>(
      h2_bf, cs0, rp0, s0, d0, st0, cs1, rp1, s1, d1, st1, N, nblk4);
  hipMemsetAsync(wsum, 0, 2 * 256 * sizeof(float), stream);
  mfma_gemm<128, 128, 0, 1><<<gblk, 256, 0, stream>>>(
      st0, nullptr, nullptr, nullptr, nullptr, k2wt, kl2b, nullptr, wsum, N);
  mfma_gemm<128, 128, 0, 1><<<gblk, 256, 0, stream>>>(
      st1, nullptr, nullptr, nullptr, nullptr, k2wt, kl2b, nullptr, wsum + 128, N);
  attn_kernel<128><<<1, 128, 0, stream>>>(wsum, q2, attn2, 1.0f / (float)N);

  // ---- pool (combine fused) + fused final/head ----
  hipMemsetAsync(psum, 0, (size_t)G * 128 * sizeof(float), stream);
  int pblk = (N + PCH - 1) / PCH;
  pool_fused_kernel<<<pblk, 64, 0, stream>>>(st0, st1, attn2, batch, psum, N);
  poolhead_kernel<<<G, 128, 0, stream>>>(psum, batch, N, d1w, d1b, bng, bnb, bnm, bnv,
                                         d2w, d2b, out);
}

// Round 8
// 445.236 us; speedup vs baseline: 4.4982x; 1.2117x over previous
//
#include <hip/hip_runtime.h>
#include <math.h>

#define NHEAD 4
#define PCH 16

typedef __bf16 bf16x8 __attribute__((ext_vector_type(8)));
typedef float f32x4 __attribute__((ext_vector_type(4)));

__device__ __forceinline__ unsigned short f2bf(float f) {
  unsigned int u = __float_as_uint(f);
  u += 0x7FFF + ((u >> 16) & 1);  // round-to-nearest-even
  return (unsigned short)(u >> 16);
}
__device__ __forceinline__ float bf2f(unsigned short s) {
  return __uint_as_float(((unsigned int)s) << 16);
}
__device__ __forceinline__ unsigned int comb2(unsigned int p, unsigned int q,
                                              float a0, float a1) {
  float lo = a0 * bf2f((unsigned short)p) + a1 * bf2f((unsigned short)q);
  float hi = a0 * bf2f((unsigned short)(p >> 16)) + a1 * bf2f((unsigned short)(q >> 16));
  return (unsigned)f2bf(lo) | ((unsigned)f2bf(hi) << 16);
}
__device__ __forceinline__ float fast_tanh(float x) {
  x = fminf(fmaxf(x, -15.f), 15.f);
  float e = __expf(2.f * x);
  return (e - 1.f) / (e + 1.f);
}

// ============ combined: weight transpose+cast (blocks < wblk) + dst histogram ============
__global__ void wtrans_hist_kernel(const float* __restrict__ p1w, const float* __restrict__ p2w,
                                   const float* __restrict__ k1w, const float* __restrict__ k2w,
                                   unsigned short* __restrict__ p1wt,
                                   unsigned short* __restrict__ p2wt,
                                   unsigned short* __restrict__ k1wt,
                                   unsigned short* __restrict__ k2wt,
                                   const int* __restrict__ ei0, const int* __restrict__ ei1,
                                   int E, int* __restrict__ deg, int N, int wblk) {
  if ((int)blockIdx.x < wblk) {
    int i = blockIdx.x * 256 + threadIdx.x;
    if (i < 32768) {                      // p1: [128,256]
      int k = i >> 8, f = i & 255;
      p1wt[f * 128 + k] = f2bf(p1w[i]);
    } else if (i < 65536) {               // p2: [256,128]
      int j = i - 32768; int k = j >> 7, f = j & 127;
      p2wt[f * 256 + k] = f2bf(p2w[j]);
    } else if (i < 131072) {              // k1: [256,256]
      int j = i - 65536; int k = j >> 8, f = j & 255;
      k1wt[f * 256 + k] = f2bf(k1w[j]);
    } else if (i < 147456) {              // k2: [128,128]
      int j = i - 131072; int k = j >> 7, f = j & 127;
      k2wt[f * 128 + k] = f2bf(k2w[j]);
    }
  } else {
    int i = (blockIdx.x - wblk) * 256 + threadIdx.x;
    if (i < 2 * E) {
      int r = i >= E;
      int e = i - (r ? E : 0);
      const int* ei = r ? ei1 : ei0;
      atomicAdd(&deg[r * N + ei[E + e]], 1);
    }
  }
}

__global__ void scan_local2_kernel(const int* __restrict__ deg, int* __restrict__ incl,
                                   int* __restrict__ bsum, int n, int nb) {
  __shared__ int tile[256];
  int r = blockIdx.x / nb;
  int b = blockIdx.x - r * nb;
  int i = b * 256 + threadIdx.x;
  int v = (i < n) ? deg[r * n + i] : 0;
  tile[threadIdx.x] = v;
  __syncthreads();
  for (int off = 1; off < 256; off <<= 1) {
    int t = (threadIdx.x >= (unsigned)off) ? tile[threadIdx.x - off] : 0;
    __syncthreads();
    tile[threadIdx.x] += t;
    __syncthreads();
  }
  if (i < n) incl[r * n + i] = tile[threadIdx.x];
  if (threadIdx.x == 255) bsum[blockIdx.x] = tile[255];
}

__global__ void scan_bsum2_kernel(int* __restrict__ bsum, int nb) {
  __shared__ int tile[256];
  int r = blockIdx.x;
  int v = (threadIdx.x < (unsigned)nb) ? bsum[r * nb + threadIdx.x] : 0;
  tile[threadIdx.x] = v;
  __syncthreads();
  for (int off = 1; off < 256; off <<= 1) {
    int t = (threadIdx.x >= (unsigned)off) ? tile[threadIdx.x - off] : 0;
    __syncthreads();
    tile[threadIdx.x] += t;
    __syncthreads();
  }
  if (threadIdx.x < (unsigned)nb) bsum[r * nb + threadIdx.x] = tile[threadIdx.x] - v;
}

__global__ void scan_fix2_kernel(const int* __restrict__ incl, const int* __restrict__ deg,
                                 const int* __restrict__ bsum, int* __restrict__ rp0,
                                 int* __restrict__ rp1, int n, int nb, int E) {
  int r = blockIdx.x / nb;
  int b = blockIdx.x - r * nb;
  int i = b * 256 + threadIdx.x;
  int* rp = r ? rp1 : rp0;
  if (i < n) rp[i] = incl[r * n + i] - deg[r * n + i] + bsum[blockIdx.x];
  if (i == 0) rp[n] = E;
}

__global__ void scatter2_kernel(const int* __restrict__ ei0, const int* __restrict__ ei1,
                                int E, const int* __restrict__ rp0, const int* __restrict__ rp1,
                                int* __restrict__ cur, int* __restrict__ cs0,
                                int* __restrict__ cs1, int N) {
  int i = blockIdx.x * blockDim.x + threadIdx.x;
  int tot = 2 * E;
  for (; i < tot; i += gridDim.x * blockDim.x) {
    int r = i >= E;
    int e = i - (r ? E : 0);
    const int* ei = r ? ei1 : ei0;
    const int* rp = r ? rp1 : rp0;
    int* cs = r ? cs1 : cs0;
    int dst = ei[E + e];
    int pos = rp[dst] + atomicAdd(&cur[r * N + dst], 1);
    cs[pos] = ei[e];  // src node id
  }
}

// =============== MFMA GEMM core: 64 rows x F cols/block, 256 thr, 16x16x32 bf16 ===============
#define MFMA_GEMM_CORE(K, F, BX)                                                      \
  constexpr int G = F / 64, S = 4 / G, RT = 4 / S;                                    \
  __shared__ unsigned short As[64][40]; /* pad 40: bank spread, rows 16B-aligned */   \
  const int tid = threadIdx.x;                                                        \
  const int lane = tid & 63, wid = tid >> 6;                                          \
  const int cg = wid % G, rg = wid / G;                                               \
  const int l15 = lane & 15, l4 = lane >> 4;                                          \
  const int m0 = (BX)*64;                                                             \
  const int wrow = rg * RT * 16;                                                      \
  f32x4 acc[RT][4];                                                                   \
  _Pragma("unroll") for (int rt = 0; rt < RT; ++rt)                                   \
  _Pragma("unroll") for (int ct = 0; ct < 4; ++ct)                                    \
      acc[rt][ct] = (f32x4){0.f, 0.f, 0.f, 0.f};                                      \
  const int arow = tid >> 2;                                                          \
  const int akk = (tid & 3) * 8;                                                      \
  for (int k0 = 0; k0 < K; k0 += 32) {                                                \
    uint4 av = {0u, 0u, 0u, 0u};                                                      \
    int row = m0 + arow;                                                              \
    if (row < M) { MFMA_LOAD_A }                                                      \
    __syncthreads();                                                                  \
    *(uint4*)&As[arow][akk] = av;                                                     \
    __syncthreads();                                                                  \
    bf16x8 bfr[4];                                                                    \
    _Pragma("unroll") for (int ct = 0; ct < 4; ++ct) {                                \
      int colx = cg * 64 + ct * 16 + l15;                                             \
      bfr[ct] = *(const bf16x8*)&Wt[(size_t)colx * K + k0 + l4 * 8];                  \
    }                                                                                 \
    _Pragma("unroll") for (int rt = 0; rt < RT; ++rt) {                               \
      bf16x8 afr = *(const bf16x8*)&As[wrow + rt * 16 + l15][l4 * 8];                 \
      _Pragma("unroll") for (int ct = 0; ct < 4; ++ct)                                \
        acc[rt][ct] = __builtin_amdgcn_mfma_f32_16x16x32_bf16(                        \
            afr, bfr[ct], acc[rt][ct], 0, 0, 0);                                      \
    }                                                                                 \
  }

// ---- proj GEMM with fused bias store + s/d epilogue ----
// MODE: 1 = A fp32 (convert in staging); 2 = A = bf16(a0*S0 + a1*S1)
template <int K, int F, int MODE, int DD>
__global__ __launch_bounds__(256) void mfma_gemm_proj(
    const float* __restrict__ Af,
    const unsigned short* __restrict__ S0, const unsigned short* __restrict__ S1,
    const float* __restrict__ attnp, const unsigned short* __restrict__ Wt,
    const float* __restrict__ bias, unsigned short* __restrict__ out,
    const float* __restrict__ as0v, const float* __restrict__ ad0v,
    const float* __restrict__ as1v, const float* __restrict__ ad1v,
    float* __restrict__ s0g, float* __restrict__ d0g,
    float* __restrict__ s1g, float* __restrict__ d1g, int M) {
  float ca0 = 0.f, ca1 = 0.f;
  if constexpr (MODE == 2) { ca0 = attnp[0]; ca1 = attnp[1]; }
#define MFMA_LOAD_A                                                                   \
  if constexpr (MODE == 1) {                                                          \
    float4 f0 = *(const float4*)&Af[(size_t)row * K + k0 + akk];                      \
    float4 f1 = *(const float4*)&Af[(size_t)row * K + k0 + akk + 4];                  \
    av.x = (unsigned)f2bf(f0.x) | ((unsigned)f2bf(f0.y) << 16);                       \
    av.y = (unsigned)f2bf(f0.z) | ((unsigned)f2bf(f0.w) << 16);                       \
    av.z = (unsigned)f2bf(f1.x) | ((unsigned)f2bf(f1.y) << 16);                       \
    av.w = (unsigned)f2bf(f1.z) | ((unsigned)f2bf(f1.w) << 16);                       \
  } else {                                                                            \
    uint4 u0 = *(const uint4*)&S0[(size_t)row * K + k0 + akk];                        \
    uint4 u1 = *(const uint4*)&S1[(size_t)row * K + k0 + akk];                        \
    av.x = comb2(u0.x, u1.x, ca0, ca1);                                               \
    av.y = comb2(u0.y, u1.y, ca0, ca1);                                               \
    av.z = comb2(u0.z, u1.z, ca0, ca1);                                               \
    av.w = comb2(u0.w, u1.w, ca0, ca1);                                               \
  }
  MFMA_GEMM_CORE(K, F, blockIdx.x)
#undef MFMA_LOAD_A
  // ---- bf16 h store ----
#pragma unroll
  for (int ct = 0; ct < 4; ++ct) {
    int n = cg * 64 + ct * 16 + l15;
    float bv = bias[n];
#pragma unroll
    for (int rt = 0; rt < RT; ++rt)
#pragma unroll
      for (int r = 0; r < 4; ++r) {
        int m = m0 + wrow + rt * 16 + l4 * 4 + r;
        if (m < M) out[(size_t)m * F + n] = f2bf(acc[rt][ct][r] + bv);
      }
  }
  // ---- fused s/d epilogue: per-head column reductions ----
  constexpr int HPW = 64 / DD, CTH = DD / 16;
#pragma unroll
  for (int hw = 0; hw < HPW; ++hw) {
    int head = cg * HPW + hw;
    float a0v[CTH], a1v[CTH], a2v[CTH], a3v[CTH], bvv[CTH];
#pragma unroll
    for (int c = 0; c < CTH; ++c) {
      int col = cg * 64 + (hw * CTH + c) * 16 + l15;
      a0v[c] = as0v[col]; a1v[c] = ad0v[col];
      a2v[c] = as1v[col]; a3v[c] = ad1v[col];
      bvv[c] = bias[col];
    }
#pragma unroll
    for (int rt = 0; rt < RT; ++rt) {
#pragma unroll
      for (int r = 0; r < 4; ++r) {
        float v0 = 0.f, v1 = 0.f, v2 = 0.f, v3 = 0.f;
#pragma unroll
        for (int c = 0; c < CTH; ++c) {
          float hval = acc[rt][hw * CTH + c][r] + bvv[c];
          v0 += hval * a0v[c]; v1 += hval * a1v[c];
          v2 += hval * a2v[c]; v3 += hval * a3v[c];
        }
#pragma unroll
        for (int off = 8; off > 0; off >>= 1) {
          v0 += __shfl_xor(v0, off, 16);
          v1 += __shfl_xor(v1, off, 16);
          v2 += __shfl_xor(v2, off, 16);
          v3 += __shfl_xor(v3, off, 16);
        }
        if (l15 == 0) {
          int m = m0 + wrow + rt * 16 + l4 * 4 + r;
          if (m < M) {
            int idx = m * NHEAD + head;
            s0g[idx] = v0; d0g[idx] = v1;
            s1g[idx] = v2; d1g[idx] = v3;
          }
        }
      }
    }
  }
}

// ---- semantic GEMM, both relations in one launch: wsum[f] += sum_rows tanh(A@W + b) ----
template <int K, int F>
__global__ __launch_bounds__(256) void mfma_gemm_tanh2(
    const unsigned short* __restrict__ A0, const unsigned short* __restrict__ A1,
    const unsigned short* __restrict__ Wt, const float* __restrict__ bias,
    float* __restrict__ wsum, int M, int half) {
  const unsigned short* A;
  float* ws;
  int bx = blockIdx.x;
  if (bx < half) { A = A0; ws = wsum; }
  else { A = A1; ws = wsum + F; bx -= half; }
#define MFMA_LOAD_A av = *(const uint4*)&A[(size_t)row * K + k0 + akk];
  MFMA_GEMM_CORE(K, F, bx)
#undef MFMA_LOAD_A
#pragma unroll
  for (int ct = 0; ct < 4; ++ct) {
    int n = cg * 64 + ct * 16 + l15;
    float bv = bias[n];
    float cs = 0.f;
#pragma unroll
    for (int rt = 0; rt < RT; ++rt)
#pragma unroll
      for (int r = 0; r < 4; ++r) {
        int m = m0 + wrow + rt * 16 + l4 * 4 + r;
        if (m < M) cs += fast_tanh(acc[rt][ct][r] + bv);
      }
    cs += __shfl_xor(cs, 16, 64);
    cs += __shfl_xor(cs, 32, 64);
    if (l4 == 0) atomicAdd(&ws[n], cs);
  }
}

// ---- fused per-dst softmax + weighted gather + relu; wave/node, 4-edge unroll ----
// both relations in ONE launch; block 0 zeroes wsum (FULL 2F, strided) for next GEMM
__device__ __forceinline__ void acc4(uint2 hv, float v, float* acc) {
  acc[0] += v * bf2f((unsigned short)(hv.x & 0xffff));
  acc[1] += v * bf2f((unsigned short)(hv.x >> 16));
  acc[2] += v * bf2f((unsigned short)(hv.y & 0xffff));
  acc[3] += v * bf2f((unsigned short)(hv.y >> 16));
}
__device__ __forceinline__ void acc2(unsigned int hv, float v, float* acc) {
  acc[0] += v * bf2f((unsigned short)(hv & 0xffff));
  acc[1] += v * bf2f((unsigned short)(hv >> 16));
}
__device__ __forceinline__ float ecoef(float sv, float dv) {
  float a = sv + dv;
  a = (a >= 0.f) ? a : 0.2f * a;
  return __expf(a);  // segment_max skipped: cancels in softmax, alpha is O(1)
}

template <int F, int D>
__global__ void message2_kernel(const unsigned short* __restrict__ h,
                                const int* __restrict__ cs0, const int* __restrict__ rp0,
                                const float* __restrict__ s0, const float* __restrict__ d0,
                                unsigned short* __restrict__ o0,
                                const int* __restrict__ cs1, const int* __restrict__ rp1,
                                const float* __restrict__ s1, const float* __restrict__ d1,
                                unsigned short* __restrict__ o1,
                                float* __restrict__ wsum,  // zeroed by block 0 (2F floats)
                                int N, int half) {
  constexpr int VEC = F / 64;
  // BUGFIX r7: strided loop — 2F can exceed blockDim (F=256 -> 512 floats).
  // Partial zero left wsum[256..511] accumulating across graph replays.
  if (blockIdx.x == 0) {
    for (int i = threadIdx.x; i < 2 * F; i += 256) wsum[i] = 0.f;
  }
  int b = blockIdx.x;
  const int* colsrc; const int* rp; const float* s; const float* d;
  unsigned short* out;
  if (b < half) { colsrc = cs0; rp = rp0; s = s0; d = d0; out = o0; }
  else { b -= half; colsrc = cs1; rp = rp1; s = s1; d = d1; out = o1; }
  int w = threadIdx.x >> 6;
  int lane = threadIdx.x & 63;
  int nn = b * 4 + w;
  if (nn >= N) return;
  int f0 = lane * VEC;
  int hh = f0 / D;
  float dv = d[nn * NHEAD + hh];
  int lo = rp[nn], hi = rp[nn + 1];
  float acc[VEC];
#pragma unroll
  for (int v = 0; v < VEC; ++v) acc[v] = 0.f;
  float den = 0.f;
  int j = lo;
  for (; j + 4 <= hi; j += 4) {
    int c0 = colsrc[j], c1 = colsrc[j + 1], c2 = colsrc[j + 2], c3 = colsrc[j + 3];
    float e0 = s[c0 * NHEAD + hh], e1 = s[c1 * NHEAD + hh];
    float e2 = s[c2 * NHEAD + hh], e3 = s[c3 * NHEAD + hh];
    if constexpr (VEC == 4) {
      uint2 h0 = *(const uint2*)&h[(size_t)c0 * F + f0];
      uint2 h1 = *(const uint2*)&h[(size_t)c1 * F + f0];
      uint2 h2 = *(const uint2*)&h[(size_t)c2 * F + f0];
      uint2 h3 = *(const uint2*)&h[(size_t)c3 * F + f0];
      float v0 = ecoef(e0, dv), v1 = ecoef(e1, dv);
      float v2 = ecoef(e2, dv), v3 = ecoef(e3, dv);
      den += v0 + v1 + v2 + v3;
      acc4(h0, v0, acc); acc4(h1, v1, acc);
      acc4(h2, v2, acc); acc4(h3, v3, acc);
    } else {
      unsigned int h0 = *(const unsigned int*)&h[(size_t)c0 * F + f0];
      unsigned int h1 = *(const unsigned int*)&h[(size_t)c1 * F + f0];
      unsigned int h2 = *(const unsigned int*)&h[(size_t)c2 * F + f0];
      unsigned int h3 = *(const unsigned int*)&h[(size_t)c3 * F + f0];
      float v0 = ecoef(e0, dv), v1 = ecoef(e1, dv);
      float v2 = ecoef(e2, dv), v3 = ecoef(e3, dv);
      den += v0 + v1 + v2 + v3;
      acc2(h0, v0, acc); acc2(h1, v1, acc);
      acc2(h2, v2, acc); acc2(h3, v3, acc);
    }
  }
  for (; j < hi; ++j) {
    int c = colsrc[j];
    float v = ecoef(s[c * NHEAD + hh], dv);
    den += v;
    if constexpr (VEC == 4) acc4(*(const uint2*)&h[(size_t)c * F + f0], v, acc);
    else acc2(*(const unsigned int*)&h[(size_t)c * F + f0], v, acc);
  }
  float inv = 1.f / (den + 1e-16f);
  if constexpr (VEC == 4) {
    uint2 o;
    o.x = (unsigned)f2bf(fmaxf(acc[0] * inv, 0.f)) |
          ((unsigned)f2bf(fmaxf(acc[1] * inv, 0.f)) << 16);
    o.y = (unsigned)f2bf(fmaxf(acc[2] * inv, 0.f)) |
          ((unsigned)f2bf(fmaxf(acc[3] * inv, 0.f)) << 16);
    *(uint2*)&out[(size_t)nn * F + f0] = o;
  } else {
    unsigned int o = (unsigned)f2bf(fmaxf(acc[0] * inv, 0.f)) |
                     ((unsigned)f2bf(fmaxf(acc[1] * inv, 0.f)) << 16);
    *(unsigned int*)&out[(size_t)nn * F + f0] = o;
  }
}

// ---------------- attn = softmax_r( mean_w_r . q ); optionally zero psum ----------------
template <int F, bool ZP>
__global__ void attn_kernel(const float* __restrict__ wsum, const float* __restrict__ q,
                            float* __restrict__ attn, float inv_n,
                            float* __restrict__ psum, int pn) {
  __shared__ float red[2][F / 64];
  int f = threadIdx.x;
  if constexpr (ZP) {
    for (int i = f; i < pn; i += F) psum[i] = 0.f;
  }
  float qv = q[f];
  float v0 = wsum[f] * inv_n * qv;
  float v1 = wsum[F + f] * inv_n * qv;
#pragma unroll
  for (int off = 32; off > 0; off >>= 1) {
    v0 += __shfl_down(v0, off, 64);
    v1 += __shfl_down(v1, off, 64);
  }
  int w = f / 64;
  if ((f & 63) == 0) { red[0][w] = v0; red[1][w] = v1; }
  __syncthreads();
  if (f == 0) {
    float d0 = 0.f, d1 = 0.f;
#pragma unroll
    for (int i = 0; i < F / 64; ++i) { d0 += red[0][i]; d1 += red[1][i]; }
    float m = fmaxf(d0, d1);
    float e0 = expf(d0 - m), e1 = expf(d1 - m);
    float inv = 1.f / (e0 + e1);
    attn[0] = e0 * inv;
    attn[1] = e1 * inv;
  }
}

// ------- pool with layer-2 combine fused (PCH=16 -> 3125 blocks, 1 wave each) -------
__global__ void pool_fused_kernel(const unsigned short* __restrict__ st0,
                                  const unsigned short* __restrict__ st1,
                                  const float* __restrict__ attn,
                                  const int* __restrict__ batch,
                                  float* __restrict__ psum, int n) {
  int c0 = blockIdx.x * PCH;
  if (c0 >= n) return;
  int lane = threadIdx.x;  // 64; 2 features each
  float a0 = attn[0], a1 = attn[1];
  int end = min(c0 + PCH, n);
  int g_cur = batch[c0];
  float acc0 = 0.f, acc1 = 0.f;
  for (int nn = c0; nn < end; ++nn) {
    int g = batch[nn];
    if (g != g_cur) {
      atomicAdd(&psum[g_cur * 128 + lane * 2], acc0);
      atomicAdd(&psum[g_cur * 128 + lane * 2 + 1], acc1);
      acc0 = acc1 = 0.f;
      g_cur = g;
    }
    unsigned int u0 = *(const unsigned int*)&st0[(size_t)nn * 128 + lane * 2];
    unsigned int u1 = *(const unsigned int*)&st1[(size_t)nn * 128 + lane * 2];
    acc0 += bf2f(f2bf(a0 * bf2f((unsigned short)(u0 & 0xffff)) +
                      a1 * bf2f((unsigned short)(u1 & 0xffff))));
    acc1 += bf2f(f2bf(a0 * bf2f((unsigned short)(u0 >> 16)) +
                      a1 * bf2f((unsigned short)(u1 >> 16))));
  }
  atomicAdd(&psum[g_cur * 128 + lane * 2], acc0);
  atomicAdd(&psum[g_cur * 128 + lane * 2 + 1], acc1);
}

__device__ __forceinline__ int lower_bound_i(const int* a, int n, int key) {
  int lo = 0, hi = n;
  while (lo < hi) {
    int mid = (lo + hi) >> 1;
    if (a[mid] < key) lo = mid + 1; else hi = mid;
  }
  return lo;
}

// ------- fused pool-final + MLP head: G blocks x 128 threads -------
__global__ void poolhead_kernel(const float* __restrict__ psum, const int* __restrict__ batch,
                                int n, const float* __restrict__ d1w,
                                const float* __restrict__ d1b, const float* __restrict__ gamma,
                                const float* __restrict__ beta, const float* __restrict__ mean,
                                const float* __restrict__ var, const float* __restrict__ d2w,
                                const float* __restrict__ d2b, float* __restrict__ out) {
  __shared__ float pool_sh[128];
  int g = blockIdx.x;
  int f = threadIdx.x;  // 128
  int lo = lower_bound_i(batch, n, g);
  int hi = lower_bound_i(batch, n, g + 1);
  float cnt = fmaxf((float)(hi - lo), 1.f);
  pool_sh[f] = psum[g * 128 + f] / cnt;
  __syncthreads();
  if (f < 64) {
    float acc = d1b[f];
#pragma unroll 8
    for (int k = 0; k < 128; ++k) acc += pool_sh[k] * d1w[k * 64 + f];
    float z = (acc - mean[f]) / sqrtf(var[f] + 1e-5f) * gamma[f] + beta[f];
    z = (z >= 0.f) ? z : 0.1f * z;
    float t = z * d2w[f];
#pragma unroll
    for (int off = 32; off > 0; off >>= 1) t += __shfl_down(t, off, 64);
    if (f == 0) out[g] = t + d2b[0];
  }
}

// =====================================================================
extern "C" void kernel_launch(void* const* d_in, const int* in_sizes, int n_in,
                              void* d_out, int out_size, void* d_ws, size_t ws_size,
                              hipStream_t stream) {
  const float* x      = (const float*)d_in[0];
  const int* ei0      = (const int*)d_in[1];
  const int* ei1      = (const int*)d_in[2];
  const int* batch    = (const int*)d_in[3];
  const float* p1w    = (const float*)d_in[4];
  const float* p1b    = (const float*)d_in[5];
  const float* as1r0  = (const float*)d_in[6];
  const float* ad1r0  = (const float*)d_in[7];
  const float* as1r1  = (const float*)d_in[8];
  const float* ad1r1  = (const float*)d_in[9];
  const float* kl1w   = (const float*)d_in[10];
  const float* kl1b   = (const float*)d_in[11];
  const float* q1     = (const float*)d_in[12];
  const float* p2w    = (const float*)d_in[13];
  const float* p2b    = (const float*)d_in[14];
  const float* as2r0  = (const float*)d_in[15];
  const float* ad2r0  = (const float*)d_in[16];
  const float* as2r1  = (const float*)d_in[17];
  const float* ad2r1  = (const float*)d_in[18];
  const float* kl2w   = (const float*)d_in[19];
  const float* kl2b   = (const float*)d_in[20];
  const float* q2     = (const float*)d_in[21];
  const float* d1w    = (const float*)d_in[22];
  const float* d1b    = (const float*)d_in[23];
  const float* bng    = (const float*)d_in[24];
  const float* bnb    = (const float*)d_in[25];
  const float* bnm    = (const float*)d_in[26];
  const float* bnv    = (const float*)d_in[27];
  const float* d2w    = (const float*)d_in[28];
  const float* d2b    = (const float*)d_in[29];
  float* out = (float*)d_out;

  const int N = in_sizes[3];       // 50000
  const int E = in_sizes[1] / 2;   // 400000
  const int G = 64;

  char* p = (char*)d_ws;
  auto alloc = [&](size_t bytes) -> void* {
    void* r = (void*)p;
    p += (bytes + 255) & ~(size_t)255;
    return r;
  };
  int* rp0    = (int*)alloc((N + 1) * sizeof(int));
  int* rp1    = (int*)alloc((N + 1) * sizeof(int));
  int* cs0    = (int*)alloc(E * sizeof(int));        // src per CSR slot
  int* cs1    = (int*)alloc(E * sizeof(int));
  int* deg    = (int*)alloc(2 * (size_t)N * sizeof(int));   // deg+cur: one memset
  int* cur    = (int*)alloc(2 * (size_t)N * sizeof(int));
  int* incl   = (int*)alloc(2 * (size_t)N * sizeof(int));
  int* bsum   = (int*)alloc(512 * sizeof(int));
  unsigned short* h_bf  = (unsigned short*)alloc((size_t)N * 256 * 2);
  unsigned short* st0   = (unsigned short*)alloc((size_t)N * 256 * 2);
  unsigned short* st1   = (unsigned short*)alloc((size_t)N * 256 * 2);
  unsigned short* h2_bf = (unsigned short*)alloc((size_t)N * 128 * 2);
  unsigned short* p1wt  = (unsigned short*)alloc(128 * 256 * 2);
  unsigned short* p2wt  = (unsigned short*)alloc(256 * 128 * 2);
  unsigned short* k1wt  = (unsigned short*)alloc(256 * 256 * 2);
  unsigned short* k2wt  = (unsigned short*)alloc(128 * 128 * 2);
  float* s0     = (float*)alloc((size_t)N * NHEAD * sizeof(float));
  float* d0     = (float*)alloc((size_t)N * NHEAD * sizeof(float));
  float* s1     = (float*)alloc((size_t)N * NHEAD * sizeof(float));
  float* d1     = (float*)alloc((size_t)N * NHEAD * sizeof(float));
  float* wsum   = (float*)alloc(2 * 256 * sizeof(float));
  float* attn1  = (float*)alloc(2 * sizeof(float));
  float* attn2  = (float*)alloc(2 * sizeof(float));
  float* psum   = (float*)alloc((size_t)G * 128 * sizeof(float));

  // ---- 1: zero deg+cur (contiguous allocs -> single memset) ----
  size_t zlen = (size_t)((char*)cur - (char*)deg) + 2 * (size_t)N * sizeof(int);
  hipMemsetAsync(deg, 0, zlen, stream);

  // ---- 2: weight transpose+cast fused with dst histogram ----
  int wblk = 576;  // 147456 / 256
  int e2blk = (2 * E + 255) / 256;
  wtrans_hist_kernel<<<wblk + e2blk, 256, 0, stream>>>(
      p1w, p2w, kl1w, kl2w, p1wt, p2wt, k1wt, k2wt, ei0, ei1, E, deg, N, wblk);

  // ---- 3-6: scan + scatter ----
  int nb = (N + 255) / 256;
  scan_local2_kernel<<<2 * nb, 256, 0, stream>>>(deg, incl, bsum, N, nb);
  scan_bsum2_kernel<<<2, 256, 0, stream>>>(bsum, nb);
  scan_fix2_kernel<<<2 * nb, 256, 0, stream>>>(incl, deg, bsum, rp0, rp1, N, nb, E);
  scatter2_kernel<<<e2blk, 256, 0, stream>>>(ei0, ei1, E, rp0, rp1, cur, cs0, cs1, N);

  int gblk = (N + 63) / 64;
  int nblk4 = (N + 3) / 4;

  // ================= layer 1: 128 -> 256, D=64 =================
  mfma_gemm_proj<128, 256, 1, 64><<<gblk, 256, 0, stream>>>(
      x, nullptr, nullptr, nullptr, p1wt, p1b, h_bf,
      as1r0, ad1r0, as1r1, ad1r1, s0, d0, s1, d1, N);
  message2_kernel<256, 64><<<2 * nblk4, 256, 0, stream>>>(
      h_bf, cs0, rp0, s0, d0, st0, cs1, rp1, s1, d1, st1, wsum, N, nblk4);
  mfma_gemm_tanh2<256, 256><<<2 * gblk, 256, 0, stream>>>(
      st0, st1, k1wt, kl1b, wsum, N, gblk);
  attn_kernel<256, false><<<1, 256, 0, stream>>>(wsum, q1, attn1, 1.0f / (float)N,
                                                 nullptr, 0);

  // ================= layer 2: 256 -> 128, D=32 =================
  mfma_gemm_proj<256, 128, 2, 32><<<gblk, 256, 0, stream>>>(
      nullptr, st0, st1, attn1, p2wt, p2b, h2_bf,
      as2r0, ad2r0, as2r1, ad2r1, s0, d0, s1, d1, N);
  message2_kernel<128, 32><<<2 * nblk4, 256, 0, stream>>>(
      h2_bf, cs0, rp0, s0, d0, st0, cs1, rp1, s1, d1, st1, wsum, N, nblk4);
  mfma_gemm_tanh2<128, 128><<<2 * gblk, 256, 0, stream>>>(
      st0, st1, k2wt, kl2b, wsum, N, gblk);
  attn_kernel<128, true><<<1, 128, 0, stream>>>(wsum, q2, attn2, 1.0f / (float)N,
                                                psum, G * 128);

  // ---- pool (combine fused) + fused final/head ----
  int pblk = (N + PCH - 1) / PCH;
  pool_fused_kernel<<<pblk, 64, 0, stream>>>(st0, st1, attn2, batch, psum, N);
  poolhead_kernel<<<G, 128, 0, stream>>>(psum, batch, N, d1w, d1b, bng, bnb, bnm, bnv,
                                         d2w, d2b, out);
}

// Round 9
// 378.905 us; speedup vs baseline: 5.2857x; 1.1751x over previous
//
#include <hip/hip_runtime.h>
#include <math.h>

#define NHEAD 4
#define PCH 16
#define NSLOT 64
#define SLOT_STRIDE 512  // floats per slot (>= 2F for both layers)

typedef __bf16 bf16x8 __attribute__((ext_vector_type(8)));
typedef float f32x4 __attribute__((ext_vector_type(4)));

__device__ __forceinline__ unsigned short f2bf(float f) {
  unsigned int u = __float_as_uint(f);
  u += 0x7FFF + ((u >> 16) & 1);  // round-to-nearest-even
  return (unsigned short)(u >> 16);
}
__device__ __forceinline__ float bf2f(unsigned short s) {
  return __uint_as_float(((unsigned int)s) << 16);
}
__device__ __forceinline__ unsigned int comb2(unsigned int p, unsigned int q,
                                              float a0, float a1) {
  float lo = a0 * bf2f((unsigned short)p) + a1 * bf2f((unsigned short)q);
  float hi = a0 * bf2f((unsigned short)(p >> 16)) + a1 * bf2f((unsigned short)(q >> 16));
  return (unsigned)f2bf(lo) | ((unsigned)f2bf(hi) << 16);
}
__device__ __forceinline__ float fast_tanh(float x) {
  x = fminf(fmaxf(x, -15.f), 15.f);
  float e = __expf(2.f * x);
  return (e - 1.f) / (e + 1.f);
}

// ============ combined: weight transpose+cast (blocks < wblk) + dst histogram ============
__global__ void wtrans_hist_kernel(const float* __restrict__ p1w, const float* __restrict__ p2w,
                                   const float* __restrict__ k1w, const float* __restrict__ k2w,
                                   unsigned short* __restrict__ p1wt,
                                   unsigned short* __restrict__ p2wt,
                                   unsigned short* __restrict__ k1wt,
                                   unsigned short* __restrict__ k2wt,
                                   const int* __restrict__ ei0, const int* __restrict__ ei1,
                                   int E, int* __restrict__ deg, int N, int wblk) {
  if ((int)blockIdx.x < wblk) {
    int i = blockIdx.x * 256 + threadIdx.x;
    if (i < 32768) {                      // p1: [128,256]
      int k = i >> 8, f = i & 255;
      p1wt[f * 128 + k] = f2bf(p1w[i]);
    } else if (i < 65536) {               // p2: [256,128]
      int j = i - 32768; int k = j >> 7, f = j & 127;
      p2wt[f * 256 + k] = f2bf(p2w[j]);
    } else if (i < 131072) {              // k1: [256,256]
      int j = i - 65536; int k = j >> 8, f = j & 255;
      k1wt[f * 256 + k] = f2bf(k1w[j]);
    } else if (i < 147456) {              // k2: [128,128]
      int j = i - 131072; int k = j >> 7, f = j & 127;
      k2wt[f * 128 + k] = f2bf(k2w[j]);
    }
  } else {
    int i = (blockIdx.x - wblk) * 256 + threadIdx.x;
    if (i < 2 * E) {
      int r = i >= E;
      int e = i - (r ? E : 0);
      const int* ei = r ? ei1 : ei0;
      atomicAdd(&deg[r * N + ei[E + e]], 1);
    }
  }
}

__global__ void scan_local2_kernel(const int* __restrict__ deg, int* __restrict__ incl,
                                   int* __restrict__ bsum, int n, int nb) {
  __shared__ int tile[256];
  int r = blockIdx.x / nb;
  int b = blockIdx.x - r * nb;
  int i = b * 256 + threadIdx.x;
  int v = (i < n) ? deg[r * n + i] : 0;
  tile[threadIdx.x] = v;
  __syncthreads();
  for (int off = 1; off < 256; off <<= 1) {
    int t = (threadIdx.x >= (unsigned)off) ? tile[threadIdx.x - off] : 0;
    __syncthreads();
    tile[threadIdx.x] += t;
    __syncthreads();
  }
  if (i < n) incl[r * n + i] = tile[threadIdx.x];
  if (threadIdx.x == 255) bsum[blockIdx.x] = tile[255];
}

__global__ void scan_bsum2_kernel(int* __restrict__ bsum, int nb) {
  __shared__ int tile[256];
  int r = blockIdx.x;
  int v = (threadIdx.x < (unsigned)nb) ? bsum[r * nb + threadIdx.x] : 0;
  tile[threadIdx.x] = v;
  __syncthreads();
  for (int off = 1; off < 256; off <<= 1) {
    int t = (threadIdx.x >= (unsigned)off) ? tile[threadIdx.x - off] : 0;
    __syncthreads();
    tile[threadIdx.x] += t;
    __syncthreads();
  }
  if (threadIdx.x < (unsigned)nb) bsum[r * nb + threadIdx.x] = tile[threadIdx.x] - v;
}

__global__ void scan_fix2_kernel(const int* __restrict__ incl, const int* __restrict__ deg,
                                 const int* __restrict__ bsum, int* __restrict__ rp0,
                                 int* __restrict__ rp1, int n, int nb, int E) {
  int r = blockIdx.x / nb;
  int b = blockIdx.x - r * nb;
  int i = b * 256 + threadIdx.x;
  int* rp = r ? rp1 : rp0;
  if (i < n) rp[i] = incl[r * n + i] - deg[r * n + i] + bsum[blockIdx.x];
  if (i == 0) rp[n] = E;
}

__global__ void scatter2_kernel(const int* __restrict__ ei0, const int* __restrict__ ei1,
                                int E, const int* __restrict__ rp0, const int* __restrict__ rp1,
                                int* __restrict__ cur, int* __restrict__ cs0,
                                int* __restrict__ cs1, int N) {
  int i = blockIdx.x * blockDim.x + threadIdx.x;
  int tot = 2 * E;
  for (; i < tot; i += gridDim.x * blockDim.x) {
    int r = i >= E;
    int e = i - (r ? E : 0);
    const int* ei = r ? ei1 : ei0;
    const int* rp = r ? rp1 : rp0;
    int* cs = r ? cs1 : cs0;
    int dst = ei[E + e];
    int pos = rp[dst] + atomicAdd(&cur[r * N + dst], 1);
    cs[pos] = ei[e];  // src node id
  }
}

// =============== MFMA GEMM core: 64 rows x F cols/block, 256 thr, 16x16x32 bf16 ===============
#define MFMA_GEMM_CORE(K, F, BX)                                                      \
  constexpr int G = F / 64, S = 4 / G, RT = 4 / S;                                    \
  __shared__ unsigned short As[64][40]; /* pad 40: bank spread, rows 16B-aligned */   \
  const int tid = threadIdx.x;                                                        \
  const int lane = tid & 63, wid = tid >> 6;                                          \
  const int cg = wid % G, rg = wid / G;                                               \
  const int l15 = lane & 15, l4 = lane >> 4;                                          \
  const int m0 = (BX)*64;                                                             \
  const int wrow = rg * RT * 16;                                                      \
  f32x4 acc[RT][4];                                                                   \
  _Pragma("unroll") for (int rt = 0; rt < RT; ++rt)                                   \
  _Pragma("unroll") for (int ct = 0; ct < 4; ++ct)                                    \
      acc[rt][ct] = (f32x4){0.f, 0.f, 0.f, 0.f};                                      \
  const int arow = tid >> 2;                                                          \
  const int akk = (tid & 3) * 8;                                                      \
  for (int k0 = 0; k0 < K; k0 += 32) {                                                \
    uint4 av = {0u, 0u, 0u, 0u};                                                      \
    int row = m0 + arow;                                                              \
    if (row < M) { MFMA_LOAD_A }                                                      \
    __syncthreads();                                                                  \
    *(uint4*)&As[arow][akk] = av;                                                     \
    __syncthreads();                                                                  \
    bf16x8 bfr[4];                                                                    \
    _Pragma("unroll") for (int ct = 0; ct < 4; ++ct) {                                \
      int colx = cg * 64 + ct * 16 + l15;                                             \
      bfr[ct] = *(const bf16x8*)&Wt[(size_t)colx * K + k0 + l4 * 8];                  \
    }                                                                                 \
    _Pragma("unroll") for (int rt = 0; rt < RT; ++rt) {                               \
      bf16x8 afr = *(const bf16x8*)&As[wrow + rt * 16 + l15][l4 * 8];                 \
      _Pragma("unroll") for (int ct = 0; ct < 4; ++ct)                                \
        acc[rt][ct] = __builtin_amdgcn_mfma_f32_16x16x32_bf16(                        \
            afr, bfr[ct], acc[rt][ct], 0, 0, 0);                                      \
    }                                                                                 \
  }

// ---- proj GEMM with fused bias store + s/d epilogue ----
// MODE: 1 = A fp32 (convert in staging); 2 = A = bf16(a0*S0 + a1*S1)
template <int K, int F, int MODE, int DD>
__global__ __launch_bounds__(256) void mfma_gemm_proj(
    const float* __restrict__ Af,
    const unsigned short* __restrict__ S0, const unsigned short* __restrict__ S1,
    const float* __restrict__ attnp, const unsigned short* __restrict__ Wt,
    const float* __restrict__ bias, unsigned short* __restrict__ out,
    const float* __restrict__ as0v, const float* __restrict__ ad0v,
    const float* __restrict__ as1v, const float* __restrict__ ad1v,
    float* __restrict__ s0g, float* __restrict__ d0g,
    float* __restrict__ s1g, float* __restrict__ d1g, int M) {
  float ca0 = 0.f, ca1 = 0.f;
  if constexpr (MODE == 2) { ca0 = attnp[0]; ca1 = attnp[1]; }
#define MFMA_LOAD_A                                                                   \
  if constexpr (MODE == 1) {                                                          \
    float4 f0 = *(const float4*)&Af[(size_t)row * K + k0 + akk];                      \
    float4 f1 = *(const float4*)&Af[(size_t)row * K + k0 + akk + 4];                  \
    av.x = (unsigned)f2bf(f0.x) | ((unsigned)f2bf(f0.y) << 16);                       \
    av.y = (unsigned)f2bf(f0.z) | ((unsigned)f2bf(f0.w) << 16);                       \
    av.z = (unsigned)f2bf(f1.x) | ((unsigned)f2bf(f1.y) << 16);                       \
    av.w = (unsigned)f2bf(f1.z) | ((unsigned)f2bf(f1.w) << 16);                       \
  } else {                                                                            \
    uint4 u0 = *(const uint4*)&S0[(size_t)row * K + k0 + akk];                        \
    uint4 u1 = *(const uint4*)&S1[(size_t)row * K + k0 + akk];                        \
    av.x = comb2(u0.x, u1.x, ca0, ca1);                                               \
    av.y = comb2(u0.y, u1.y, ca0, ca1);                                               \
    av.z = comb2(u0.z, u1.z, ca0, ca1);                                               \
    av.w = comb2(u0.w, u1.w, ca0, ca1);                                               \
  }
  MFMA_GEMM_CORE(K, F, blockIdx.x)
#undef MFMA_LOAD_A
  // ---- bf16 h store ----
#pragma unroll
  for (int ct = 0; ct < 4; ++ct) {
    int n = cg * 64 + ct * 16 + l15;
    float bv = bias[n];
#pragma unroll
    for (int rt = 0; rt < RT; ++rt)
#pragma unroll
      for (int r = 0; r < 4; ++r) {
        int m = m0 + wrow + rt * 16 + l4 * 4 + r;
        if (m < M) out[(size_t)m * F + n] = f2bf(acc[rt][ct][r] + bv);
      }
  }
  // ---- fused s/d epilogue: per-head column reductions ----
  constexpr int HPW = 64 / DD, CTH = DD / 16;
#pragma unroll
  for (int hw = 0; hw < HPW; ++hw) {
    int head = cg * HPW + hw;
    float a0v[CTH], a1v[CTH], a2v[CTH], a3v[CTH], bvv[CTH];
#pragma unroll
    for (int c = 0; c < CTH; ++c) {
      int col = cg * 64 + (hw * CTH + c) * 16 + l15;
      a0v[c] = as0v[col]; a1v[c] = ad0v[col];
      a2v[c] = as1v[col]; a3v[c] = ad1v[col];
      bvv[c] = bias[col];
    }
#pragma unroll
    for (int rt = 0; rt < RT; ++rt) {
#pragma unroll
      for (int r = 0; r < 4; ++r) {
        float v0 = 0.f, v1 = 0.f, v2 = 0.f, v3 = 0.f;
#pragma unroll
        for (int c = 0; c < CTH; ++c) {
          float hval = acc[rt][hw * CTH + c][r] + bvv[c];
          v0 += hval * a0v[c]; v1 += hval * a1v[c];
          v2 += hval * a2v[c]; v3 += hval * a3v[c];
        }
#pragma unroll
        for (int off = 8; off > 0; off >>= 1) {
          v0 += __shfl_xor(v0, off, 16);
          v1 += __shfl_xor(v1, off, 16);
          v2 += __shfl_xor(v2, off, 16);
          v3 += __shfl_xor(v3, off, 16);
        }
        if (l15 == 0) {
          int m = m0 + wrow + rt * 16 + l4 * 4 + r;
          if (m < M) {
            int idx = m * NHEAD + head;
            s0g[idx] = v0; d0g[idx] = v1;
            s1g[idx] = v2; d1g[idx] = v3;
          }
        }
      }
    }
  }
}

// ---- semantic GEMM, both relations in one launch: slot-spread atomics ----
// wslots[NSLOT][SLOT_STRIDE]; block adds into slot (blockIdx&63), +F for relation 1.
template <int K, int F>
__global__ __launch_bounds__(256) void mfma_gemm_tanh2(
    const unsigned short* __restrict__ A0, const unsigned short* __restrict__ A1,
    const unsigned short* __restrict__ Wt, const float* __restrict__ bias,
    float* __restrict__ wslots, int M, int half) {
  const unsigned short* A;
  float* ws = wslots + (blockIdx.x & (NSLOT - 1)) * SLOT_STRIDE;
  int bx = blockIdx.x;
  if (bx < half) { A = A0; }
  else { A = A1; ws += F; bx -= half; }
#define MFMA_LOAD_A av = *(const uint4*)&A[(size_t)row * K + k0 + akk];
  MFMA_GEMM_CORE(K, F, bx)
#undef MFMA_LOAD_A
#pragma unroll
  for (int ct = 0; ct < 4; ++ct) {
    int n = cg * 64 + ct * 16 + l15;
    float bv = bias[n];
    float cs = 0.f;
#pragma unroll
    for (int rt = 0; rt < RT; ++rt)
#pragma unroll
      for (int r = 0; r < 4; ++r) {
        int m = m0 + wrow + rt * 16 + l4 * 4 + r;
        if (m < M) cs += fast_tanh(acc[rt][ct][r] + bv);
      }
    cs += __shfl_xor(cs, 16, 64);
    cs += __shfl_xor(cs, 32, 64);
    if (l4 == 0) atomicAdd(&ws[n], cs);
  }
}

// ---- fused per-dst softmax + weighted gather + relu; wave/node, 4-edge unroll ----
// both relations in ONE launch; blocks 0..63 zero their wslot (2F floats, strided)
__device__ __forceinline__ void acc4(uint2 hv, float v, float* acc) {
  acc[0] += v * bf2f((unsigned short)(hv.x & 0xffff));
  acc[1] += v * bf2f((unsigned short)(hv.x >> 16));
  acc[2] += v * bf2f((unsigned short)(hv.y & 0xffff));
  acc[3] += v * bf2f((unsigned short)(hv.y >> 16));
}
__device__ __forceinline__ void acc2(unsigned int hv, float v, float* acc) {
  acc[0] += v * bf2f((unsigned short)(hv & 0xffff));
  acc[1] += v * bf2f((unsigned short)(hv >> 16));
}
__device__ __forceinline__ float ecoef(float sv, float dv) {
  float a = sv + dv;
  a = (a >= 0.f) ? a : 0.2f * a;
  return __expf(a);  // segment_max skipped: cancels in softmax, alpha is O(1)
}

template <int F, int D>
__global__ void message2_kernel(const unsigned short* __restrict__ h,
                                const int* __restrict__ cs0, const int* __restrict__ rp0,
                                const float* __restrict__ s0, const float* __restrict__ d0,
                                unsigned short* __restrict__ o0,
                                const int* __restrict__ cs1, const int* __restrict__ rp1,
                                const float* __restrict__ s1, const float* __restrict__ d1,
                                unsigned short* __restrict__ o1,
                                float* __restrict__ wslots,  // blocks 0..63 zero slot b
                                int N, int half) {
  constexpr int VEC = F / 64;
  if (blockIdx.x < NSLOT) {
    float* ws = wslots + blockIdx.x * SLOT_STRIDE;
    for (int i = threadIdx.x; i < 2 * F; i += 256) ws[i] = 0.f;
  }
  int b = blockIdx.x;
  const int* colsrc; const int* rp; const float* s; const float* d;
  unsigned short* out;
  if (b < half) { colsrc = cs0; rp = rp0; s = s0; d = d0; out = o0; }
  else { b -= half; colsrc = cs1; rp = rp1; s = s1; d = d1; out = o1; }
  int w = threadIdx.x >> 6;
  int lane = threadIdx.x & 63;
  int nn = b * 4 + w;
  if (nn >= N) return;
  int f0 = lane * VEC;
  int hh = f0 / D;
  float dv = d[nn * NHEAD + hh];
  int lo = rp[nn], hi = rp[nn + 1];
  float acc[VEC];
#pragma unroll
  for (int v = 0; v < VEC; ++v) acc[v] = 0.f;
  float den = 0.f;
  int j = lo;
  for (; j + 4 <= hi; j += 4) {
    int c0 = colsrc[j], c1 = colsrc[j + 1], c2 = colsrc[j + 2], c3 = colsrc[j + 3];
    float e0 = s[c0 * NHEAD + hh], e1 = s[c1 * NHEAD + hh];
    float e2 = s[c2 * NHEAD + hh], e3 = s[c3 * NHEAD + hh];
    if constexpr (VEC == 4) {
      uint2 h0 = *(const uint2*)&h[(size_t)c0 * F + f0];
      uint2 h1 = *(const uint2*)&h[(size_t)c1 * F + f0];
      uint2 h2 = *(const uint2*)&h[(size_t)c2 * F + f0];
      uint2 h3 = *(const uint2*)&h[(size_t)c3 * F + f0];
      float v0 = ecoef(e0, dv), v1 = ecoef(e1, dv);
      float v2 = ecoef(e2, dv), v3 = ecoef(e3, dv);
      den += v0 + v1 + v2 + v3;
      acc4(h0, v0, acc); acc4(h1, v1, acc);
      acc4(h2, v2, acc); acc4(h3, v3, acc);
    } else {
      unsigned int h0 = *(const unsigned int*)&h[(size_t)c0 * F + f0];
      unsigned int h1 = *(const unsigned int*)&h[(size_t)c1 * F + f0];
      unsigned int h2 = *(const unsigned int*)&h[(size_t)c2 * F + f0];
      unsigned int h3 = *(const unsigned int*)&h[(size_t)c3 * F + f0];
      float v0 = ecoef(e0, dv), v1 = ecoef(e1, dv);
      float v2 = ecoef(e2, dv), v3 = ecoef(e3, dv);
      den += v0 + v1 + v2 + v3;
      acc2(h0, v0, acc); acc2(h1, v1, acc);
      acc2(h2, v2, acc); acc2(h3, v3, acc);
    }
  }
  for (; j < hi; ++j) {
    int c = colsrc[j];
    float v = ecoef(s[c * NHEAD + hh], dv);
    den += v;
    if constexpr (VEC == 4) acc4(*(const uint2*)&h[(size_t)c * F + f0], v, acc);
    else acc2(*(const unsigned int*)&h[(size_t)c * F + f0], v, acc);
  }
  float inv = 1.f / (den + 1e-16f);
  if constexpr (VEC == 4) {
    uint2 o;
    o.x = (unsigned)f2bf(fmaxf(acc[0] * inv, 0.f)) |
          ((unsigned)f2bf(fmaxf(acc[1] * inv, 0.f)) << 16);
    o.y = (unsigned)f2bf(fmaxf(acc[2] * inv, 0.f)) |
          ((unsigned)f2bf(fmaxf(acc[3] * inv, 0.f)) << 16);
    *(uint2*)&out[(size_t)nn * F + f0] = o;
  } else {
    unsigned int o = (unsigned)f2bf(fmaxf(acc[0] * inv, 0.f)) |
                     ((unsigned)f2bf(fmaxf(acc[1] * inv, 0.f)) << 16);
    *(unsigned int*)&out[(size_t)nn * F + f0] = o;
  }
}

// ------- attn = softmax_r( mean_w_r . q ), reducing over NSLOT slots; opt zero psum -------
template <int F, bool ZP>
__global__ void attn_kernel(const float* __restrict__ wslots, const float* __restrict__ q,
                            float* __restrict__ attn, float inv_n,
                            float* __restrict__ psum, int pn) {
  __shared__ float red[2][F / 64];
  int f = threadIdx.x;
  if constexpr (ZP) {
    for (int i = f; i < pn; i += F) psum[i] = 0.f;
  }
  float w0 = 0.f, w1 = 0.f;
#pragma unroll 8
  for (int s = 0; s < NSLOT; ++s) {
    w0 += wslots[s * SLOT_STRIDE + f];
    w1 += wslots[s * SLOT_STRIDE + F + f];
  }
  float qv = q[f];
  float v0 = w0 * inv_n * qv;
  float v1 = w1 * inv_n * qv;
#pragma unroll
  for (int off = 32; off > 0; off >>= 1) {
    v0 += __shfl_down(v0, off, 64);
    v1 += __shfl_down(v1, off, 64);
  }
  int w = f / 64;
  if ((f & 63) == 0) { red[0][w] = v0; red[1][w] = v1; }
  __syncthreads();
  if (f == 0) {
    float d0 = 0.f, d1 = 0.f;
#pragma unroll
    for (int i = 0; i < F / 64; ++i) { d0 += red[0][i]; d1 += red[1][i]; }
    float m = fmaxf(d0, d1);
    float e0 = expf(d0 - m), e1 = expf(d1 - m);
    float inv = 1.f / (e0 + e1);
    attn[0] = e0 * inv;
    attn[1] = e1 * inv;
  }
}

// ------- pool with layer-2 combine fused (PCH=16 -> 3125 blocks, 1 wave each) -------
__global__ void pool_fused_kernel(const unsigned short* __restrict__ st0,
                                  const unsigned short* __restrict__ st1,
                                  const float* __restrict__ attn,
                                  const int* __restrict__ batch,
                                  float* __restrict__ psum, int n) {
  int c0 = blockIdx.x * PCH;
  if (c0 >= n) return;
  int lane = threadIdx.x;  // 64; 2 features each
  float a0 = attn[0], a1 = attn[1];
  int end = min(c0 + PCH, n);
  int g_cur = batch[c0];
  float acc0 = 0.f, acc1 = 0.f;
  for (int nn = c0; nn < end; ++nn) {
    int g = batch[nn];
    if (g != g_cur) {
      atomicAdd(&psum[g_cur * 128 + lane * 2], acc0);
      atomicAdd(&psum[g_cur * 128 + lane * 2 + 1], acc1);
      acc0 = acc1 = 0.f;
      g_cur = g;
    }
    unsigned int u0 = *(const unsigned int*)&st0[(size_t)nn * 128 + lane * 2];
    unsigned int u1 = *(const unsigned int*)&st1[(size_t)nn * 128 + lane * 2];
    acc0 += bf2f(f2bf(a0 * bf2f((unsigned short)(u0 & 0xffff)) +
                      a1 * bf2f((unsigned short)(u1 & 0xffff))));
    acc1 += bf2f(f2bf(a0 * bf2f((unsigned short)(u0 >> 16)) +
                      a1 * bf2f((unsigned short)(u1 >> 16))));
  }
  atomicAdd(&psum[g_cur * 128 + lane * 2], acc0);
  atomicAdd(&psum[g_cur * 128 + lane * 2 + 1], acc1);
}

__device__ __forceinline__ int lower_bound_i(const int* a, int n, int key) {
  int lo = 0, hi = n;
  while (lo < hi) {
    int mid = (lo + hi) >> 1;
    if (a[mid] < key) lo = mid + 1; else hi = mid;
  }
  return lo;
}

// ------- fused pool-final + MLP head: G blocks x 128 threads -------
__global__ void poolhead_kernel(const float* __restrict__ psum, const int* __restrict__ batch,
                                int n, const float* __restrict__ d1w,
                                const float* __restrict__ d1b, const float* __restrict__ gamma,
                                const float* __restrict__ beta, const float* __restrict__ mean,
                                const float* __restrict__ var, const float* __restrict__ d2w,
                                const float* __restrict__ d2b, float* __restrict__ out) {
  __shared__ float pool_sh[128];
  int g = blockIdx.x;
  int f = threadIdx.x;  // 128
  int lo = lower_bound_i(batch, n, g);
  int hi = lower_bound_i(batch, n, g + 1);
  float cnt = fmaxf((float)(hi - lo), 1.f);
  pool_sh[f] = psum[g * 128 + f] / cnt;
  __syncthreads();
  if (f < 64) {
    float acc = d1b[f];
#pragma unroll 8
    for (int k = 0; k < 128; ++k) acc += pool_sh[k] * d1w[k * 64 + f];
    float z = (acc - mean[f]) / sqrtf(var[f] + 1e-5f) * gamma[f] + beta[f];
    z = (z >= 0.f) ? z : 0.1f * z;
    float t = z * d2w[f];
#pragma unroll
    for (int off = 32; off > 0; off >>= 1) t += __shfl_down(t, off, 64);
    if (f == 0) out[g] = t + d2b[0];
  }
}

// =====================================================================
extern "C" void kernel_launch(void* const* d_in, const int* in_sizes, int n_in,
                              void* d_out, int out_size, void* d_ws, size_t ws_size,
                              hipStream_t stream) {
  const float* x      = (const float*)d_in[0];
  const int* ei0      = (const int*)d_in[1];
  const int* ei1      = (const int*)d_in[2];
  const int* batch    = (const int*)d_in[3];
  const float* p1w    = (const float*)d_in[4];
  const float* p1b    = (const float*)d_in[5];
  const float* as1r0  = (const float*)d_in[6];
  const float* ad1r0  = (const float*)d_in[7];
  const float* as1r1  = (const float*)d_in[8];
  const float* ad1r1  = (const float*)d_in[9];
  const float* kl1w   = (const float*)d_in[10];
  const float* kl1b   = (const float*)d_in[11];
  const float* q1     = (const float*)d_in[12];
  const float* p2w    = (const float*)d_in[13];
  const float* p2b    = (const float*)d_in[14];
  const float* as2r0  = (const float*)d_in[15];
  const float* ad2r0  = (const float*)d_in[16];
  const float* as2r1  = (const float*)d_in[17];
  const float* ad2r1  = (const float*)d_in[18];
  const float* kl2w   = (const float*)d_in[19];
  const float* kl2b   = (const float*)d_in[20];
  const float* q2     = (const float*)d_in[21];
  const float* d1w    = (const float*)d_in[22];
  const float* d1b    = (const float*)d_in[23];
  const float* bng    = (const float*)d_in[24];
  const float* bnb    = (const float*)d_in[25];
  const float* bnm    = (const float*)d_in[26];
  const float* bnv    = (const float*)d_in[27];
  const float* d2w    = (const float*)d_in[28];
  const float* d2b    = (const float*)d_in[29];
  float* out = (float*)d_out;

  const int N = in_sizes[3];       // 50000
  const int E = in_sizes[1] / 2;   // 400000
  const int G = 64;

  char* p = (char*)d_ws;
  auto alloc = [&](size_t bytes) -> void* {
    void* r = (void*)p;
    p += (bytes + 255) & ~(size_t)255;
    return r;
  };
  int* rp0    = (int*)alloc((N + 1) * sizeof(int));
  int* rp1    = (int*)alloc((N + 1) * sizeof(int));
  int* cs0    = (int*)alloc(E * sizeof(int));        // src per CSR slot
  int* cs1    = (int*)alloc(E * sizeof(int));
  int* deg    = (int*)alloc(2 * (size_t)N * sizeof(int));   // deg+cur: one memset
  int* cur    = (int*)alloc(2 * (size_t)N * sizeof(int));
  int* incl   = (int*)alloc(2 * (size_t)N * sizeof(int));
  int* bsum   = (int*)alloc(512 * sizeof(int));
  unsigned short* h_bf  = (unsigned short*)alloc((size_t)N * 256 * 2);
  unsigned short* st0   = (unsigned short*)alloc((size_t)N * 256 * 2);
  unsigned short* st1   = (unsigned short*)alloc((size_t)N * 256 * 2);
  unsigned short* h2_bf = (unsigned short*)alloc((size_t)N * 128 * 2);
  unsigned short* p1wt  = (unsigned short*)alloc(128 * 256 * 2);
  unsigned short* p2wt  = (unsigned short*)alloc(256 * 128 * 2);
  unsigned short* k1wt  = (unsigned short*)alloc(256 * 256 * 2);
  unsigned short* k2wt  = (unsigned short*)alloc(128 * 128 * 2);
  float* s0     = (float*)alloc((size_t)N * NHEAD * sizeof(float));
  float* d0     = (float*)alloc((size_t)N * NHEAD * sizeof(float));
  float* s1     = (float*)alloc((size_t)N * NHEAD * sizeof(float));
  float* d1     = (float*)alloc((size_t)N * NHEAD * sizeof(float));
  float* wslots = (float*)alloc((size_t)NSLOT * SLOT_STRIDE * sizeof(float));
  float* attn1  = (float*)alloc(2 * sizeof(float));
  float* attn2  = (float*)alloc(2 * sizeof(float));
  float* psum   = (float*)alloc((size_t)G * 128 * sizeof(float));

  // ---- 1: zero deg+cur (contiguous allocs -> single memset) ----
  size_t zlen = (size_t)((char*)cur - (char*)deg) + 2 * (size_t)N * sizeof(int);
  hipMemsetAsync(deg, 0, zlen, stream);

  // ---- 2: weight transpose+cast fused with dst histogram ----
  int wblk = 576;  // 147456 / 256
  int e2blk = (2 * E + 255) / 256;
  wtrans_hist_kernel<<<wblk + e2blk, 256, 0, stream>>>(
      p1w, p2w, kl1w, kl2w, p1wt, p2wt, k1wt, k2wt, ei0, ei1, E, deg, N, wblk);

  // ---- 3-6: scan + scatter ----
  int nb = (N + 255) / 256;
  scan_local2_kernel<<<2 * nb, 256, 0, stream>>>(deg, incl, bsum, N, nb);
  scan_bsum2_kernel<<<2, 256, 0, stream>>>(bsum, nb);
  scan_fix2_kernel<<<2 * nb, 256, 0, stream>>>(incl, deg, bsum, rp0, rp1, N, nb, E);
  scatter2_kernel<<<e2blk, 256, 0, stream>>>(ei0, ei1, E, rp0, rp1, cur, cs0, cs1, N);

  int gblk = (N + 63) / 64;
  int nblk4 = (N + 3) / 4;

  // ================= layer 1: 128 -> 256, D=64 =================
  mfma_gemm_proj<128, 256, 1, 64><<<gblk, 256, 0, stream>>>(
      x, nullptr, nullptr, nullptr, p1wt, p1b, h_bf,
      as1r0, ad1r0, as1r1, ad1r1, s0, d0, s1, d1, N);
  message2_kernel<256, 64><<<2 * nblk4, 256, 0, stream>>>(
      h_bf, cs0, rp0, s0, d0, st0, cs1, rp1, s1, d1, st1, wslots, N, nblk4);
  mfma_gemm_tanh2<256, 256><<<2 * gblk, 256, 0, stream>>>(
      st0, st1, k1wt, kl1b, wslots, N, gblk);
  attn_kernel<256, false><<<1, 256, 0, stream>>>(wslots, q1, attn1, 1.0f / (float)N,
                                                 nullptr, 0);

  // ================= layer 2: 256 -> 128, D=32 =================
  mfma_gemm_proj<256, 128, 2, 32><<<gblk, 256, 0, stream>>>(
      nullptr, st0, st1, attn1, p2wt, p2b, h2_bf,
      as2r0, ad2r0, as2r1, ad2r1, s0, d0, s1, d1, N);
  message2_kernel<128, 32><<<2 * nblk4, 256, 0, stream>>>(
      h2_bf, cs0, rp0, s0, d0, st0, cs1, rp1, s1, d1, st1, wslots, N, nblk4);
  mfma_gemm_tanh2<128, 128><<<2 * gblk, 256, 0, stream>>>(
      st0, st1, k2wt, kl2b, wslots, N, gblk);
  attn_kernel<128, true><<<1, 128, 0, stream>>>(wslots, q2, attn2, 1.0f / (float)N,
                                                psum, G * 128);

  // ---- pool (combine fused) + fused final/head ----
  int pblk = (N + PCH - 1) / PCH;
  pool_fused_kernel<<<pblk, 64, 0, stream>>>(st0, st1, attn2, batch, psum, N);
  poolhead_kernel<<<G, 128, 0, stream>>>(psum, batch, N, d1w, d1b, bng, bnb, bnm, bnv,
                                         d2w, d2b, out);
}